// Round 14
// baseline (2544.745 us; speedup 1.0000x reference)
//
#include <hip/hip_runtime.h>
#include <math.h>

#define NB 8
#define DDIM 768
#define NHEAD 12
#define NDEPTH 12
#define HDIM 64
#define GRIDW 24
#define NL0 576
#define NL 577
#define LPAD 640
#define NHID 3072
#define MROWS (NB*NL)     // 4616
#define MPAD 4736         // 37*128, 74*64
#define EPSV 1e-5f
#define QT3 3             // 256-q-row blocks per head
#define NCONV 512

typedef unsigned short ushortT;
typedef __attribute__((ext_vector_type(8))) short bf16x8;
typedef __attribute__((ext_vector_type(4))) float f32x4;

__device__ __forceinline__ ushortT f2b(float f) {
    union { float f; unsigned u; } x; x.f = f;
    unsigned r = x.u + 0x7fffu + ((x.u >> 16) & 1u);
    return (ushortT)(r >> 16);
}

__device__ __forceinline__ float b2f(ushortT u) {
    union { unsigned u; float f; } x; x.u = ((unsigned)u) << 16;
    return x.f;
}

__device__ __forceinline__ void load_lds16(const void* g, void* l) {
    __builtin_amdgcn_global_load_lds((const __attribute__((address_space(1))) void*)g,
                                     (__attribute__((address_space(3))) void*)l, 16, 0, 0);
}

// ---------------- fp32 -> bf16 convert ----------------
__global__ void f2b_k(const float* __restrict__ in, ushortT* __restrict__ out, long n) {
    for (long i = ((long)blockIdx.x * 256 + threadIdx.x) * 4; i < n; i += (long)gridDim.x * 1024) {
        float4 v = *(const float4*)(in + i);
        ushort4 o; o.x = f2b(v.x); o.y = f2b(v.y); o.z = f2b(v.z); o.w = f2b(v.w);
        *(ushort4*)(out + i) = o;
    }
}

// ---------------- 4-array convert (preamble: layer-0 weights) ----------------
__global__ void wconv4_k(const float* __restrict__ a, ushortT* __restrict__ ao, long na,
                         const float* __restrict__ b, ushortT* __restrict__ bo, long nb,
                         const float* __restrict__ c, ushortT* __restrict__ co, long nc,
                         const float* __restrict__ d, ushortT* __restrict__ dd, long nd) {
    long stride = (long)gridDim.x * 1024;
    long i0 = ((long)blockIdx.x * 256 + threadIdx.x) * 4;
    for (long i = i0; i < na; i += stride) {
        float4 v = *(const float4*)(a + i);
        ushort4 o; o.x = f2b(v.x); o.y = f2b(v.y); o.z = f2b(v.z); o.w = f2b(v.w);
        *(ushort4*)(ao + i) = o;
    }
    for (long i = i0; i < nb; i += stride) {
        float4 v = *(const float4*)(b + i);
        ushort4 o; o.x = f2b(v.x); o.y = f2b(v.y); o.z = f2b(v.z); o.w = f2b(v.w);
        *(ushort4*)(bo + i) = o;
    }
    for (long i = i0; i < nc; i += stride) {
        float4 v = *(const float4*)(c + i);
        ushort4 o; o.x = f2b(v.x); o.y = f2b(v.y); o.z = f2b(v.z); o.w = f2b(v.w);
        *(ushort4*)(co + i) = o;
    }
    for (long i = i0; i < nd; i += stride) {
        float4 v = *(const float4*)(d + i);
        ushort4 o; o.x = f2b(v.x); o.y = f2b(v.y); o.z = f2b(v.z); o.w = f2b(v.w);
        *(ushort4*)(dd + i) = o;
    }
}

// ---------------- im2col -> bf16 patches[4608, 768] ----------------
__global__ void im2col_k(const float* __restrict__ x, ushortT* __restrict__ p) {
    for (long idx = (long)blockIdx.x * 256 + threadIdx.x; idx < (long)4608 * 768; idx += (long)gridDim.x * 256) {
        int row = (int)(idx / 768), col = (int)(idx - (long)row * 768);
        int b = row / NL0, pi = row - b * NL0;
        int gy = pi / GRIDW, gx = pi - gy * GRIDW;
        int c = col >> 8, r = col & 255;
        int py = r >> 4, px = r & 15;
        p[idx] = f2b(x[(((long)(b * 3 + c) * 384) + gy * 16 + py) * 384 + gx * 16 + px]);
    }
}

__global__ void cls_k(const float* __restrict__ cls, float* __restrict__ t) {
    t[(long)blockIdx.x * NL * DDIM + threadIdx.x] = cls[threadIdx.x];
}

__global__ void rope_k(float* __restrict__ sin_t, float* __restrict__ cos_t) {
    int pos = blockIdx.x, d = threadIdx.x;
    int gy = pos / GRIDW, gx = pos - gy * GRIDW;
    int j = d >> 1;
    float ang;
    if (j < 16) ang = (float)gy * powf(10000.f, -(float)j / 16.f);
    else        ang = (float)gx * powf(10000.f, -(float)(j - 16) / 16.f);
    sin_t[pos * 64 + d] = sinf(ang);
    cos_t[pos * 64 + d] = cosf(ang);
}

// ---------------- LayerNorm (plain; layer-0 ln1 and all ln2) ----------------
__global__ __launch_bounds__(256) void ln_k(const float* __restrict__ in,
                                            const float* __restrict__ sc,
                                            const float* __restrict__ bi,
                                            float* __restrict__ outf,
                                            ushortT* __restrict__ outb,
                                            long in_rstride) {
    int row = blockIdx.x;
    const float* ip = in + (long)row * in_rstride;
    float x[3];
    float s = 0.f, s2 = 0.f;
    #pragma unroll
    for (int i = 0; i < 3; ++i) {
        x[i] = ip[threadIdx.x + i * 256];
        s += x[i]; s2 += x[i] * x[i];
    }
    __shared__ float red0[256], red1[256];
    red0[threadIdx.x] = s; red1[threadIdx.x] = s2;
    __syncthreads();
    for (int off = 128; off; off >>= 1) {
        if (threadIdx.x < off) {
            red0[threadIdx.x] += red0[threadIdx.x + off];
            red1[threadIdx.x] += red1[threadIdx.x + off];
        }
        __syncthreads();
    }
    float mean = red0[0] * (1.f / 768.f);
    float var  = red1[0] * (1.f / 768.f) - mean * mean;
    float inv = rsqrtf(var + EPSV);
    #pragma unroll
    for (int i = 0; i < 3; ++i) {
        int c = threadIdx.x + i * 256;
        float val = (x[i] - mean) * inv * sc[c] + bi[c];
        if (outb) outb[(long)row * 768 + c] = f2b(val);
        else      outf[(long)row * 768 + c] = val;
    }
}

// ---------------- fused: t += mlp2_bias + sum4(bf16 psum); then LN1(next layer) -> h_bf ----------------
__global__ __launch_bounds__(256) void red_ln_k(const ushortT* __restrict__ psum,
                                                const float* __restrict__ b2,
                                                float* __restrict__ t,
                                                const float* __restrict__ sc,
                                                const float* __restrict__ bi,
                                                ushortT* __restrict__ outb) {
    int row = blockIdx.x;
    const size_t S = (size_t)MPAD * DDIM;
    const size_t rb = (size_t)row * DDIM;
    float x[3];
    float s = 0.f, s2 = 0.f;
    #pragma unroll
    for (int i = 0; i < 3; ++i) {
        int c = threadIdx.x + i * 256;
        float v = t[rb + c] + b2[c] + b2f(psum[rb + c]) + b2f(psum[S + rb + c])
                + b2f(psum[2 * S + rb + c]) + b2f(psum[3 * S + rb + c]);
        x[i] = v; s += v; s2 += v * v;
        t[rb + c] = v;
    }
    __shared__ float red0[256], red1[256];
    red0[threadIdx.x] = s; red1[threadIdx.x] = s2;
    __syncthreads();
    for (int off = 128; off; off >>= 1) {
        if (threadIdx.x < off) {
            red0[threadIdx.x] += red0[threadIdx.x + off];
            red1[threadIdx.x] += red1[threadIdx.x + off];
        }
        __syncthreads();
    }
    float mean = red0[0] * (1.f / 768.f);
    float var  = red1[0] * (1.f / 768.f) - mean * mean;
    float inv = rsqrtf(var + EPSV);
    #pragma unroll
    for (int i = 0; i < 3; ++i) {
        int c = threadIdx.x + i * 256;
        outb[rb + c] = f2b((x[i] - mean) * inv * sc[c] + bi[c]);
    }
}

// ---------------- final: reduce CLS rows only + final LN -> d_out[8,768] f32 ----------------
__global__ __launch_bounds__(256) void red_final_k(const ushortT* __restrict__ psum,
                                                   const float* __restrict__ b2,
                                                   const float* __restrict__ t,
                                                   const float* __restrict__ sc,
                                                   const float* __restrict__ bi,
                                                   float* __restrict__ outf) {
    int row = blockIdx.x * NL;            // CLS row of batch blockIdx.x
    const size_t S = (size_t)MPAD * DDIM;
    const size_t rb = (size_t)row * DDIM;
    float x[3];
    float s = 0.f, s2 = 0.f;
    #pragma unroll
    for (int i = 0; i < 3; ++i) {
        int c = threadIdx.x + i * 256;
        float v = t[rb + c] + b2[c] + b2f(psum[rb + c]) + b2f(psum[S + rb + c])
                + b2f(psum[2 * S + rb + c]) + b2f(psum[3 * S + rb + c]);
        x[i] = v; s += v; s2 += v * v;
    }
    __shared__ float red0[256], red1[256];
    red0[threadIdx.x] = s; red1[threadIdx.x] = s2;
    __syncthreads();
    for (int off = 128; off; off >>= 1) {
        if (threadIdx.x < off) {
            red0[threadIdx.x] += red0[threadIdx.x + off];
            red1[threadIdx.x] += red1[threadIdx.x + off];
        }
        __syncthreads();
    }
    float mean = red0[0] * (1.f / 768.f);
    float var  = red1[0] * (1.f / 768.f) - mean * mean;
    float inv = rsqrtf(var + EPSV);
    #pragma unroll
    for (int i = 0; i < 3; ++i) {
        int c = threadIdx.x + i * 256;
        outf[(long)blockIdx.x * 768 + c] = (x[i] - mean) * inv * sc[c] + bi[c];
    }
}

// ---------------- templated bf16 MFMA GEMM (2-stage dbuf, NW waves) ----------------
// NW*64 threads. 2-stage double-buffered LDS; stage(t+1) issued BEFORE compute(t);
// one vmcnt(0)+s_barrier per K-step. T2 XOR swizzle; T1 XCD chunking.
// NOTE (r12 lesson): 2 blocks/CU for cross-block drain coverage beats bigger
// wave-tiles at 1 block/CU — keep LDS <= 64KB for these shapes.
// flags: 1=bias 2=resid(f32) 4=gelu 8=remap(576->577) 16=store f32 32=store bf16
//        64=qkv mode (RoPE + scale + scatter; requires NI==4; BN==128)
// SPLITK>1: blockIdx.z selects K-chunk; acc -> psum[z][MPAD][N] as bf16.
template<int WR, int WC, int MI, int NI, int SPLITK, int NW>
__global__ __launch_bounds__(NW * 64) void gemm_t(const ushortT* __restrict__ A,
                                                  const ushortT* __restrict__ W,
                                                  const float* __restrict__ bias,
                                                  const float* __restrict__ resid,
                                                  float* __restrict__ Cf,
                                                  ushortT* __restrict__ Cb,
                                                  const float* __restrict__ sinT,
                                                  const float* __restrict__ cosT,
                                                  ushortT* __restrict__ qo,
                                                  ushortT* __restrict__ ko,
                                                  ushortT* __restrict__ vo,
                                                  ushortT* __restrict__ psum,
                                                  int N, int K, int flags) {
    constexpr int BM = WR * MI * 16;
    constexpr int BN = WC * NI * 16;
    constexpr int THREADS = NW * 64;
    constexpr int ACH = (BM * 64) / (THREADS * 8);
    constexpr int BCH = (BN * 64) / (THREADS * 8);
    __shared__ ushortT As[2][BM * 64];
    __shared__ ushortT Bs[2][BN * 64];
    int tid = threadIdx.x;
    int lane = tid & 63, wid = tid >> 6;
    int wm = wid / WC, wn = wid % WC;
    int lr = lane & 15, lk = lane >> 4;
    int nwg = gridDim.x * gridDim.y;
    int flat = blockIdx.y * gridDim.x + blockIdx.x;
    int qq = nwg >> 3, rr = nwg & 7;
    int xcd = flat & 7, idx = flat >> 3;
    int wg = (xcd < rr ? xcd * (qq + 1) : rr * (qq + 1) + (xcd - rr) * qq) + idx;
    int bx = wg % gridDim.x, by = wg / gridDim.x;
    int m0 = by * BM, n0 = bx * BN;
    int kspan = K / SPLITK;
    int k0 = (SPLITK > 1) ? blockIdx.z * kspan : 0;
    f32x4 acc[MI][NI] = {};

    auto stage = [&](int buf, int kt) {
        #pragma unroll
        for (int i = 0; i < ACH; ++i) {
            int ch = i * THREADS + tid;
            int r = ch >> 3, cb = (ch & 7) * 16;
            int cbs = cb ^ ((r & 7) << 4);
            load_lds16(A + (size_t)(m0 + r) * K + kt + (cbs >> 1), &As[buf][ch * 8]);
        }
        #pragma unroll
        for (int i = 0; i < BCH; ++i) {
            int ch = i * THREADS + tid;
            int r = ch >> 3, cb = (ch & 7) * 16;
            int cbs = cb ^ ((r & 7) << 4);
            load_lds16(W + (size_t)(n0 + r) * K + kt + (cbs >> 1), &Bs[buf][ch * 8]);
        }
    };

    stage(0, k0);
    asm volatile("s_waitcnt vmcnt(0)" ::: "memory");
    __builtin_amdgcn_s_barrier();
    int nk = kspan / 64;
    int cur = 0;
    for (int it = 0; it < nk; ++it) {
        if (it + 1 < nk) stage(cur ^ 1, k0 + (it + 1) * 64);
        #pragma unroll
        for (int ks = 0; ks < 2; ++ks) {
            bf16x8 aF[MI], bF[NI];
            #pragma unroll
            for (int mi = 0; mi < MI; ++mi) {
                int row = wm * MI * 16 + mi * 16 + lr;
                aF[mi] = *(const bf16x8*)((const char*)&As[cur][0] + row * 128 +
                                          ((ks * 64 + lk * 16) ^ ((row & 7) << 4)));
            }
            #pragma unroll
            for (int ni = 0; ni < NI; ++ni) {
                int row = wn * NI * 16 + ni * 16 + lr;
                bF[ni] = *(const bf16x8*)((const char*)&Bs[cur][0] + row * 128 +
                                          ((ks * 64 + lk * 16) ^ ((row & 7) << 4)));
            }
            #pragma unroll
            for (int mi = 0; mi < MI; ++mi)
                #pragma unroll
                for (int ni = 0; ni < NI; ++ni)
                    acc[mi][ni] = __builtin_amdgcn_mfma_f32_16x16x32_bf16(aF[mi], bF[ni], acc[mi][ni], 0, 0, 0);
        }
        asm volatile("s_waitcnt vmcnt(0)" ::: "memory");
        __builtin_amdgcn_s_barrier();
        cur ^= 1;
    }

    if (SPLITK > 1) {
        #pragma unroll
        for (int mi = 0; mi < MI; ++mi) {
            int rbase = m0 + wm * MI * 16 + mi * 16 + (lane >> 4) * 4;
            #pragma unroll
            for (int ni = 0; ni < NI; ++ni) {
                int c = n0 + wn * NI * 16 + ni * 16 + lr;
                #pragma unroll
                for (int r = 0; r < 4; ++r)
                    psum[((size_t)blockIdx.z * MPAD + rbase + r) * N + c] = f2b(acc[mi][ni][r]);
            }
        }
        return;
    }
    if (flags & 64) {
        if constexpr (NI == 4 && BN == 128) {
            int selB = n0 / DDIM;      // 768 % 128 == 0: block lies wholly in q, k, or v
            if (selB == 2) {
                // V block: bounce through LDS (reuse As) for coalesced transposed writes.
                ushortT* vtile = &As[0][0];
                #pragma unroll
                for (int mi = 0; mi < MI; ++mi) {
                    #pragma unroll
                    for (int ni = 0; ni < NI; ++ni) {
                        #pragma unroll
                        for (int r = 0; r < 4; ++r) {
                            int ll = wm * MI * 16 + mi * 16 + (lane >> 4) * 4 + r;
                            int dl = wn * 64 + ni * 16 + lr;
                            vtile[dl * BM + (ll ^ ((dl & 7) << 4))] = f2b(acc[mi][ni][r]);
                        }
                    }
                }
                __syncthreads();
                for (int e = tid; e < 128 * BM; e += THREADS) {
                    int dl = e / BM, ll = e - dl * BM;
                    int row = m0 + ll;
                    if (row < MROWS) {
                        int b = row / NL, l = row - b * NL;
                        int cv = (n0 - 2 * DDIM) + dl;
                        int h = cv >> 6, d = cv & 63;
                        int bh = b * NHEAD + h;
                        vo[((long)bh * HDIM + d) * LPAD + l] = vtile[dl * BM + (ll ^ ((dl & 7) << 4))];
                    }
                }
            } else {
                #pragma unroll
                for (int mi = 0; mi < MI; ++mi) {
                    #pragma unroll
                    for (int r = 0; r < 4; ++r) {
                        int row = m0 + wm * MI * 16 + mi * 16 + (lane >> 4) * 4 + r;
                        if (row >= MROWS) continue;
                        int b = row / NL, l = row - b * NL;
                        #pragma unroll
                        for (int ni = 0; ni < NI; ++ni) {
                            int c = n0 + wn * 64 + ni * 16 + lr;
                            float val = acc[mi][ni][r];
                            int sel = c / DDIM;
                            int cc = c - sel * DDIM;
                            int h = cc >> 6, d = cc & 63;
                            if (l > 0) {
                                int pos = l - 1;
                                float cs = cosT[pos * 64 + d], sn = sinT[pos * 64 + d];
                                float partner = acc[mi][ni ^ 2][r];
                                float rh = (d < 32) ? -partner : partner;
                                val = val * cs + rh * sn;
                            }
                            int bh = b * NHEAD + h;
                            if (sel == 0) qo[((long)bh * LPAD + l) * HDIM + d] = f2b(val * 0.125f);
                            else          ko[((long)bh * LPAD + l) * HDIM + d] = f2b(val);
                        }
                    }
                }
            }
        }
        return;
    }
    #pragma unroll
    for (int mi = 0; mi < MI; ++mi) {
        int rbase = m0 + wm * MI * 16 + mi * 16 + (lane >> 4) * 4;
        #pragma unroll
        for (int ni = 0; ni < NI; ++ni) {
            int c = n0 + wn * NI * 16 + ni * 16 + lr;
            float bv = (flags & 1) ? bias[c] : 0.f;
            #pragma unroll
            for (int r = 0; r < 4; ++r) {
                int row = rbase + r;
                float val = acc[mi][ni][r] + bv;
                if (flags & 4) val = 0.5f * val * (1.f + erff(val * 0.70710678118654752f));
                long orow = row;
                if (flags & 8) orow = (long)(row / NL0) * NL + 1 + (row % NL0);
                if (flags & 2) val += resid[orow * (long)N + c];
                if (flags & 16) Cf[orow * (long)N + c] = val;
                if (flags & 32) Cb[orow * (long)N + c] = f2b(val);
            }
        }
    }
}

// ---------------- MFMA flash attention: 8 waves, 4 q-tiles (256 rows) per block ----------------
// waves 0-3 own q-tiles {0,1}, waves 4-7 own {2,3}; K staged by waves 0-3, V by 4-7.
// blocks [0, 96*QT3): attention; [96*QT3, +NCONV): convert next layer's weights.
__global__ __launch_bounds__(512) void fattn_k(const ushortT* __restrict__ q,
                                               const ushortT* __restrict__ k,
                                               const ushortT* __restrict__ vt,
                                               ushortT* __restrict__ o,
                                               const float* __restrict__ wa, ushortT* __restrict__ wao, long na,
                                               const float* __restrict__ wb, ushortT* __restrict__ wbo, long nbn,
                                               const float* __restrict__ wc, ushortT* __restrict__ wco, long nc,
                                               const float* __restrict__ wd, ushortT* __restrict__ wdo, long nd) {
    if (blockIdx.x >= 96 * QT3) {
        int cid = blockIdx.x - 96 * QT3;
        long stride = (long)NCONV * 2048;
        long i0 = ((long)cid * 512 + threadIdx.x) * 4;
        for (long i = i0; i < na; i += stride) {
            float4 v = *(const float4*)(wa + i);
            ushort4 t4; t4.x = f2b(v.x); t4.y = f2b(v.y); t4.z = f2b(v.z); t4.w = f2b(v.w);
            *(ushort4*)(wao + i) = t4;
        }
        for (long i = i0; i < nbn; i += stride) {
            float4 v = *(const float4*)(wb + i);
            ushort4 t4; t4.x = f2b(v.x); t4.y = f2b(v.y); t4.z = f2b(v.z); t4.w = f2b(v.w);
            *(ushort4*)(wbo + i) = t4;
        }
        for (long i = i0; i < nc; i += stride) {
            float4 v = *(const float4*)(wc + i);
            ushort4 t4; t4.x = f2b(v.x); t4.y = f2b(v.y); t4.z = f2b(v.z); t4.w = f2b(v.w);
            *(ushort4*)(wco + i) = t4;
        }
        for (long i = i0; i < nd; i += stride) {
            float4 v = *(const float4*)(wd + i);
            ushort4 t4; t4.x = f2b(v.x); t4.y = f2b(v.y); t4.z = f2b(v.z); t4.w = f2b(v.w);
            *(ushort4*)(wdo + i) = t4;
        }
        return;
    }
    __shared__ ushortT Qs[4][4096], Ks[4096], Vs[4096];
    __shared__ ushortT Ps[8192];                       // 8 waves x 2048 B
    int tid = threadIdx.x;
    int wave = tid >> 6, lane = tid & 63;
    int g2 = wave >> 2, wavein = wave & 3;
    int lr = lane & 15, lk = lane >> 4, g = lk;
    int bh = blockIdx.x / QT3, qp = blockIdx.x % QT3;
    int q0 = qp * 256;
    int b = bh / NHEAD, h = bh - b * NHEAD;
    int l8 = lane >> 3, c16 = lane & 7;
    int colsw = (c16 * 16) ^ ((l8 & 7) << 4);

    // stage this wave-group's two 64-row Q tiles (skip tiles beyond LPAD)
    #pragma unroll
    for (int qs = 0; qs < 2; ++qs) {
        int tileq = g2 * 2 + qs;
        int start = q0 + tileq * 64;
        if (start < LPAD) {
            const ushortT* src = q + ((long)bh * LPAD + start) * HDIM;
            #pragma unroll
            for (int j = 0; j < 2; ++j) {
                int row = wavein * 16 + j * 8 + l8;
                load_lds16(src + (long)row * HDIM + (colsw >> 1), Qs[tileq] + wavein * 1024 + j * 512);
            }
        }
    }
    __syncthreads();
    bf16x8 qF[2][2];
    #pragma unroll
    for (int qs = 0; qs < 2; ++qs)
        #pragma unroll
        for (int ks = 0; ks < 2; ++ks) {
            int row = wavein * 16 + lr;
            qF[qs][ks] = *(const bf16x8*)((const char*)Qs[g2 * 2 + qs] + row * 128 +
                                          ((ks * 64 + lk * 16) ^ ((lr & 7) << 4)));
        }
    f32x4 oa[2][4] = {};
    float m_r[2][4], l_r[2][4];
    #pragma unroll
    for (int qs = 0; qs < 2; ++qs)
        #pragma unroll
        for (int r = 0; r < 4; ++r) { m_r[qs][r] = -3e38f; l_r[qs][r] = 0.f; }

    for (int t0 = 0; t0 < 10; ++t0) {
        int k0 = t0 * 64;
        __syncthreads();
        {
            #pragma unroll
            for (int j = 0; j < 2; ++j) {
                int row = wavein * 16 + j * 8 + l8;
                if (g2 == 0) {
                    const ushortT* srck = k + ((long)bh * LPAD + k0) * HDIM;
                    load_lds16(srck + (long)row * HDIM + (colsw >> 1), Ks + wavein * 1024 + j * 512);
                } else {
                    const ushortT* srcv = vt + (long)bh * HDIM * LPAD + k0;
                    load_lds16(srcv + (long)row * LPAD + (colsw >> 1), Vs + wavein * 1024 + j * 512);
                }
            }
        }
        __syncthreads();
        #pragma unroll
        for (int qs = 0; qs < 2; ++qs) {
            int start = q0 + (g2 * 2 + qs) * 64;
            if (start > 576) continue;          // uniform per (block, wave-group, qs)
            f32x4 s[4] = {};
            #pragma unroll
            for (int ks = 0; ks < 2; ++ks) {
                #pragma unroll
                for (int kt = 0; kt < 4; ++kt) {
                    int row = kt * 16 + lr;
                    bf16x8 kF = *(const bf16x8*)((const char*)Ks + row * 128 +
                                                 ((ks * 64 + lk * 16) ^ ((lr & 7) << 4)));
                    s[kt] = __builtin_amdgcn_mfma_f32_16x16x32_bf16(qF[qs][ks], kF, s[kt], 0, 0, 0);
                }
            }
            if (k0 + 63 > 576) {
                #pragma unroll
                for (int kt = 0; kt < 4; ++kt)
                    if (k0 + kt * 16 + lr > 576) {
                        #pragma unroll
                        for (int r = 0; r < 4; ++r) s[kt][r] = -3e38f;
                    }
            }
            float mx[4], al[4], rs[4];
            #pragma unroll
            for (int r = 0; r < 4; ++r)
                mx[r] = fmaxf(fmaxf(s[0][r], s[1][r]), fmaxf(s[2][r], s[3][r]));
            #pragma unroll
            for (int off = 1; off < 16; off <<= 1) {
                #pragma unroll
                for (int r = 0; r < 4; ++r) mx[r] = fmaxf(mx[r], __shfl_xor(mx[r], off));
            }
            #pragma unroll
            for (int r = 0; r < 4; ++r) {
                float mn = fmaxf(m_r[qs][r], mx[r]);
                al[r] = __expf(m_r[qs][r] - mn);
                m_r[qs][r] = mn;
                rs[r] = 0.f;
            }
            #pragma unroll
            for (int kt = 0; kt < 4; ++kt) {
                #pragma unroll
                for (int r = 0; r < 4; ++r) {
                    float p = __expf(s[kt][r] - m_r[qs][r]);
                    rs[r] += p;
                    int rowp = g * 4 + r;
                    *(ushortT*)((char*)Ps + wave * 2048 + rowp * 128 +
                                ((kt * 32 + lr * 2) ^ ((rowp & 7) << 4))) = f2b(p);
                }
            }
            #pragma unroll
            for (int off = 1; off < 16; off <<= 1) {
                #pragma unroll
                for (int r = 0; r < 4; ++r) rs[r] += __shfl_xor(rs[r], off);
            }
            #pragma unroll
            for (int r = 0; r < 4; ++r) l_r[qs][r] = l_r[qs][r] * al[r] + rs[r];
            #pragma unroll
            for (int dt = 0; dt < 4; ++dt) {
                #pragma unroll
                for (int r = 0; r < 4; ++r) oa[qs][dt][r] *= al[r];
            }
            // own-wave P write -> read: compiler inserts lgkmcnt wait
            #pragma unroll
            for (int ks = 0; ks < 2; ++ks) {
                bf16x8 pA = *(const bf16x8*)((const char*)Ps + wave * 2048 + lr * 128 +
                                             ((ks * 64 + lk * 16) ^ ((lr & 7) << 4)));
                #pragma unroll
                for (int dt = 0; dt < 4; ++dt) {
                    bf16x8 vF = *(const bf16x8*)((const char*)Vs + (dt * 16 + lr) * 128 +
                                                 ((ks * 64 + lk * 16) ^ ((lr & 7) << 4)));
                    oa[qs][dt] = __builtin_amdgcn_mfma_f32_16x16x32_bf16(pA, vF, oa[qs][dt], 0, 0, 0);
                }
            }
        }
    }
    #pragma unroll
    for (int qs = 0; qs < 2; ++qs) {
        #pragma unroll
        for (int r = 0; r < 4; ++r) {
            int l = q0 + (g2 * 2 + qs) * 64 + wavein * 16 + g * 4 + r;
            if (l > 576) continue;
            float inv = 1.f / l_r[qs][r];
            #pragma unroll
            for (int dt = 0; dt < 4; ++dt)
                o[((long)(b * NL + l)) * DDIM + h * HDIM + dt * 16 + lr] = f2b(oa[qs][dt][r] * inv);
        }
    }
}

extern "C" void kernel_launch(void* const* d_in, const int* in_sizes, int n_in,
                              void* d_out, int out_size, void* d_ws, size_t ws_size,
                              hipStream_t stream) {
    const float* x       = (const float*)d_in[0];
    const float* patch_w = (const float*)d_in[1];
    const float* patch_b = (const float*)d_in[2];
    const float* cls     = (const float*)d_in[3];
    const float* ln1_s   = (const float*)d_in[4];
    const float* ln1_b   = (const float*)d_in[5];
    const float* qkv_w   = (const float*)d_in[6];
    const float* proj_w  = (const float*)d_in[7];
    const float* proj_b  = (const float*)d_in[8];
    const float* ln2_s   = (const float*)d_in[9];
    const float* ln2_b   = (const float*)d_in[10];
    const float* mlp_w1  = (const float*)d_in[11];
    const float* mlp_b1  = (const float*)d_in[12];
    const float* mlp_w2  = (const float*)d_in[13];
    const float* mlp_b2  = (const float*)d_in[14];
    const float* norm_s  = (const float*)d_in[15];
    const float* norm_b  = (const float*)d_in[16];

    const size_t SZ_WQ = (size_t)3 * DDIM * DDIM;
    const size_t SZ_WP = (size_t)DDIM * DDIM;
    const size_t SZ_W1 = (size_t)NHID * DDIM;
    const size_t SZ_W2 = (size_t)DDIM * NHID;

    char* w = (char*)d_ws;
    float* t      = (float*)w;  w += (size_t)MPAD * DDIM * 4;
    float* sin_t  = (float*)w;  w += (size_t)NL0 * HDIM * 4;
    float* cos_t  = (float*)w;  w += (size_t)NL0 * HDIM * 4;
    ushortT* psum = (ushortT*)w; w += (size_t)4 * MPAD * DDIM * 2;   // bf16 partials
    ushortT* h_bf   = (ushortT*)w; w += (size_t)MPAD * DDIM * 2;
    ushortT* o_bf   = (ushortT*)w; w += (size_t)MPAD * DDIM * 2;
    ushortT* mlp_bf = (ushortT*)w; w += (size_t)MPAD * NHID * 2;
    ushortT* patches = mlp_bf;    // alias: disjoint lifetime (pre-loop only)
    ushortT* q_bf   = (ushortT*)w; w += (size_t)96 * LPAD * HDIM * 2;
    ushortT* k_bf   = (ushortT*)w; w += (size_t)96 * LPAD * HDIM * 2;
    ushortT* v_t    = (ushortT*)w; w += (size_t)96 * HDIM * LPAD * 2;
    ushortT* pw_bf  = (ushortT*)w; w += (size_t)DDIM * 768 * 2;
    // double-buffered per-layer weight sets
    ushortT* wqB[2]; ushortT* wpB[2]; ushortT* w1B[2]; ushortT* w2B[2];
    for (int s = 0; s < 2; ++s) {
        wqB[s] = (ushortT*)w; w += SZ_WQ * 2;
        wpB[s] = (ushortT*)w; w += SZ_WP * 2;
        w1B[s] = (ushortT*)w; w += SZ_W1 * 2;
        w2B[s] = (ushortT*)w; w += SZ_W2 * 2;
    }

    const float* nfp = nullptr;
    ushortT* nus = nullptr;
    float* nf = nullptr;

    hipLaunchKernelGGL(rope_k, dim3(NL0), dim3(64), 0, stream, sin_t, cos_t);
    hipLaunchKernelGGL(im2col_k, dim3(2048), dim3(256), 0, stream, x, patches);
    hipLaunchKernelGGL(f2b_k, dim3(512), dim3(256), 0, stream, patch_w, pw_bf, (long)DDIM * 768);
    hipLaunchKernelGGL(cls_k, dim3(NB), dim3(DDIM), 0, stream, cls, t);
    // layer-0 weights
    hipLaunchKernelGGL(wconv4_k, dim3(1024), dim3(256), 0, stream,
                       qkv_w, wqB[0], (long)SZ_WQ,
                       proj_w, wpB[0], (long)SZ_WP,
                       mlp_w1, w1B[0], (long)SZ_W1,
                       mlp_w2, w2B[0], (long)SZ_W2);
    // patch embed: 64x128 tile, 8 waves, grid 6x72
    hipLaunchKernelGGL((gemm_t<2, 4, 2, 2, 1, 8>), dim3(DDIM / 128, 4608 / 64), dim3(512), 0, stream,
                       patches, pw_bf, patch_b, nfp, t, nus, nfp, nfp, nus, nus, nus, nus,
                       DDIM, 768, 1 | 8 | 16);

    for (int i = 0; i < NDEPTH; ++i) {
        int cur = i & 1, nxt = (i + 1) & 1;
        if (i == 0) {
            hipLaunchKernelGGL(ln_k, dim3(MROWS), dim3(256), 0, stream,
                               t, ln1_s, ln1_b, nf, h_bf, (long)DDIM);
        } else {
            hipLaunchKernelGGL(red_ln_k, dim3(MROWS), dim3(256), 0, stream,
                               psum, mlp_b2 + (i - 1) * DDIM, t,
                               ln1_s + i * DDIM, ln1_b + i * DDIM, h_bf);
        }
        // QKV GEMM (128x128, 8 waves) with fused RoPE + scatter (coalesced V via LDS bounce)
        hipLaunchKernelGGL((gemm_t<4, 2, 2, 4, 1, 8>), dim3((3 * DDIM) / 128, MPAD / 128), dim3(512), 0, stream,
                           h_bf, wqB[cur], nfp, nfp, nf, nus, sin_t, cos_t,
                           q_bf, k_bf, v_t, nus, 3 * DDIM, DDIM, 64);
        // attention (4 q-tiles/block, 8 waves) + fused next-layer weight conversion
        long cn = (i + 1 < NDEPTH) ? 1 : 0;
        hipLaunchKernelGGL(fattn_k, dim3(96 * QT3 + NCONV), dim3(512), 0, stream,
                           q_bf, k_bf, v_t, o_bf,
                           qkv_w + SZ_WQ * (i + 1), wqB[nxt], cn * (long)SZ_WQ,
                           proj_w + SZ_WP * (i + 1), wpB[nxt], cn * (long)SZ_WP,
                           mlp_w1 + SZ_W1 * (i + 1), w1B[nxt], cn * (long)SZ_W1,
                           mlp_w2 + SZ_W2 * (i + 1), w2B[nxt], cn * (long)SZ_W2);
        // proj: 64x128 tile, 8 waves, grid 6x74
        hipLaunchKernelGGL((gemm_t<2, 4, 2, 2, 1, 8>), dim3(DDIM / 128, MPAD / 64), dim3(512), 0, stream,
                           o_bf, wpB[cur], proj_b + i * DDIM, t, t, nus, nfp, nfp, nus, nus, nus, nus,
                           DDIM, DDIM, 1 | 2 | 16);
        hipLaunchKernelGGL(ln_k, dim3(MROWS), dim3(256), 0, stream,
                           t, ln2_s + i * DDIM, ln2_b + i * DDIM, nf, h_bf, (long)DDIM);
        // mlp1: 128x128, 8 waves
        hipLaunchKernelGGL((gemm_t<4, 2, 2, 4, 1, 8>), dim3(NHID / 128, MPAD / 128), dim3(512), 0, stream,
                           h_bf, w1B[cur], mlp_b1 + i * NHID, nfp, nf, mlp_bf, nfp, nfp,
                           nus, nus, nus, nus, NHID, DDIM, 1 | 4 | 32);
        // mlp2: split-K 4 bf16 partials, 128x128, 8 waves
        hipLaunchKernelGGL((gemm_t<4, 2, 2, 4, 4, 8>), dim3(DDIM / 128, MPAD / 128, 4), dim3(512), 0, stream,
                           mlp_bf, w2B[cur], nfp, nfp, nf, nus, nfp, nfp,
                           nus, nus, nus, psum, DDIM, NHID, 0);
    }
    // final: reduce CLS rows + final LN -> d_out
    hipLaunchKernelGGL(red_final_k, dim3(NB), dim3(256), 0, stream,
                       psum, mlp_b2 + (NDEPTH - 1) * DDIM, t, norm_s, norm_b, (float*)d_out);
}

// Round 15
// 2296.697 us; speedup vs baseline: 1.1080x; 1.1080x over previous
//
#include <hip/hip_runtime.h>
#include <math.h>

#define NB 8
#define DDIM 768
#define NHEAD 12
#define NDEPTH 12
#define HDIM 64
#define GRIDW 24
#define NL0 576
#define NL 577
#define LPAD 640
#define NHID 3072
#define MROWS (NB*NL)     // 4616
#define MPAD 4736         // 37*128, 74*64
#define EPSV 1e-5f
#define QT2 5             // q-tile PAIRS per head (2x64 rows each)
#define NCONV 512

typedef unsigned short ushortT;
typedef __attribute__((ext_vector_type(8))) short bf16x8;
typedef __attribute__((ext_vector_type(4))) float f32x4;

__device__ __forceinline__ ushortT f2b(float f) {
    union { float f; unsigned u; } x; x.f = f;
    unsigned r = x.u + 0x7fffu + ((x.u >> 16) & 1u);
    return (ushortT)(r >> 16);
}

__device__ __forceinline__ float b2f(ushortT u) {
    union { unsigned u; float f; } x; x.u = ((unsigned)u) << 16;
    return x.f;
}

__device__ __forceinline__ void load_lds16(const void* g, void* l) {
    __builtin_amdgcn_global_load_lds((const __attribute__((address_space(1))) void*)g,
                                     (__attribute__((address_space(3))) void*)l, 16, 0, 0);
}

// ---------------- fp32 -> bf16 convert ----------------
__global__ void f2b_k(const float* __restrict__ in, ushortT* __restrict__ out, long n) {
    for (long i = ((long)blockIdx.x * 256 + threadIdx.x) * 4; i < n; i += (long)gridDim.x * 1024) {
        float4 v = *(const float4*)(in + i);
        ushort4 o; o.x = f2b(v.x); o.y = f2b(v.y); o.z = f2b(v.z); o.w = f2b(v.w);
        *(ushort4*)(out + i) = o;
    }
}

// ---------------- 4-array convert (preamble: layer-0 weights) ----------------
__global__ void wconv4_k(const float* __restrict__ a, ushortT* __restrict__ ao, long na,
                         const float* __restrict__ b, ushortT* __restrict__ bo, long nb,
                         const float* __restrict__ c, ushortT* __restrict__ co, long nc,
                         const float* __restrict__ d, ushortT* __restrict__ dd, long nd) {
    long stride = (long)gridDim.x * 1024;
    long i0 = ((long)blockIdx.x * 256 + threadIdx.x) * 4;
    for (long i = i0; i < na; i += stride) {
        float4 v = *(const float4*)(a + i);
        ushort4 o; o.x = f2b(v.x); o.y = f2b(v.y); o.z = f2b(v.z); o.w = f2b(v.w);
        *(ushort4*)(ao + i) = o;
    }
    for (long i = i0; i < nb; i += stride) {
        float4 v = *(const float4*)(b + i);
        ushort4 o; o.x = f2b(v.x); o.y = f2b(v.y); o.z = f2b(v.z); o.w = f2b(v.w);
        *(ushort4*)(bo + i) = o;
    }
    for (long i = i0; i < nc; i += stride) {
        float4 v = *(const float4*)(c + i);
        ushort4 o; o.x = f2b(v.x); o.y = f2b(v.y); o.z = f2b(v.z); o.w = f2b(v.w);
        *(ushort4*)(co + i) = o;
    }
    for (long i = i0; i < nd; i += stride) {
        float4 v = *(const float4*)(d + i);
        ushort4 o; o.x = f2b(v.x); o.y = f2b(v.y); o.z = f2b(v.z); o.w = f2b(v.w);
        *(ushort4*)(dd + i) = o;
    }
}

// ---------------- im2col -> bf16 patches[4608, 768] ----------------
__global__ void im2col_k(const float* __restrict__ x, ushortT* __restrict__ p) {
    for (long idx = (long)blockIdx.x * 256 + threadIdx.x; idx < (long)4608 * 768; idx += (long)gridDim.x * 256) {
        int row = (int)(idx / 768), col = (int)(idx - (long)row * 768);
        int b = row / NL0, pi = row - b * NL0;
        int gy = pi / GRIDW, gx = pi - gy * GRIDW;
        int c = col >> 8, r = col & 255;
        int py = r >> 4, px = r & 15;
        p[idx] = f2b(x[(((long)(b * 3 + c) * 384) + gy * 16 + py) * 384 + gx * 16 + px]);
    }
}

__global__ void cls_k(const float* __restrict__ cls, float* __restrict__ t) {
    t[(long)blockIdx.x * NL * DDIM + threadIdx.x] = cls[threadIdx.x];
}

__global__ void rope_k(float* __restrict__ sin_t, float* __restrict__ cos_t) {
    int pos = blockIdx.x, d = threadIdx.x;
    int gy = pos / GRIDW, gx = pos - gy * GRIDW;
    int j = d >> 1;
    float ang;
    if (j < 16) ang = (float)gy * powf(10000.f, -(float)j / 16.f);
    else        ang = (float)gx * powf(10000.f, -(float)(j - 16) / 16.f);
    sin_t[pos * 64 + d] = sinf(ang);
    cos_t[pos * 64 + d] = cosf(ang);
}

// ---------------- LayerNorm (plain; layer-0 ln1 and all ln2) ----------------
__global__ __launch_bounds__(256) void ln_k(const float* __restrict__ in,
                                            const float* __restrict__ sc,
                                            const float* __restrict__ bi,
                                            float* __restrict__ outf,
                                            ushortT* __restrict__ outb,
                                            long in_rstride) {
    int row = blockIdx.x;
    const float* ip = in + (long)row * in_rstride;
    float x[3];
    float s = 0.f, s2 = 0.f;
    #pragma unroll
    for (int i = 0; i < 3; ++i) {
        x[i] = ip[threadIdx.x + i * 256];
        s += x[i]; s2 += x[i] * x[i];
    }
    __shared__ float red0[256], red1[256];
    red0[threadIdx.x] = s; red1[threadIdx.x] = s2;
    __syncthreads();
    for (int off = 128; off; off >>= 1) {
        if (threadIdx.x < off) {
            red0[threadIdx.x] += red0[threadIdx.x + off];
            red1[threadIdx.x] += red1[threadIdx.x + off];
        }
        __syncthreads();
    }
    float mean = red0[0] * (1.f / 768.f);
    float var  = red1[0] * (1.f / 768.f) - mean * mean;
    float inv = rsqrtf(var + EPSV);
    #pragma unroll
    for (int i = 0; i < 3; ++i) {
        int c = threadIdx.x + i * 256;
        float val = (x[i] - mean) * inv * sc[c] + bi[c];
        if (outb) outb[(long)row * 768 + c] = f2b(val);
        else      outf[(long)row * 768 + c] = val;
    }
}

// ---------------- fused: t += mlp2_bias + sum2(bf16 psum); then LN1(next layer) -> h_bf ----------------
__global__ __launch_bounds__(256) void red_ln_k(const ushortT* __restrict__ psum,
                                                const float* __restrict__ b2,
                                                float* __restrict__ t,
                                                const float* __restrict__ sc,
                                                const float* __restrict__ bi,
                                                ushortT* __restrict__ outb) {
    int row = blockIdx.x;
    const size_t S = (size_t)MPAD * DDIM;
    const size_t rb = (size_t)row * DDIM;
    float x[3];
    float s = 0.f, s2 = 0.f;
    #pragma unroll
    for (int i = 0; i < 3; ++i) {
        int c = threadIdx.x + i * 256;
        float v = t[rb + c] + b2[c] + b2f(psum[rb + c]) + b2f(psum[S + rb + c]);
        x[i] = v; s += v; s2 += v * v;
        t[rb + c] = v;
    }
    __shared__ float red0[256], red1[256];
    red0[threadIdx.x] = s; red1[threadIdx.x] = s2;
    __syncthreads();
    for (int off = 128; off; off >>= 1) {
        if (threadIdx.x < off) {
            red0[threadIdx.x] += red0[threadIdx.x + off];
            red1[threadIdx.x] += red1[threadIdx.x + off];
        }
        __syncthreads();
    }
    float mean = red0[0] * (1.f / 768.f);
    float var  = red1[0] * (1.f / 768.f) - mean * mean;
    float inv = rsqrtf(var + EPSV);
    #pragma unroll
    for (int i = 0; i < 3; ++i) {
        int c = threadIdx.x + i * 256;
        outb[rb + c] = f2b((x[i] - mean) * inv * sc[c] + bi[c]);
    }
}

// ---------------- final: reduce CLS rows only + final LN -> d_out[8,768] f32 ----------------
__global__ __launch_bounds__(256) void red_final_k(const ushortT* __restrict__ psum,
                                                   const float* __restrict__ b2,
                                                   const float* __restrict__ t,
                                                   const float* __restrict__ sc,
                                                   const float* __restrict__ bi,
                                                   float* __restrict__ outf) {
    int row = blockIdx.x * NL;            // CLS row of batch blockIdx.x
    const size_t S = (size_t)MPAD * DDIM;
    const size_t rb = (size_t)row * DDIM;
    float x[3];
    float s = 0.f, s2 = 0.f;
    #pragma unroll
    for (int i = 0; i < 3; ++i) {
        int c = threadIdx.x + i * 256;
        float v = t[rb + c] + b2[c] + b2f(psum[rb + c]) + b2f(psum[S + rb + c]);
        x[i] = v; s += v; s2 += v * v;
    }
    __shared__ float red0[256], red1[256];
    red0[threadIdx.x] = s; red1[threadIdx.x] = s2;
    __syncthreads();
    for (int off = 128; off; off >>= 1) {
        if (threadIdx.x < off) {
            red0[threadIdx.x] += red0[threadIdx.x + off];
            red1[threadIdx.x] += red1[threadIdx.x + off];
        }
        __syncthreads();
    }
    float mean = red0[0] * (1.f / 768.f);
    float var  = red1[0] * (1.f / 768.f) - mean * mean;
    float inv = rsqrtf(var + EPSV);
    #pragma unroll
    for (int i = 0; i < 3; ++i) {
        int c = threadIdx.x + i * 256;
        outf[(long)blockIdx.x * 768 + c] = (x[i] - mean) * inv * sc[c] + bi[c];
    }
}

// ---------------- templated bf16 MFMA GEMM (2-stage dbuf, NW waves) ----------------
// NW*64 threads. 2-stage double-buffered LDS; stage(t+1) issued BEFORE compute(t);
// one vmcnt(0)+s_barrier per K-step. T2 XOR swizzle; T1 XCD chunking.
// NOTE (r12 lesson): 2 blocks/CU for cross-block drain coverage beats bigger
// wave-tiles at 1 block/CU — keep LDS <= 64KB for these shapes.
// flags: 1=bias 2=resid(f32) 4=gelu 8=remap(576->577) 16=store f32 32=store bf16
//        64=qkv mode (RoPE + scale + scatter; requires NI==4; BN==128)
// SPLITK>1: blockIdx.z selects K-chunk; acc -> psum[z][MPAD][N] as bf16.
template<int WR, int WC, int MI, int NI, int SPLITK, int NW>
__global__ __launch_bounds__(NW * 64) void gemm_t(const ushortT* __restrict__ A,
                                                  const ushortT* __restrict__ W,
                                                  const float* __restrict__ bias,
                                                  const float* __restrict__ resid,
                                                  float* __restrict__ Cf,
                                                  ushortT* __restrict__ Cb,
                                                  const float* __restrict__ sinT,
                                                  const float* __restrict__ cosT,
                                                  ushortT* __restrict__ qo,
                                                  ushortT* __restrict__ ko,
                                                  ushortT* __restrict__ vo,
                                                  ushortT* __restrict__ psum,
                                                  int N, int K, int flags) {
    constexpr int BM = WR * MI * 16;
    constexpr int BN = WC * NI * 16;
    constexpr int THREADS = NW * 64;
    constexpr int ACH = (BM * 64) / (THREADS * 8);
    constexpr int BCH = (BN * 64) / (THREADS * 8);
    __shared__ ushortT As[2][BM * 64];
    __shared__ ushortT Bs[2][BN * 64];
    int tid = threadIdx.x;
    int lane = tid & 63, wid = tid >> 6;
    int wm = wid / WC, wn = wid % WC;
    int lr = lane & 15, lk = lane >> 4;
    int nwg = gridDim.x * gridDim.y;
    int flat = blockIdx.y * gridDim.x + blockIdx.x;
    int qq = nwg >> 3, rr = nwg & 7;
    int xcd = flat & 7, idx = flat >> 3;
    int wg = (xcd < rr ? xcd * (qq + 1) : rr * (qq + 1) + (xcd - rr) * qq) + idx;
    int bx = wg % gridDim.x, by = wg / gridDim.x;
    int m0 = by * BM, n0 = bx * BN;
    int kspan = K / SPLITK;
    int k0 = (SPLITK > 1) ? blockIdx.z * kspan : 0;
    f32x4 acc[MI][NI] = {};

    auto stage = [&](int buf, int kt) {
        #pragma unroll
        for (int i = 0; i < ACH; ++i) {
            int ch = i * THREADS + tid;
            int r = ch >> 3, cb = (ch & 7) * 16;
            int cbs = cb ^ ((r & 7) << 4);
            load_lds16(A + (size_t)(m0 + r) * K + kt + (cbs >> 1), &As[buf][ch * 8]);
        }
        #pragma unroll
        for (int i = 0; i < BCH; ++i) {
            int ch = i * THREADS + tid;
            int r = ch >> 3, cb = (ch & 7) * 16;
            int cbs = cb ^ ((r & 7) << 4);
            load_lds16(W + (size_t)(n0 + r) * K + kt + (cbs >> 1), &Bs[buf][ch * 8]);
        }
    };

    stage(0, k0);
    asm volatile("s_waitcnt vmcnt(0)" ::: "memory");
    __builtin_amdgcn_s_barrier();
    int nk = kspan / 64;
    int cur = 0;
    for (int it = 0; it < nk; ++it) {
        if (it + 1 < nk) stage(cur ^ 1, k0 + (it + 1) * 64);
        #pragma unroll
        for (int ks = 0; ks < 2; ++ks) {
            bf16x8 aF[MI], bF[NI];
            #pragma unroll
            for (int mi = 0; mi < MI; ++mi) {
                int row = wm * MI * 16 + mi * 16 + lr;
                aF[mi] = *(const bf16x8*)((const char*)&As[cur][0] + row * 128 +
                                          ((ks * 64 + lk * 16) ^ ((row & 7) << 4)));
            }
            #pragma unroll
            for (int ni = 0; ni < NI; ++ni) {
                int row = wn * NI * 16 + ni * 16 + lr;
                bF[ni] = *(const bf16x8*)((const char*)&Bs[cur][0] + row * 128 +
                                          ((ks * 64 + lk * 16) ^ ((row & 7) << 4)));
            }
            #pragma unroll
            for (int mi = 0; mi < MI; ++mi)
                #pragma unroll
                for (int ni = 0; ni < NI; ++ni)
                    acc[mi][ni] = __builtin_amdgcn_mfma_f32_16x16x32_bf16(aF[mi], bF[ni], acc[mi][ni], 0, 0, 0);
        }
        asm volatile("s_waitcnt vmcnt(0)" ::: "memory");
        __builtin_amdgcn_s_barrier();
        cur ^= 1;
    }

    if (SPLITK > 1) {
        #pragma unroll
        for (int mi = 0; mi < MI; ++mi) {
            int rbase = m0 + wm * MI * 16 + mi * 16 + (lane >> 4) * 4;
            #pragma unroll
            for (int ni = 0; ni < NI; ++ni) {
                int c = n0 + wn * NI * 16 + ni * 16 + lr;
                #pragma unroll
                for (int r = 0; r < 4; ++r)
                    psum[((size_t)blockIdx.z * MPAD + rbase + r) * N + c] = f2b(acc[mi][ni][r]);
            }
        }
        return;
    }
    if (flags & 64) {
        if constexpr (NI == 4 && BN == 128) {
            int selB = n0 / DDIM;      // 768 % 128 == 0: block lies wholly in q, k, or v
            if (selB == 2) {
                // V block: bounce through LDS (reuse As) for coalesced transposed writes.
                ushortT* vtile = &As[0][0];
                #pragma unroll
                for (int mi = 0; mi < MI; ++mi) {
                    #pragma unroll
                    for (int ni = 0; ni < NI; ++ni) {
                        #pragma unroll
                        for (int r = 0; r < 4; ++r) {
                            int ll = wm * MI * 16 + mi * 16 + (lane >> 4) * 4 + r;
                            int dl = wn * 64 + ni * 16 + lr;
                            vtile[dl * BM + (ll ^ ((dl & 7) << 4))] = f2b(acc[mi][ni][r]);
                        }
                    }
                }
                __syncthreads();
                for (int e = tid; e < 128 * BM; e += THREADS) {
                    int dl = e / BM, ll = e - dl * BM;
                    int row = m0 + ll;
                    if (row < MROWS) {
                        int b = row / NL, l = row - b * NL;
                        int cv = (n0 - 2 * DDIM) + dl;
                        int h = cv >> 6, d = cv & 63;
                        int bh = b * NHEAD + h;
                        vo[((long)bh * HDIM + d) * LPAD + l] = vtile[dl * BM + (ll ^ ((dl & 7) << 4))];
                    }
                }
            } else {
                #pragma unroll
                for (int mi = 0; mi < MI; ++mi) {
                    #pragma unroll
                    for (int r = 0; r < 4; ++r) {
                        int row = m0 + wm * MI * 16 + mi * 16 + (lane >> 4) * 4 + r;
                        if (row >= MROWS) continue;
                        int b = row / NL, l = row - b * NL;
                        #pragma unroll
                        for (int ni = 0; ni < NI; ++ni) {
                            int c = n0 + wn * 64 + ni * 16 + lr;
                            float val = acc[mi][ni][r];
                            int sel = c / DDIM;
                            int cc = c - sel * DDIM;
                            int h = cc >> 6, d = cc & 63;
                            if (l > 0) {
                                int pos = l - 1;
                                float cs = cosT[pos * 64 + d], sn = sinT[pos * 64 + d];
                                float partner = acc[mi][ni ^ 2][r];
                                float rh = (d < 32) ? -partner : partner;
                                val = val * cs + rh * sn;
                            }
                            int bh = b * NHEAD + h;
                            if (sel == 0) qo[((long)bh * LPAD + l) * HDIM + d] = f2b(val * 0.125f);
                            else          ko[((long)bh * LPAD + l) * HDIM + d] = f2b(val);
                        }
                    }
                }
            }
        }
        return;
    }
    #pragma unroll
    for (int mi = 0; mi < MI; ++mi) {
        int rbase = m0 + wm * MI * 16 + mi * 16 + (lane >> 4) * 4;
        #pragma unroll
        for (int ni = 0; ni < NI; ++ni) {
            int c = n0 + wn * NI * 16 + ni * 16 + lr;
            float bv = (flags & 1) ? bias[c] : 0.f;
            #pragma unroll
            for (int r = 0; r < 4; ++r) {
                int row = rbase + r;
                float val = acc[mi][ni][r] + bv;
                if (flags & 4) val = 0.5f * val * (1.f + erff(val * 0.70710678118654752f));
                long orow = row;
                if (flags & 8) orow = (long)(row / NL0) * NL + 1 + (row % NL0);
                if (flags & 2) val += resid[orow * (long)N + c];
                if (flags & 16) Cf[orow * (long)N + c] = val;
                if (flags & 32) Cb[orow * (long)N + c] = f2b(val);
            }
        }
    }
}

// ---------------- MFMA flash attention: 2 q-tiles per block + fused weight conversion ----------------
__global__ __launch_bounds__(256) void fattn_k(const ushortT* __restrict__ q,
                                               const ushortT* __restrict__ k,
                                               const ushortT* __restrict__ vt,
                                               ushortT* __restrict__ o,
                                               const float* __restrict__ wa, ushortT* __restrict__ wao, long na,
                                               const float* __restrict__ wb, ushortT* __restrict__ wbo, long nbn,
                                               const float* __restrict__ wc, ushortT* __restrict__ wco, long nc,
                                               const float* __restrict__ wd, ushortT* __restrict__ wdo, long nd) {
    if (blockIdx.x >= 96 * QT2) {
        int cid = blockIdx.x - 96 * QT2;
        long stride = (long)NCONV * 1024;
        long i0 = ((long)cid * 256 + threadIdx.x) * 4;
        for (long i = i0; i < na; i += stride) {
            float4 v = *(const float4*)(wa + i);
            ushort4 t4; t4.x = f2b(v.x); t4.y = f2b(v.y); t4.z = f2b(v.z); t4.w = f2b(v.w);
            *(ushort4*)(wao + i) = t4;
        }
        for (long i = i0; i < nbn; i += stride) {
            float4 v = *(const float4*)(wb + i);
            ushort4 t4; t4.x = f2b(v.x); t4.y = f2b(v.y); t4.z = f2b(v.z); t4.w = f2b(v.w);
            *(ushort4*)(wbo + i) = t4;
        }
        for (long i = i0; i < nc; i += stride) {
            float4 v = *(const float4*)(wc + i);
            ushort4 t4; t4.x = f2b(v.x); t4.y = f2b(v.y); t4.z = f2b(v.z); t4.w = f2b(v.w);
            *(ushort4*)(wco + i) = t4;
        }
        for (long i = i0; i < nd; i += stride) {
            float4 v = *(const float4*)(wd + i);
            ushort4 t4; t4.x = f2b(v.x); t4.y = f2b(v.y); t4.z = f2b(v.z); t4.w = f2b(v.w);
            *(ushort4*)(wdo + i) = t4;
        }
        return;
    }
    __shared__ ushortT Qs[2][4096], Ks[4096], Vs[4096], Ps[4096];
    int tid = threadIdx.x;
    int wave = tid >> 6, lane = tid & 63;
    int lr = lane & 15, lk = lane >> 4, g = lk;
    int bh = blockIdx.x / QT2, qp = blockIdx.x % QT2;
    int q0 = qp * 128;
    int b = bh / NHEAD, h = bh - b * NHEAD;
    int l8 = lane >> 3, c16 = lane & 7;
    int colsw = (c16 * 16) ^ ((l8 & 7) << 4);

    #pragma unroll
    for (int qs = 0; qs < 2; ++qs) {
        const ushortT* src = q + ((long)bh * LPAD + q0 + qs * 64) * HDIM;
        #pragma unroll
        for (int j = 0; j < 2; ++j) {
            int row = wave * 16 + j * 8 + l8;
            load_lds16(src + (long)row * HDIM + (colsw >> 1), Qs[qs] + wave * 1024 + j * 512);
        }
    }
    __syncthreads();
    bf16x8 qF[2][2];
    #pragma unroll
    for (int qs = 0; qs < 2; ++qs)
        #pragma unroll
        for (int ks = 0; ks < 2; ++ks) {
            int row = wave * 16 + lr;
            qF[qs][ks] = *(const bf16x8*)((const char*)Qs[qs] + row * 128 +
                                          ((ks * 64 + lk * 16) ^ ((lr & 7) << 4)));
        }
    f32x4 oa[2][4] = {};
    float m_r[2][4], l_r[2][4];
    #pragma unroll
    for (int qs = 0; qs < 2; ++qs)
        #pragma unroll
        for (int r = 0; r < 4; ++r) { m_r[qs][r] = -3e38f; l_r[qs][r] = 0.f; }

    for (int t0 = 0; t0 < 10; ++t0) {
        int k0 = t0 * 64;
        __syncthreads();
        {
            const ushortT* srck = k + ((long)bh * LPAD + k0) * HDIM;
            const ushortT* srcv = vt + (long)bh * HDIM * LPAD + k0;
            #pragma unroll
            for (int j = 0; j < 2; ++j) {
                int row = wave * 16 + j * 8 + l8;
                load_lds16(srck + (long)row * HDIM + (colsw >> 1), Ks + wave * 1024 + j * 512);
                load_lds16(srcv + (long)row * LPAD + (colsw >> 1), Vs + wave * 1024 + j * 512);
            }
        }
        __syncthreads();
        #pragma unroll
        for (int qs = 0; qs < 2; ++qs) {
            f32x4 s[4] = {};
            #pragma unroll
            for (int ks = 0; ks < 2; ++ks) {
                #pragma unroll
                for (int kt = 0; kt < 4; ++kt) {
                    int row = kt * 16 + lr;
                    bf16x8 kF = *(const bf16x8*)((const char*)Ks + row * 128 +
                                                 ((ks * 64 + lk * 16) ^ ((lr & 7) << 4)));
                    s[kt] = __builtin_amdgcn_mfma_f32_16x16x32_bf16(qF[qs][ks], kF, s[kt], 0, 0, 0);
                }
            }
            if (k0 + 63 > 576) {
                #pragma unroll
                for (int kt = 0; kt < 4; ++kt)
                    if (k0 + kt * 16 + lr > 576) {
                        #pragma unroll
                        for (int r = 0; r < 4; ++r) s[kt][r] = -3e38f;
                    }
            }
            float mx[4], al[4], rs[4];
            #pragma unroll
            for (int r = 0; r < 4; ++r)
                mx[r] = fmaxf(fmaxf(s[0][r], s[1][r]), fmaxf(s[2][r], s[3][r]));
            #pragma unroll
            for (int off = 1; off < 16; off <<= 1) {
                #pragma unroll
                for (int r = 0; r < 4; ++r) mx[r] = fmaxf(mx[r], __shfl_xor(mx[r], off));
            }
            #pragma unroll
            for (int r = 0; r < 4; ++r) {
                float mn = fmaxf(m_r[qs][r], mx[r]);
                al[r] = __expf(m_r[qs][r] - mn);
                m_r[qs][r] = mn;
                rs[r] = 0.f;
            }
            #pragma unroll
            for (int kt = 0; kt < 4; ++kt) {
                #pragma unroll
                for (int r = 0; r < 4; ++r) {
                    float p = __expf(s[kt][r] - m_r[qs][r]);
                    rs[r] += p;
                    int rowp = g * 4 + r;
                    *(ushortT*)((char*)Ps + wave * 2048 + rowp * 128 +
                                ((kt * 32 + lr * 2) ^ ((rowp & 7) << 4))) = f2b(p);
                }
            }
            #pragma unroll
            for (int off = 1; off < 16; off <<= 1) {
                #pragma unroll
                for (int r = 0; r < 4; ++r) rs[r] += __shfl_xor(rs[r], off);
            }
            #pragma unroll
            for (int r = 0; r < 4; ++r) l_r[qs][r] = l_r[qs][r] * al[r] + rs[r];
            #pragma unroll
            for (int dt = 0; dt < 4; ++dt) {
                #pragma unroll
                for (int r = 0; r < 4; ++r) oa[qs][dt][r] *= al[r];
            }
            #pragma unroll
            for (int ks = 0; ks < 2; ++ks) {
                bf16x8 pA = *(const bf16x8*)((const char*)Ps + wave * 2048 + lr * 128 +
                                             ((ks * 64 + lk * 16) ^ ((lr & 7) << 4)));
                #pragma unroll
                for (int dt = 0; dt < 4; ++dt) {
                    bf16x8 vF = *(const bf16x8*)((const char*)Vs + (dt * 16 + lr) * 128 +
                                                 ((ks * 64 + lk * 16) ^ ((lr & 7) << 4)));
                    oa[qs][dt] = __builtin_amdgcn_mfma_f32_16x16x32_bf16(pA, vF, oa[qs][dt], 0, 0, 0);
                }
            }
        }
    }
    #pragma unroll
    for (int qs = 0; qs < 2; ++qs) {
        #pragma unroll
        for (int r = 0; r < 4; ++r) {
            int l = q0 + qs * 64 + wave * 16 + g * 4 + r;
            if (l > 576) continue;
            float inv = 1.f / l_r[qs][r];
            #pragma unroll
            for (int dt = 0; dt < 4; ++dt)
                o[((long)(b * NL + l)) * DDIM + h * HDIM + dt * 16 + lr] = f2b(oa[qs][dt][r] * inv);
        }
    }
}

extern "C" void kernel_launch(void* const* d_in, const int* in_sizes, int n_in,
                              void* d_out, int out_size, void* d_ws, size_t ws_size,
                              hipStream_t stream) {
    const float* x       = (const float*)d_in[0];
    const float* patch_w = (const float*)d_in[1];
    const float* patch_b = (const float*)d_in[2];
    const float* cls     = (const float*)d_in[3];
    const float* ln1_s   = (const float*)d_in[4];
    const float* ln1_b   = (const float*)d_in[5];
    const float* qkv_w   = (const float*)d_in[6];
    const float* proj_w  = (const float*)d_in[7];
    const float* proj_b  = (const float*)d_in[8];
    const float* ln2_s   = (const float*)d_in[9];
    const float* ln2_b   = (const float*)d_in[10];
    const float* mlp_w1  = (const float*)d_in[11];
    const float* mlp_b1  = (const float*)d_in[12];
    const float* mlp_w2  = (const float*)d_in[13];
    const float* mlp_b2  = (const float*)d_in[14];
    const float* norm_s  = (const float*)d_in[15];
    const float* norm_b  = (const float*)d_in[16];

    const size_t SZ_WQ = (size_t)3 * DDIM * DDIM;
    const size_t SZ_WP = (size_t)DDIM * DDIM;
    const size_t SZ_W1 = (size_t)NHID * DDIM;
    const size_t SZ_W2 = (size_t)DDIM * NHID;

    char* w = (char*)d_ws;
    float* t      = (float*)w;  w += (size_t)MPAD * DDIM * 4;
    float* sin_t  = (float*)w;  w += (size_t)NL0 * HDIM * 4;
    float* cos_t  = (float*)w;  w += (size_t)NL0 * HDIM * 4;
    ushortT* psum = (ushortT*)w; w += (size_t)2 * MPAD * DDIM * 2;   // bf16 partials (split-K=2)
    ushortT* h_bf   = (ushortT*)w; w += (size_t)MPAD * DDIM * 2;
    ushortT* o_bf   = (ushortT*)w; w += (size_t)MPAD * DDIM * 2;
    ushortT* mlp_bf = (ushortT*)w; w += (size_t)MPAD * NHID * 2;
    ushortT* patches = mlp_bf;    // alias: disjoint lifetime (pre-loop only)
    ushortT* q_bf   = (ushortT*)w; w += (size_t)96 * LPAD * HDIM * 2;
    ushortT* k_bf   = (ushortT*)w; w += (size_t)96 * LPAD * HDIM * 2;
    ushortT* v_t    = (ushortT*)w; w += (size_t)96 * HDIM * LPAD * 2;
    ushortT* pw_bf  = (ushortT*)w; w += (size_t)DDIM * 768 * 2;
    // double-buffered per-layer weight sets
    ushortT* wqB[2]; ushortT* wpB[2]; ushortT* w1B[2]; ushortT* w2B[2];
    for (int s = 0; s < 2; ++s) {
        wqB[s] = (ushortT*)w; w += SZ_WQ * 2;
        wpB[s] = (ushortT*)w; w += SZ_WP * 2;
        w1B[s] = (ushortT*)w; w += SZ_W1 * 2;
        w2B[s] = (ushortT*)w; w += SZ_W2 * 2;
    }

    const float* nfp = nullptr;
    ushortT* nus = nullptr;
    float* nf = nullptr;

    hipLaunchKernelGGL(rope_k, dim3(NL0), dim3(64), 0, stream, sin_t, cos_t);
    hipLaunchKernelGGL(im2col_k, dim3(2048), dim3(256), 0, stream, x, patches);
    hipLaunchKernelGGL(f2b_k, dim3(512), dim3(256), 0, stream, patch_w, pw_bf, (long)DDIM * 768);
    hipLaunchKernelGGL(cls_k, dim3(NB), dim3(DDIM), 0, stream, cls, t);
    // layer-0 weights
    hipLaunchKernelGGL(wconv4_k, dim3(1024), dim3(256), 0, stream,
                       qkv_w, wqB[0], (long)SZ_WQ,
                       proj_w, wpB[0], (long)SZ_WP,
                       mlp_w1, w1B[0], (long)SZ_W1,
                       mlp_w2, w2B[0], (long)SZ_W2);
    // patch embed: 64x128 tile, 8 waves, grid 6x72
    hipLaunchKernelGGL((gemm_t<2, 4, 2, 2, 1, 8>), dim3(DDIM / 128, 4608 / 64), dim3(512), 0, stream,
                       patches, pw_bf, patch_b, nfp, t, nus, nfp, nfp, nus, nus, nus, nus,
                       DDIM, 768, 1 | 8 | 16);

    for (int i = 0; i < NDEPTH; ++i) {
        int cur = i & 1, nxt = (i + 1) & 1;
        if (i == 0) {
            hipLaunchKernelGGL(ln_k, dim3(MROWS), dim3(256), 0, stream,
                               t, ln1_s, ln1_b, nf, h_bf, (long)DDIM);
        } else {
            hipLaunchKernelGGL(red_ln_k, dim3(MROWS), dim3(256), 0, stream,
                               psum, mlp_b2 + (i - 1) * DDIM, t,
                               ln1_s + i * DDIM, ln1_b + i * DDIM, h_bf);
        }
        // QKV GEMM (128x128, 8 waves) with fused RoPE + scatter (coalesced V via LDS bounce)
        hipLaunchKernelGGL((gemm_t<4, 2, 2, 4, 1, 8>), dim3((3 * DDIM) / 128, MPAD / 128), dim3(512), 0, stream,
                           h_bf, wqB[cur], nfp, nfp, nf, nus, sin_t, cos_t,
                           q_bf, k_bf, v_t, nus, 3 * DDIM, DDIM, 64);
        // attention (2 q-tiles/block) + fused next-layer weight conversion
        long cn = (i + 1 < NDEPTH) ? 1 : 0;
        hipLaunchKernelGGL(fattn_k, dim3(96 * QT2 + NCONV), dim3(256), 0, stream,
                           q_bf, k_bf, v_t, o_bf,
                           qkv_w + SZ_WQ * (i + 1), wqB[nxt], cn * (long)SZ_WQ,
                           proj_w + SZ_WP * (i + 1), wpB[nxt], cn * (long)SZ_WP,
                           mlp_w1 + SZ_W1 * (i + 1), w1B[nxt], cn * (long)SZ_W1,
                           mlp_w2 + SZ_W2 * (i + 1), w2B[nxt], cn * (long)SZ_W2);
        // proj: 64x128 tile, 8 waves, grid 6x74
        hipLaunchKernelGGL((gemm_t<2, 4, 2, 2, 1, 8>), dim3(DDIM / 128, MPAD / 64), dim3(512), 0, stream,
                           o_bf, wpB[cur], proj_b + i * DDIM, t, t, nus, nfp, nfp, nus, nus, nus, nus,
                           DDIM, DDIM, 1 | 2 | 16);
        hipLaunchKernelGGL(ln_k, dim3(MROWS), dim3(256), 0, stream,
                           t, ln2_s + i * DDIM, ln2_b + i * DDIM, nf, h_bf, (long)DDIM);
        // mlp1: 128x128, 8 waves
        hipLaunchKernelGGL((gemm_t<4, 2, 2, 4, 1, 8>), dim3(NHID / 128, MPAD / 128), dim3(512), 0, stream,
                           h_bf, w1B[cur], mlp_b1 + i * NHID, nfp, nf, mlp_bf, nfp, nfp,
                           nus, nus, nus, nus, NHID, DDIM, 1 | 4 | 32);
        // mlp2: split-K 2 bf16 partials, 128x128, 8 waves
        hipLaunchKernelGGL((gemm_t<4, 2, 2, 4, 2, 8>), dim3(DDIM / 128, MPAD / 128, 2), dim3(512), 0, stream,
                           mlp_bf, w2B[cur], nfp, nfp, nf, nus, nfp, nfp,
                           nus, nus, nus, psum, DDIM, NHID, 0);
    }
    // final: reduce CLS rows + final LN -> d_out
    hipLaunchKernelGGL(red_final_k, dim3(NB), dim3(256), 0, stream,
                       psum, mlp_b2 + (NDEPTH - 1) * DDIM, t, norm_s, norm_b, (float*)d_out);
}

// Round 16
// 2287.024 us; speedup vs baseline: 1.1127x; 1.0042x over previous
//
#include <hip/hip_runtime.h>
#include <math.h>

#define NB 8
#define DDIM 768
#define NHEAD 12
#define NDEPTH 12
#define HDIM 64
#define GRIDW 24
#define NL0 576
#define NL 577
#define LPAD 640
#define NHID 3072
#define MROWS (NB*NL)     // 4616
#define MPAD 4736         // 37*128, 74*64
#define EPSV 1e-5f
#define QT2 5             // q-tile PAIRS per head (2x64 rows each)
#define NCONV 512

typedef unsigned short ushortT;
typedef __attribute__((ext_vector_type(8))) short bf16x8;
typedef __attribute__((ext_vector_type(4))) float f32x4;

__device__ __forceinline__ ushortT f2b(float f) {
    union { float f; unsigned u; } x; x.f = f;
    unsigned r = x.u + 0x7fffu + ((x.u >> 16) & 1u);
    return (ushortT)(r >> 16);
}

__device__ __forceinline__ float b2f(ushortT u) {
    union { unsigned u; float f; } x; x.u = ((unsigned)u) << 16;
    return x.f;
}

__device__ __forceinline__ void load_lds16(const void* g, void* l) {
    __builtin_amdgcn_global_load_lds((const __attribute__((address_space(1))) void*)g,
                                     (__attribute__((address_space(3))) void*)l, 16, 0, 0);
}

// ---------------- fp32 -> bf16 convert ----------------
__global__ void f2b_k(const float* __restrict__ in, ushortT* __restrict__ out, long n) {
    for (long i = ((long)blockIdx.x * 256 + threadIdx.x) * 4; i < n; i += (long)gridDim.x * 1024) {
        float4 v = *(const float4*)(in + i);
        ushort4 o; o.x = f2b(v.x); o.y = f2b(v.y); o.z = f2b(v.z); o.w = f2b(v.w);
        *(ushort4*)(out + i) = o;
    }
}

// ---------------- 4-array convert (preamble: layer-0 weights) ----------------
__global__ void wconv4_k(const float* __restrict__ a, ushortT* __restrict__ ao, long na,
                         const float* __restrict__ b, ushortT* __restrict__ bo, long nb,
                         const float* __restrict__ c, ushortT* __restrict__ co, long nc,
                         const float* __restrict__ d, ushortT* __restrict__ dd, long nd) {
    long stride = (long)gridDim.x * 1024;
    long i0 = ((long)blockIdx.x * 256 + threadIdx.x) * 4;
    for (long i = i0; i < na; i += stride) {
        float4 v = *(const float4*)(a + i);
        ushort4 o; o.x = f2b(v.x); o.y = f2b(v.y); o.z = f2b(v.z); o.w = f2b(v.w);
        *(ushort4*)(ao + i) = o;
    }
    for (long i = i0; i < nb; i += stride) {
        float4 v = *(const float4*)(b + i);
        ushort4 o; o.x = f2b(v.x); o.y = f2b(v.y); o.z = f2b(v.z); o.w = f2b(v.w);
        *(ushort4*)(bo + i) = o;
    }
    for (long i = i0; i < nc; i += stride) {
        float4 v = *(const float4*)(c + i);
        ushort4 o; o.x = f2b(v.x); o.y = f2b(v.y); o.z = f2b(v.z); o.w = f2b(v.w);
        *(ushort4*)(co + i) = o;
    }
    for (long i = i0; i < nd; i += stride) {
        float4 v = *(const float4*)(d + i);
        ushort4 o; o.x = f2b(v.x); o.y = f2b(v.y); o.z = f2b(v.z); o.w = f2b(v.w);
        *(ushort4*)(dd + i) = o;
    }
}

// ---------------- im2col -> bf16 patches[4608, 768] ----------------
__global__ void im2col_k(const float* __restrict__ x, ushortT* __restrict__ p) {
    for (long idx = (long)blockIdx.x * 256 + threadIdx.x; idx < (long)4608 * 768; idx += (long)gridDim.x * 256) {
        int row = (int)(idx / 768), col = (int)(idx - (long)row * 768);
        int b = row / NL0, pi = row - b * NL0;
        int gy = pi / GRIDW, gx = pi - gy * GRIDW;
        int c = col >> 8, r = col & 255;
        int py = r >> 4, px = r & 15;
        p[idx] = f2b(x[(((long)(b * 3 + c) * 384) + gy * 16 + py) * 384 + gx * 16 + px]);
    }
}

__global__ void cls_k(const float* __restrict__ cls, float* __restrict__ t) {
    t[(long)blockIdx.x * NL * DDIM + threadIdx.x] = cls[threadIdx.x];
}

__global__ void rope_k(float* __restrict__ sin_t, float* __restrict__ cos_t) {
    int pos = blockIdx.x, d = threadIdx.x;
    int gy = pos / GRIDW, gx = pos - gy * GRIDW;
    int j = d >> 1;
    float ang;
    if (j < 16) ang = (float)gy * powf(10000.f, -(float)j / 16.f);
    else        ang = (float)gx * powf(10000.f, -(float)(j - 16) / 16.f);
    sin_t[pos * 64 + d] = sinf(ang);
    cos_t[pos * 64 + d] = cosf(ang);
}

// ---------------- LayerNorm (plain; layer-0 ln1 and all ln2) ----------------
__global__ __launch_bounds__(256) void ln_k(const float* __restrict__ in,
                                            const float* __restrict__ sc,
                                            const float* __restrict__ bi,
                                            float* __restrict__ outf,
                                            ushortT* __restrict__ outb,
                                            long in_rstride) {
    int row = blockIdx.x;
    const float* ip = in + (long)row * in_rstride;
    float x[3];
    float s = 0.f, s2 = 0.f;
    #pragma unroll
    for (int i = 0; i < 3; ++i) {
        x[i] = ip[threadIdx.x + i * 256];
        s += x[i]; s2 += x[i] * x[i];
    }
    __shared__ float red0[256], red1[256];
    red0[threadIdx.x] = s; red1[threadIdx.x] = s2;
    __syncthreads();
    for (int off = 128; off; off >>= 1) {
        if (threadIdx.x < off) {
            red0[threadIdx.x] += red0[threadIdx.x + off];
            red1[threadIdx.x] += red1[threadIdx.x + off];
        }
        __syncthreads();
    }
    float mean = red0[0] * (1.f / 768.f);
    float var  = red1[0] * (1.f / 768.f) - mean * mean;
    float inv = rsqrtf(var + EPSV);
    #pragma unroll
    for (int i = 0; i < 3; ++i) {
        int c = threadIdx.x + i * 256;
        float val = (x[i] - mean) * inv * sc[c] + bi[c];
        if (outb) outb[(long)row * 768 + c] = f2b(val);
        else      outf[(long)row * 768 + c] = val;
    }
}

// ---------------- fused: t += mlp2_bias + sum2(bf16 psum); then LN1(next layer) -> h_bf ----------------
__global__ __launch_bounds__(256) void red_ln_k(const ushortT* __restrict__ psum,
                                                const float* __restrict__ b2,
                                                float* __restrict__ t,
                                                const float* __restrict__ sc,
                                                const float* __restrict__ bi,
                                                ushortT* __restrict__ outb) {
    int row = blockIdx.x;
    const size_t S = (size_t)MPAD * DDIM;
    const size_t rb = (size_t)row * DDIM;
    float x[3];
    float s = 0.f, s2 = 0.f;
    #pragma unroll
    for (int i = 0; i < 3; ++i) {
        int c = threadIdx.x + i * 256;
        float v = t[rb + c] + b2[c] + b2f(psum[rb + c]) + b2f(psum[S + rb + c]);
        x[i] = v; s += v; s2 += v * v;
        t[rb + c] = v;
    }
    __shared__ float red0[256], red1[256];
    red0[threadIdx.x] = s; red1[threadIdx.x] = s2;
    __syncthreads();
    for (int off = 128; off; off >>= 1) {
        if (threadIdx.x < off) {
            red0[threadIdx.x] += red0[threadIdx.x + off];
            red1[threadIdx.x] += red1[threadIdx.x + off];
        }
        __syncthreads();
    }
    float mean = red0[0] * (1.f / 768.f);
    float var  = red1[0] * (1.f / 768.f) - mean * mean;
    float inv = rsqrtf(var + EPSV);
    #pragma unroll
    for (int i = 0; i < 3; ++i) {
        int c = threadIdx.x + i * 256;
        outb[rb + c] = f2b((x[i] - mean) * inv * sc[c] + bi[c]);
    }
}

// ---------------- final: reduce CLS rows only + final LN -> d_out[8,768] f32 ----------------
__global__ __launch_bounds__(256) void red_final_k(const ushortT* __restrict__ psum,
                                                   const float* __restrict__ b2,
                                                   const float* __restrict__ t,
                                                   const float* __restrict__ sc,
                                                   const float* __restrict__ bi,
                                                   float* __restrict__ outf) {
    int row = blockIdx.x * NL;            // CLS row of batch blockIdx.x
    const size_t S = (size_t)MPAD * DDIM;
    const size_t rb = (size_t)row * DDIM;
    float x[3];
    float s = 0.f, s2 = 0.f;
    #pragma unroll
    for (int i = 0; i < 3; ++i) {
        int c = threadIdx.x + i * 256;
        float v = t[rb + c] + b2[c] + b2f(psum[rb + c]) + b2f(psum[S + rb + c]);
        x[i] = v; s += v; s2 += v * v;
    }
    __shared__ float red0[256], red1[256];
    red0[threadIdx.x] = s; red1[threadIdx.x] = s2;
    __syncthreads();
    for (int off = 128; off; off >>= 1) {
        if (threadIdx.x < off) {
            red0[threadIdx.x] += red0[threadIdx.x + off];
            red1[threadIdx.x] += red1[threadIdx.x + off];
        }
        __syncthreads();
    }
    float mean = red0[0] * (1.f / 768.f);
    float var  = red1[0] * (1.f / 768.f) - mean * mean;
    float inv = rsqrtf(var + EPSV);
    #pragma unroll
    for (int i = 0; i < 3; ++i) {
        int c = threadIdx.x + i * 256;
        outf[(long)blockIdx.x * 768 + c] = (x[i] - mean) * inv * sc[c] + bi[c];
    }
}

// ---------------- templated bf16 MFMA GEMM (2-stage dbuf, NW waves) ----------------
template<int WR, int WC, int MI, int NI, int SPLITK, int NW>
__global__ __launch_bounds__(NW * 64) void gemm_t(const ushortT* __restrict__ A,
                                                  const ushortT* __restrict__ W,
                                                  const float* __restrict__ bias,
                                                  const float* __restrict__ resid,
                                                  float* __restrict__ Cf,
                                                  ushortT* __restrict__ Cb,
                                                  const float* __restrict__ sinT,
                                                  const float* __restrict__ cosT,
                                                  ushortT* __restrict__ qo,
                                                  ushortT* __restrict__ ko,
                                                  ushortT* __restrict__ vo,
                                                  ushortT* __restrict__ psum,
                                                  int N, int K, int flags) {
    constexpr int BM = WR * MI * 16;
    constexpr int BN = WC * NI * 16;
    constexpr int THREADS = NW * 64;
    constexpr int ACH = (BM * 64) / (THREADS * 8);
    constexpr int BCH = (BN * 64) / (THREADS * 8);
    __shared__ ushortT As[2][BM * 64];
    __shared__ ushortT Bs[2][BN * 64];
    int tid = threadIdx.x;
    int lane = tid & 63, wid = tid >> 6;
    int wm = wid / WC, wn = wid % WC;
    int lr = lane & 15, lk = lane >> 4;
    int nwg = gridDim.x * gridDim.y;
    int flat = blockIdx.y * gridDim.x + blockIdx.x;
    int qq = nwg >> 3, rr = nwg & 7;
    int xcd = flat & 7, idx = flat >> 3;
    int wg = (xcd < rr ? xcd * (qq + 1) : rr * (qq + 1) + (xcd - rr) * qq) + idx;
    int bx = wg % gridDim.x, by = wg / gridDim.x;
    int m0 = by * BM, n0 = bx * BN;
    int kspan = K / SPLITK;
    int k0 = (SPLITK > 1) ? blockIdx.z * kspan : 0;
    f32x4 acc[MI][NI] = {};

    auto stage = [&](int buf, int kt) {
        #pragma unroll
        for (int i = 0; i < ACH; ++i) {
            int ch = i * THREADS + tid;
            int r = ch >> 3, cb = (ch & 7) * 16;
            int cbs = cb ^ ((r & 7) << 4);
            load_lds16(A + (size_t)(m0 + r) * K + kt + (cbs >> 1), &As[buf][ch * 8]);
        }
        #pragma unroll
        for (int i = 0; i < BCH; ++i) {
            int ch = i * THREADS + tid;
            int r = ch >> 3, cb = (ch & 7) * 16;
            int cbs = cb ^ ((r & 7) << 4);
            load_lds16(W + (size_t)(n0 + r) * K + kt + (cbs >> 1), &Bs[buf][ch * 8]);
        }
    };

    stage(0, k0);
    asm volatile("s_waitcnt vmcnt(0)" ::: "memory");
    __builtin_amdgcn_s_barrier();
    int nk = kspan / 64;
    int cur = 0;
    for (int it = 0; it < nk; ++it) {
        if (it + 1 < nk) stage(cur ^ 1, k0 + (it + 1) * 64);
        #pragma unroll
        for (int ks = 0; ks < 2; ++ks) {
            bf16x8 aF[MI], bF[NI];
            #pragma unroll
            for (int mi = 0; mi < MI; ++mi) {
                int row = wm * MI * 16 + mi * 16 + lr;
                aF[mi] = *(const bf16x8*)((const char*)&As[cur][0] + row * 128 +
                                          ((ks * 64 + lk * 16) ^ ((row & 7) << 4)));
            }
            #pragma unroll
            for (int ni = 0; ni < NI; ++ni) {
                int row = wn * NI * 16 + ni * 16 + lr;
                bF[ni] = *(const bf16x8*)((const char*)&Bs[cur][0] + row * 128 +
                                          ((ks * 64 + lk * 16) ^ ((row & 7) << 4)));
            }
            #pragma unroll
            for (int mi = 0; mi < MI; ++mi)
                #pragma unroll
                for (int ni = 0; ni < NI; ++ni)
                    acc[mi][ni] = __builtin_amdgcn_mfma_f32_16x16x32_bf16(aF[mi], bF[ni], acc[mi][ni], 0, 0, 0);
        }
        asm volatile("s_waitcnt vmcnt(0)" ::: "memory");
        __builtin_amdgcn_s_barrier();
        cur ^= 1;
    }

    if (SPLITK > 1) {
        #pragma unroll
        for (int mi = 0; mi < MI; ++mi) {
            int rbase = m0 + wm * MI * 16 + mi * 16 + (lane >> 4) * 4;
            #pragma unroll
            for (int ni = 0; ni < NI; ++ni) {
                int c = n0 + wn * NI * 16 + ni * 16 + lr;
                #pragma unroll
                for (int r = 0; r < 4; ++r)
                    psum[((size_t)blockIdx.z * MPAD + rbase + r) * N + c] = f2b(acc[mi][ni][r]);
            }
        }
        return;
    }
    if (flags & 64) {
        if constexpr (NI == 4 && BN == 128) {
            int selB = n0 / DDIM;      // 768 % 128 == 0: block lies wholly in q, k, or v
            if (selB == 2) {
                // V block: bounce through LDS (reuse As) for coalesced transposed writes.
                ushortT* vtile = &As[0][0];
                #pragma unroll
                for (int mi = 0; mi < MI; ++mi) {
                    #pragma unroll
                    for (int ni = 0; ni < NI; ++ni) {
                        #pragma unroll
                        for (int r = 0; r < 4; ++r) {
                            int ll = wm * MI * 16 + mi * 16 + (lane >> 4) * 4 + r;
                            int dl = wn * 64 + ni * 16 + lr;
                            vtile[dl * BM + (ll ^ ((dl & 7) << 4))] = f2b(acc[mi][ni][r]);
                        }
                    }
                }
                __syncthreads();
                for (int e = tid; e < 128 * BM; e += THREADS) {
                    int dl = e / BM, ll = e - dl * BM;
                    int row = m0 + ll;
                    if (row < MROWS) {
                        int b = row / NL, l = row - b * NL;
                        int cv = (n0 - 2 * DDIM) + dl;
                        int h = cv >> 6, d = cv & 63;
                        int bh = b * NHEAD + h;
                        vo[((long)bh * HDIM + d) * LPAD + l] = vtile[dl * BM + (ll ^ ((dl & 7) << 4))];
                    }
                }
            } else {
                #pragma unroll
                for (int mi = 0; mi < MI; ++mi) {
                    #pragma unroll
                    for (int r = 0; r < 4; ++r) {
                        int row = m0 + wm * MI * 16 + mi * 16 + (lane >> 4) * 4 + r;
                        if (row >= MROWS) continue;
                        int b = row / NL, l = row - b * NL;
                        #pragma unroll
                        for (int ni = 0; ni < NI; ++ni) {
                            int c = n0 + wn * 64 + ni * 16 + lr;
                            float val = acc[mi][ni][r];
                            int sel = c / DDIM;
                            int cc = c - sel * DDIM;
                            int h = cc >> 6, d = cc & 63;
                            if (l > 0) {
                                int pos = l - 1;
                                float cs = cosT[pos * 64 + d], sn = sinT[pos * 64 + d];
                                float partner = acc[mi][ni ^ 2][r];
                                float rh = (d < 32) ? -partner : partner;
                                val = val * cs + rh * sn;
                            }
                            int bh = b * NHEAD + h;
                            if (sel == 0) qo[((long)bh * LPAD + l) * HDIM + d] = f2b(val * 0.125f);
                            else          ko[((long)bh * LPAD + l) * HDIM + d] = f2b(val);
                        }
                    }
                }
            }
        }
        return;
    }
    #pragma unroll
    for (int mi = 0; mi < MI; ++mi) {
        int rbase = m0 + wm * MI * 16 + mi * 16 + (lane >> 4) * 4;
        #pragma unroll
        for (int ni = 0; ni < NI; ++ni) {
            int c = n0 + wn * NI * 16 + ni * 16 + lr;
            float bv = (flags & 1) ? bias[c] : 0.f;
            #pragma unroll
            for (int r = 0; r < 4; ++r) {
                int row = rbase + r;
                float val = acc[mi][ni][r] + bv;
                if (flags & 4) val = 0.5f * val * (1.f + erff(val * 0.70710678118654752f));
                long orow = row;
                if (flags & 8) orow = (long)(row / NL0) * NL + 1 + (row % NL0);
                if (flags & 2) val += resid[orow * (long)N + c];
                if (flags & 16) Cf[orow * (long)N + c] = val;
                if (flags & 32) Cb[orow * (long)N + c] = f2b(val);
            }
        }
    }
}

// ---------------- MFMA flash attention: 2 q-tiles per block + fused weight conversion ----------------
// T1 head-chunking: the 5 blocks of each head share K/V; bijective XCD remap
// (480 = 8*60) gives each XCD 60 consecutive blocks = 12 whole heads -> K/V L2 reuse.
__global__ __launch_bounds__(256) void fattn_k(const ushortT* __restrict__ q,
                                               const ushortT* __restrict__ k,
                                               const ushortT* __restrict__ vt,
                                               ushortT* __restrict__ o,
                                               const float* __restrict__ wa, ushortT* __restrict__ wao, long na,
                                               const float* __restrict__ wb, ushortT* __restrict__ wbo, long nbn,
                                               const float* __restrict__ wc, ushortT* __restrict__ wco, long nc,
                                               const float* __restrict__ wd, ushortT* __restrict__ wdo, long nd) {
    if (blockIdx.x >= 96 * QT2) {
        int cid = blockIdx.x - 96 * QT2;
        long stride = (long)NCONV * 1024;
        long i0 = ((long)cid * 256 + threadIdx.x) * 4;
        for (long i = i0; i < na; i += stride) {
            float4 v = *(const float4*)(wa + i);
            ushort4 t4; t4.x = f2b(v.x); t4.y = f2b(v.y); t4.z = f2b(v.z); t4.w = f2b(v.w);
            *(ushort4*)(wao + i) = t4;
        }
        for (long i = i0; i < nbn; i += stride) {
            float4 v = *(const float4*)(wb + i);
            ushort4 t4; t4.x = f2b(v.x); t4.y = f2b(v.y); t4.z = f2b(v.z); t4.w = f2b(v.w);
            *(ushort4*)(wbo + i) = t4;
        }
        for (long i = i0; i < nc; i += stride) {
            float4 v = *(const float4*)(wc + i);
            ushort4 t4; t4.x = f2b(v.x); t4.y = f2b(v.y); t4.z = f2b(v.z); t4.w = f2b(v.w);
            *(ushort4*)(wco + i) = t4;
        }
        for (long i = i0; i < nd; i += stride) {
            float4 v = *(const float4*)(wd + i);
            ushort4 t4; t4.x = f2b(v.x); t4.y = f2b(v.y); t4.z = f2b(v.z); t4.w = f2b(v.w);
            *(ushort4*)(wdo + i) = t4;
        }
        return;
    }
    // T1 bijective remap: 480 attention blocks, 480/8 = 60 per XCD (contiguous)
    int flat = blockIdx.x;
    int wg = (flat & 7) * 60 + (flat >> 3);
    __shared__ ushortT Qs[2][4096], Ks[4096], Vs[4096], Ps[4096];
    int tid = threadIdx.x;
    int wave = tid >> 6, lane = tid & 63;
    int lr = lane & 15, lk = lane >> 4, g = lk;
    int bh = wg / QT2, qp = wg % QT2;
    int q0 = qp * 128;
    int b = bh / NHEAD, h = bh - b * NHEAD;
    int l8 = lane >> 3, c16 = lane & 7;
    int colsw = (c16 * 16) ^ ((l8 & 7) << 4);

    #pragma unroll
    for (int qs = 0; qs < 2; ++qs) {
        const ushortT* src = q + ((long)bh * LPAD + q0 + qs * 64) * HDIM;
        #pragma unroll
        for (int j = 0; j < 2; ++j) {
            int row = wave * 16 + j * 8 + l8;
            load_lds16(src + (long)row * HDIM + (colsw >> 1), Qs[qs] + wave * 1024 + j * 512);
        }
    }
    __syncthreads();
    bf16x8 qF[2][2];
    #pragma unroll
    for (int qs = 0; qs < 2; ++qs)
        #pragma unroll
        for (int ks = 0; ks < 2; ++ks) {
            int row = wave * 16 + lr;
            qF[qs][ks] = *(const bf16x8*)((const char*)Qs[qs] + row * 128 +
                                          ((ks * 64 + lk * 16) ^ ((lr & 7) << 4)));
        }
    f32x4 oa[2][4] = {};
    float m_r[2][4], l_r[2][4];
    #pragma unroll
    for (int qs = 0; qs < 2; ++qs)
        #pragma unroll
        for (int r = 0; r < 4; ++r) { m_r[qs][r] = -3e38f; l_r[qs][r] = 0.f; }

    for (int t0 = 0; t0 < 10; ++t0) {
        int k0 = t0 * 64;
        __syncthreads();
        {
            const ushortT* srck = k + ((long)bh * LPAD + k0) * HDIM;
            const ushortT* srcv = vt + (long)bh * HDIM * LPAD + k0;
            #pragma unroll
            for (int j = 0; j < 2; ++j) {
                int row = wave * 16 + j * 8 + l8;
                load_lds16(srck + (long)row * HDIM + (colsw >> 1), Ks + wave * 1024 + j * 512);
                load_lds16(srcv + (long)row * LPAD + (colsw >> 1), Vs + wave * 1024 + j * 512);
            }
        }
        __syncthreads();
        #pragma unroll
        for (int qs = 0; qs < 2; ++qs) {
            f32x4 s[4] = {};
            #pragma unroll
            for (int ks = 0; ks < 2; ++ks) {
                #pragma unroll
                for (int kt = 0; kt < 4; ++kt) {
                    int row = kt * 16 + lr;
                    bf16x8 kF = *(const bf16x8*)((const char*)Ks + row * 128 +
                                                 ((ks * 64 + lk * 16) ^ ((lr & 7) << 4)));
                    s[kt] = __builtin_amdgcn_mfma_f32_16x16x32_bf16(qF[qs][ks], kF, s[kt], 0, 0, 0);
                }
            }
            if (k0 + 63 > 576) {
                #pragma unroll
                for (int kt = 0; kt < 4; ++kt)
                    if (k0 + kt * 16 + lr > 576) {
                        #pragma unroll
                        for (int r = 0; r < 4; ++r) s[kt][r] = -3e38f;
                    }
            }
            float mx[4], al[4], rs[4];
            #pragma unroll
            for (int r = 0; r < 4; ++r)
                mx[r] = fmaxf(fmaxf(s[0][r], s[1][r]), fmaxf(s[2][r], s[3][r]));
            #pragma unroll
            for (int off = 1; off < 16; off <<= 1) {
                #pragma unroll
                for (int r = 0; r < 4; ++r) mx[r] = fmaxf(mx[r], __shfl_xor(mx[r], off));
            }
            #pragma unroll
            for (int r = 0; r < 4; ++r) {
                float mn = fmaxf(m_r[qs][r], mx[r]);
                al[r] = __expf(m_r[qs][r] - mn);
                m_r[qs][r] = mn;
                rs[r] = 0.f;
            }
            #pragma unroll
            for (int kt = 0; kt < 4; ++kt) {
                #pragma unroll
                for (int r = 0; r < 4; ++r) {
                    float p = __expf(s[kt][r] - m_r[qs][r]);
                    rs[r] += p;
                    int rowp = g * 4 + r;
                    *(ushortT*)((char*)Ps + wave * 2048 + rowp * 128 +
                                ((kt * 32 + lr * 2) ^ ((rowp & 7) << 4))) = f2b(p);
                }
            }
            #pragma unroll
            for (int off = 1; off < 16; off <<= 1) {
                #pragma unroll
                for (int r = 0; r < 4; ++r) rs[r] += __shfl_xor(rs[r], off);
            }
            #pragma unroll
            for (int r = 0; r < 4; ++r) l_r[qs][r] = l_r[qs][r] * al[r] + rs[r];
            #pragma unroll
            for (int dt = 0; dt < 4; ++dt) {
                #pragma unroll
                for (int r = 0; r < 4; ++r) oa[qs][dt][r] *= al[r];
            }
            #pragma unroll
            for (int ks = 0; ks < 2; ++ks) {
                bf16x8 pA = *(const bf16x8*)((const char*)Ps + wave * 2048 + lr * 128 +
                                             ((ks * 64 + lk * 16) ^ ((lr & 7) << 4)));
                #pragma unroll
                for (int dt = 0; dt < 4; ++dt) {
                    bf16x8 vF = *(const bf16x8*)((const char*)Vs + (dt * 16 + lr) * 128 +
                                                 ((ks * 64 + lk * 16) ^ ((lr & 7) << 4)));
                    oa[qs][dt] = __builtin_amdgcn_mfma_f32_16x16x32_bf16(pA, vF, oa[qs][dt], 0, 0, 0);
                }
            }
        }
    }
    #pragma unroll
    for (int qs = 0; qs < 2; ++qs) {
        #pragma unroll
        for (int r = 0; r < 4; ++r) {
            int l = q0 + qs * 64 + wave * 16 + g * 4 + r;
            if (l > 576) continue;
            float inv = 1.f / l_r[qs][r];
            #pragma unroll
            for (int dt = 0; dt < 4; ++dt)
                o[((long)(b * NL + l)) * DDIM + h * HDIM + dt * 16 + lr] = f2b(oa[qs][dt][r] * inv);
        }
    }
}

extern "C" void kernel_launch(void* const* d_in, const int* in_sizes, int n_in,
                              void* d_out, int out_size, void* d_ws, size_t ws_size,
                              hipStream_t stream) {
    const float* x       = (const float*)d_in[0];
    const float* patch_w = (const float*)d_in[1];
    const float* patch_b = (const float*)d_in[2];
    const float* cls     = (const float*)d_in[3];
    const float* ln1_s   = (const float*)d_in[4];
    const float* ln1_b   = (const float*)d_in[5];
    const float* qkv_w   = (const float*)d_in[6];
    const float* proj_w  = (const float*)d_in[7];
    const float* proj_b  = (const float*)d_in[8];
    const float* ln2_s   = (const float*)d_in[9];
    const float* ln2_b   = (const float*)d_in[10];
    const float* mlp_w1  = (const float*)d_in[11];
    const float* mlp_b1  = (const float*)d_in[12];
    const float* mlp_w2  = (const float*)d_in[13];
    const float* mlp_b2  = (const float*)d_in[14];
    const float* norm_s  = (const float*)d_in[15];
    const float* norm_b  = (const float*)d_in[16];

    const size_t SZ_WQ = (size_t)3 * DDIM * DDIM;
    const size_t SZ_WP = (size_t)DDIM * DDIM;
    const size_t SZ_W1 = (size_t)NHID * DDIM;
    const size_t SZ_W2 = (size_t)DDIM * NHID;

    char* w = (char*)d_ws;
    float* t      = (float*)w;  w += (size_t)MPAD * DDIM * 4;
    float* sin_t  = (float*)w;  w += (size_t)NL0 * HDIM * 4;
    float* cos_t  = (float*)w;  w += (size_t)NL0 * HDIM * 4;
    ushortT* psum = (ushortT*)w; w += (size_t)2 * MPAD * DDIM * 2;   // bf16 partials (split-K=2)
    ushortT* h_bf   = (ushortT*)w; w += (size_t)MPAD * DDIM * 2;
    ushortT* o_bf   = (ushortT*)w; w += (size_t)MPAD * DDIM * 2;
    ushortT* mlp_bf = (ushortT*)w; w += (size_t)MPAD * NHID * 2;
    ushortT* patches = mlp_bf;    // alias: disjoint lifetime (pre-loop only)
    ushortT* q_bf   = (ushortT*)w; w += (size_t)96 * LPAD * HDIM * 2;
    ushortT* k_bf   = (ushortT*)w; w += (size_t)96 * LPAD * HDIM * 2;
    ushortT* v_t    = (ushortT*)w; w += (size_t)96 * HDIM * LPAD * 2;
    ushortT* pw_bf  = (ushortT*)w; w += (size_t)DDIM * 768 * 2;
    // double-buffered per-layer weight sets
    ushortT* wqB[2]; ushortT* wpB[2]; ushortT* w1B[2]; ushortT* w2B[2];
    for (int s = 0; s < 2; ++s) {
        wqB[s] = (ushortT*)w; w += SZ_WQ * 2;
        wpB[s] = (ushortT*)w; w += SZ_WP * 2;
        w1B[s] = (ushortT*)w; w += SZ_W1 * 2;
        w2B[s] = (ushortT*)w; w += SZ_W2 * 2;
    }

    const float* nfp = nullptr;
    ushortT* nus = nullptr;
    float* nf = nullptr;

    hipLaunchKernelGGL(rope_k, dim3(NL0), dim3(64), 0, stream, sin_t, cos_t);
    hipLaunchKernelGGL(im2col_k, dim3(2048), dim3(256), 0, stream, x, patches);
    hipLaunchKernelGGL(f2b_k, dim3(512), dim3(256), 0, stream, patch_w, pw_bf, (long)DDIM * 768);
    hipLaunchKernelGGL(cls_k, dim3(NB), dim3(DDIM), 0, stream, cls, t);
    // layer-0 weights
    hipLaunchKernelGGL(wconv4_k, dim3(1024), dim3(256), 0, stream,
                       qkv_w, wqB[0], (long)SZ_WQ,
                       proj_w, wpB[0], (long)SZ_WP,
                       mlp_w1, w1B[0], (long)SZ_W1,
                       mlp_w2, w2B[0], (long)SZ_W2);
    // patch embed: 64x128 tile, 8 waves, grid 6x72
    hipLaunchKernelGGL((gemm_t<2, 4, 2, 2, 1, 8>), dim3(DDIM / 128, 4608 / 64), dim3(512), 0, stream,
                       patches, pw_bf, patch_b, nfp, t, nus, nfp, nfp, nus, nus, nus, nus,
                       DDIM, 768, 1 | 8 | 16);

    for (int i = 0; i < NDEPTH; ++i) {
        int cur = i & 1, nxt = (i + 1) & 1;
        if (i == 0) {
            hipLaunchKernelGGL(ln_k, dim3(MROWS), dim3(256), 0, stream,
                               t, ln1_s, ln1_b, nf, h_bf, (long)DDIM);
        } else {
            hipLaunchKernelGGL(red_ln_k, dim3(MROWS), dim3(256), 0, stream,
                               psum, mlp_b2 + (i - 1) * DDIM, t,
                               ln1_s + i * DDIM, ln1_b + i * DDIM, h_bf);
        }
        // QKV GEMM (128x128, 8 waves) with fused RoPE + scatter (coalesced V via LDS bounce)
        hipLaunchKernelGGL((gemm_t<4, 2, 2, 4, 1, 8>), dim3((3 * DDIM) / 128, MPAD / 128), dim3(512), 0, stream,
                           h_bf, wqB[cur], nfp, nfp, nf, nus, sin_t, cos_t,
                           q_bf, k_bf, v_t, nus, 3 * DDIM, DDIM, 64);
        // attention (2 q-tiles/block, T1 head-chunking) + fused next-layer weight conversion
        long cn = (i + 1 < NDEPTH) ? 1 : 0;
        hipLaunchKernelGGL(fattn_k, dim3(96 * QT2 + NCONV), dim3(256), 0, stream,
                           q_bf, k_bf, v_t, o_bf,
                           qkv_w + SZ_WQ * (i + 1), wqB[nxt], cn * (long)SZ_WQ,
                           proj_w + SZ_WP * (i + 1), wpB[nxt], cn * (long)SZ_WP,
                           mlp_w1 + SZ_W1 * (i + 1), w1B[nxt], cn * (long)SZ_W1,
                           mlp_w2 + SZ_W2 * (i + 1), w2B[nxt], cn * (long)SZ_W2);
        // proj: 64x128 tile, 8 waves, grid 6x74
        hipLaunchKernelGGL((gemm_t<2, 4, 2, 2, 1, 8>), dim3(DDIM / 128, MPAD / 64), dim3(512), 0, stream,
                           o_bf, wpB[cur], proj_b + i * DDIM, t, t, nus, nfp, nfp, nus, nus, nus, nus,
                           DDIM, DDIM, 1 | 2 | 16);
        hipLaunchKernelGGL(ln_k, dim3(MROWS), dim3(256), 0, stream,
                           t, ln2_s + i * DDIM, ln2_b + i * DDIM, nf, h_bf, (long)DDIM);
        // mlp1: 128x128, 8 waves
        hipLaunchKernelGGL((gemm_t<4, 2, 2, 4, 1, 8>), dim3(NHID / 128, MPAD / 128), dim3(512), 0, stream,
                           h_bf, w1B[cur], mlp_b1 + i * NHID, nfp, nf, mlp_bf, nfp, nfp,
                           nus, nus, nus, nus, NHID, DDIM, 1 | 4 | 32);
        // mlp2: split-K 2 bf16 partials, 128x128, 8 waves
        hipLaunchKernelGGL((gemm_t<4, 2, 2, 4, 2, 8>), dim3(DDIM / 128, MPAD / 128, 2), dim3(512), 0, stream,
                           mlp_bf, w2B[cur], nfp, nfp, nf, nus, nfp, nfp,
                           nus, nus, nus, psum, DDIM, NHID, 0);
    }
    // final: reduce CLS rows + final LN -> d_out
    hipLaunchKernelGGL(red_final_k, dim3(NB), dim3(256), 0, stream,
                       psum, mlp_b2 + (NDEPTH - 1) * DDIM, t, norm_s, norm_b, (float*)d_out);
}

// Round 17
// 2257.082 us; speedup vs baseline: 1.1274x; 1.0133x over previous
//
#include <hip/hip_runtime.h>
#include <math.h>

#define NB 8
#define DDIM 768
#define NHEAD 12
#define NDEPTH 12
#define HDIM 64
#define GRIDW 24
#define NL0 576
#define NL 577
#define LPAD 640
#define NHID 3072
#define MROWS (NB*NL)     // 4616
#define MPAD 4736         // 37*128, 74*64
#define EPSV 1e-5f
#define QT2 5             // q-tile PAIRS per head (2x64 rows each)
#define NCONV 512

typedef unsigned short ushortT;
typedef __attribute__((ext_vector_type(8))) short bf16x8;
typedef __attribute__((ext_vector_type(4))) float f32x4;

__device__ __forceinline__ ushortT f2b(float f) {
    union { float f; unsigned u; } x; x.f = f;
    unsigned r = x.u + 0x7fffu + ((x.u >> 16) & 1u);
    return (ushortT)(r >> 16);
}

__device__ __forceinline__ float b2f(ushortT u) {
    union { unsigned u; float f; } x; x.u = ((unsigned)u) << 16;
    return x.f;
}

__device__ __forceinline__ void load_lds16(const void* g, void* l) {
    __builtin_amdgcn_global_load_lds((const __attribute__((address_space(1))) void*)g,
                                     (__attribute__((address_space(3))) void*)l, 16, 0, 0);
}

// ---------------- fp32 -> bf16 convert ----------------
__global__ void f2b_k(const float* __restrict__ in, ushortT* __restrict__ out, long n) {
    for (long i = ((long)blockIdx.x * 256 + threadIdx.x) * 4; i < n; i += (long)gridDim.x * 1024) {
        float4 v = *(const float4*)(in + i);
        ushort4 o; o.x = f2b(v.x); o.y = f2b(v.y); o.z = f2b(v.z); o.w = f2b(v.w);
        *(ushort4*)(out + i) = o;
    }
}

// ---------------- 4-array convert (preamble: layer-0 weights) ----------------
__global__ void wconv4_k(const float* __restrict__ a, ushortT* __restrict__ ao, long na,
                         const float* __restrict__ b, ushortT* __restrict__ bo, long nb,
                         const float* __restrict__ c, ushortT* __restrict__ co, long nc,
                         const float* __restrict__ d, ushortT* __restrict__ dd, long nd) {
    long stride = (long)gridDim.x * 1024;
    long i0 = ((long)blockIdx.x * 256 + threadIdx.x) * 4;
    for (long i = i0; i < na; i += stride) {
        float4 v = *(const float4*)(a + i);
        ushort4 o; o.x = f2b(v.x); o.y = f2b(v.y); o.z = f2b(v.z); o.w = f2b(v.w);
        *(ushort4*)(ao + i) = o;
    }
    for (long i = i0; i < nb; i += stride) {
        float4 v = *(const float4*)(b + i);
        ushort4 o; o.x = f2b(v.x); o.y = f2b(v.y); o.z = f2b(v.z); o.w = f2b(v.w);
        *(ushort4*)(bo + i) = o;
    }
    for (long i = i0; i < nc; i += stride) {
        float4 v = *(const float4*)(c + i);
        ushort4 o; o.x = f2b(v.x); o.y = f2b(v.y); o.z = f2b(v.z); o.w = f2b(v.w);
        *(ushort4*)(co + i) = o;
    }
    for (long i = i0; i < nd; i += stride) {
        float4 v = *(const float4*)(d + i);
        ushort4 o; o.x = f2b(v.x); o.y = f2b(v.y); o.z = f2b(v.z); o.w = f2b(v.w);
        *(ushort4*)(dd + i) = o;
    }
}

// ---------------- im2col -> bf16 patches[4608, 768] ----------------
__global__ void im2col_k(const float* __restrict__ x, ushortT* __restrict__ p) {
    for (long idx = (long)blockIdx.x * 256 + threadIdx.x; idx < (long)4608 * 768; idx += (long)gridDim.x * 256) {
        int row = (int)(idx / 768), col = (int)(idx - (long)row * 768);
        int b = row / NL0, pi = row - b * NL0;
        int gy = pi / GRIDW, gx = pi - gy * GRIDW;
        int c = col >> 8, r = col & 255;
        int py = r >> 4, px = r & 15;
        p[idx] = f2b(x[(((long)(b * 3 + c) * 384) + gy * 16 + py) * 384 + gx * 16 + px]);
    }
}

__global__ void cls_k(const float* __restrict__ cls, ushortT* __restrict__ t) {
    t[(long)blockIdx.x * NL * DDIM + threadIdx.x] = f2b(cls[threadIdx.x]);
}

__global__ void rope_k(float* __restrict__ sin_t, float* __restrict__ cos_t) {
    int pos = blockIdx.x, d = threadIdx.x;
    int gy = pos / GRIDW, gx = pos - gy * GRIDW;
    int j = d >> 1;
    float ang;
    if (j < 16) ang = (float)gy * powf(10000.f, -(float)j / 16.f);
    else        ang = (float)gx * powf(10000.f, -(float)(j - 16) / 16.f);
    sin_t[pos * 64 + d] = sinf(ang);
    cos_t[pos * 64 + d] = cosf(ang);
}

// ---------------- LayerNorm over bf16 input (layer-0 ln1 and all ln2) ----------------
__global__ __launch_bounds__(256) void ln_k(const ushortT* __restrict__ in,
                                            const float* __restrict__ sc,
                                            const float* __restrict__ bi,
                                            ushortT* __restrict__ outb) {
    int row = blockIdx.x;
    const ushortT* ip = in + (size_t)row * DDIM;
    float x[3];
    float s = 0.f, s2 = 0.f;
    #pragma unroll
    for (int i = 0; i < 3; ++i) {
        x[i] = b2f(ip[threadIdx.x + i * 256]);
        s += x[i]; s2 += x[i] * x[i];
    }
    __shared__ float red0[256], red1[256];
    red0[threadIdx.x] = s; red1[threadIdx.x] = s2;
    __syncthreads();
    for (int off = 128; off; off >>= 1) {
        if (threadIdx.x < off) {
            red0[threadIdx.x] += red0[threadIdx.x + off];
            red1[threadIdx.x] += red1[threadIdx.x + off];
        }
        __syncthreads();
    }
    float mean = red0[0] * (1.f / 768.f);
    float var  = red1[0] * (1.f / 768.f) - mean * mean;
    float inv = rsqrtf(var + EPSV);
    #pragma unroll
    for (int i = 0; i < 3; ++i) {
        int c = threadIdx.x + i * 256;
        outb[(size_t)row * DDIM + c] = f2b((x[i] - mean) * inv * sc[c] + bi[c]);
    }
}

// ---------------- fused: t += mlp2_bias + sum2(bf16 psum); then LN1(next layer) -> h_bf ----------------
__global__ __launch_bounds__(256) void red_ln_k(const ushortT* __restrict__ psum,
                                                const float* __restrict__ b2,
                                                ushortT* __restrict__ t,
                                                const float* __restrict__ sc,
                                                const float* __restrict__ bi,
                                                ushortT* __restrict__ outb) {
    int row = blockIdx.x;
    const size_t S = (size_t)MPAD * DDIM;
    const size_t rb = (size_t)row * DDIM;
    float x[3];
    float s = 0.f, s2 = 0.f;
    #pragma unroll
    for (int i = 0; i < 3; ++i) {
        int c = threadIdx.x + i * 256;
        float v = b2f(t[rb + c]) + b2[c] + b2f(psum[rb + c]) + b2f(psum[S + rb + c]);
        x[i] = v; s += v; s2 += v * v;
        t[rb + c] = f2b(v);
    }
    __shared__ float red0[256], red1[256];
    red0[threadIdx.x] = s; red1[threadIdx.x] = s2;
    __syncthreads();
    for (int off = 128; off; off >>= 1) {
        if (threadIdx.x < off) {
            red0[threadIdx.x] += red0[threadIdx.x + off];
            red1[threadIdx.x] += red1[threadIdx.x + off];
        }
        __syncthreads();
    }
    float mean = red0[0] * (1.f / 768.f);
    float var  = red1[0] * (1.f / 768.f) - mean * mean;
    float inv = rsqrtf(var + EPSV);
    #pragma unroll
    for (int i = 0; i < 3; ++i) {
        int c = threadIdx.x + i * 256;
        outb[rb + c] = f2b((x[i] - mean) * inv * sc[c] + bi[c]);
    }
}

// ---------------- final: reduce CLS rows only + final LN -> d_out[8,768] f32 ----------------
__global__ __launch_bounds__(256) void red_final_k(const ushortT* __restrict__ psum,
                                                   const float* __restrict__ b2,
                                                   const ushortT* __restrict__ t,
                                                   const float* __restrict__ sc,
                                                   const float* __restrict__ bi,
                                                   float* __restrict__ outf) {
    int row = blockIdx.x * NL;            // CLS row of batch blockIdx.x
    const size_t S = (size_t)MPAD * DDIM;
    const size_t rb = (size_t)row * DDIM;
    float x[3];
    float s = 0.f, s2 = 0.f;
    #pragma unroll
    for (int i = 0; i < 3; ++i) {
        int c = threadIdx.x + i * 256;
        float v = b2f(t[rb + c]) + b2[c] + b2f(psum[rb + c]) + b2f(psum[S + rb + c]);
        x[i] = v; s += v; s2 += v * v;
    }
    __shared__ float red0[256], red1[256];
    red0[threadIdx.x] = s; red1[threadIdx.x] = s2;
    __syncthreads();
    for (int off = 128; off; off >>= 1) {
        if (threadIdx.x < off) {
            red0[threadIdx.x] += red0[threadIdx.x + off];
            red1[threadIdx.x] += red1[threadIdx.x + off];
        }
        __syncthreads();
    }
    float mean = red0[0] * (1.f / 768.f);
    float var  = red1[0] * (1.f / 768.f) - mean * mean;
    float inv = rsqrtf(var + EPSV);
    #pragma unroll
    for (int i = 0; i < 3; ++i) {
        int c = threadIdx.x + i * 256;
        outf[(long)blockIdx.x * 768 + c] = (x[i] - mean) * inv * sc[c] + bi[c];
    }
}

// ---------------- templated bf16 MFMA GEMM (2-stage dbuf, NW waves) ----------------
// flags: 1=bias 2=resid 4=gelu 8=remap 16=store f32 32=store bf16 64=qkv mode
//        128=resid is bf16 (residual-stream)
template<int WR, int WC, int MI, int NI, int SPLITK, int NW>
__global__ __launch_bounds__(NW * 64) void gemm_t(const ushortT* __restrict__ A,
                                                  const ushortT* __restrict__ W,
                                                  const float* __restrict__ bias,
                                                  const float* __restrict__ resid,
                                                  float* __restrict__ Cf,
                                                  ushortT* __restrict__ Cb,
                                                  const float* __restrict__ sinT,
                                                  const float* __restrict__ cosT,
                                                  ushortT* __restrict__ qo,
                                                  ushortT* __restrict__ ko,
                                                  ushortT* __restrict__ vo,
                                                  ushortT* __restrict__ psum,
                                                  int N, int K, int flags) {
    constexpr int BM = WR * MI * 16;
    constexpr int BN = WC * NI * 16;
    constexpr int THREADS = NW * 64;
    constexpr int ACH = (BM * 64) / (THREADS * 8);
    constexpr int BCH = (BN * 64) / (THREADS * 8);
    __shared__ ushortT As[2][BM * 64];
    __shared__ ushortT Bs[2][BN * 64];
    int tid = threadIdx.x;
    int lane = tid & 63, wid = tid >> 6;
    int wm = wid / WC, wn = wid % WC;
    int lr = lane & 15, lk = lane >> 4;
    int nwg = gridDim.x * gridDim.y;
    int flat = blockIdx.y * gridDim.x + blockIdx.x;
    int qq = nwg >> 3, rr = nwg & 7;
    int xcd = flat & 7, idx = flat >> 3;
    int wg = (xcd < rr ? xcd * (qq + 1) : rr * (qq + 1) + (xcd - rr) * qq) + idx;
    int bx = wg % gridDim.x, by = wg / gridDim.x;
    int m0 = by * BM, n0 = bx * BN;
    int kspan = K / SPLITK;
    int k0 = (SPLITK > 1) ? blockIdx.z * kspan : 0;
    f32x4 acc[MI][NI] = {};

    auto stage = [&](int buf, int kt) {
        #pragma unroll
        for (int i = 0; i < ACH; ++i) {
            int ch = i * THREADS + tid;
            int r = ch >> 3, cb = (ch & 7) * 16;
            int cbs = cb ^ ((r & 7) << 4);
            load_lds16(A + (size_t)(m0 + r) * K + kt + (cbs >> 1), &As[buf][ch * 8]);
        }
        #pragma unroll
        for (int i = 0; i < BCH; ++i) {
            int ch = i * THREADS + tid;
            int r = ch >> 3, cb = (ch & 7) * 16;
            int cbs = cb ^ ((r & 7) << 4);
            load_lds16(W + (size_t)(n0 + r) * K + kt + (cbs >> 1), &Bs[buf][ch * 8]);
        }
    };

    stage(0, k0);
    asm volatile("s_waitcnt vmcnt(0)" ::: "memory");
    __builtin_amdgcn_s_barrier();
    int nk = kspan / 64;
    int cur = 0;
    for (int it = 0; it < nk; ++it) {
        if (it + 1 < nk) stage(cur ^ 1, k0 + (it + 1) * 64);
        #pragma unroll
        for (int ks = 0; ks < 2; ++ks) {
            bf16x8 aF[MI], bF[NI];
            #pragma unroll
            for (int mi = 0; mi < MI; ++mi) {
                int row = wm * MI * 16 + mi * 16 + lr;
                aF[mi] = *(const bf16x8*)((const char*)&As[cur][0] + row * 128 +
                                          ((ks * 64 + lk * 16) ^ ((row & 7) << 4)));
            }
            #pragma unroll
            for (int ni = 0; ni < NI; ++ni) {
                int row = wn * NI * 16 + ni * 16 + lr;
                bF[ni] = *(const bf16x8*)((const char*)&Bs[cur][0] + row * 128 +
                                          ((ks * 64 + lk * 16) ^ ((row & 7) << 4)));
            }
            #pragma unroll
            for (int mi = 0; mi < MI; ++mi)
                #pragma unroll
                for (int ni = 0; ni < NI; ++ni)
                    acc[mi][ni] = __builtin_amdgcn_mfma_f32_16x16x32_bf16(aF[mi], bF[ni], acc[mi][ni], 0, 0, 0);
        }
        asm volatile("s_waitcnt vmcnt(0)" ::: "memory");
        __builtin_amdgcn_s_barrier();
        cur ^= 1;
    }

    if (SPLITK > 1) {
        #pragma unroll
        for (int mi = 0; mi < MI; ++mi) {
            int rbase = m0 + wm * MI * 16 + mi * 16 + (lane >> 4) * 4;
            #pragma unroll
            for (int ni = 0; ni < NI; ++ni) {
                int c = n0 + wn * NI * 16 + ni * 16 + lr;
                #pragma unroll
                for (int r = 0; r < 4; ++r)
                    psum[((size_t)blockIdx.z * MPAD + rbase + r) * N + c] = f2b(acc[mi][ni][r]);
            }
        }
        return;
    }
    if (flags & 64) {
        if constexpr (NI == 4 && BN == 128) {
            int selB = n0 / DDIM;      // 768 % 128 == 0: block lies wholly in q, k, or v
            if (selB == 2) {
                // V block: bounce through LDS (reuse As) for coalesced transposed writes.
                ushortT* vtile = &As[0][0];
                #pragma unroll
                for (int mi = 0; mi < MI; ++mi) {
                    #pragma unroll
                    for (int ni = 0; ni < NI; ++ni) {
                        #pragma unroll
                        for (int r = 0; r < 4; ++r) {
                            int ll = wm * MI * 16 + mi * 16 + (lane >> 4) * 4 + r;
                            int dl = wn * 64 + ni * 16 + lr;
                            vtile[dl * BM + (ll ^ ((dl & 7) << 4))] = f2b(acc[mi][ni][r]);
                        }
                    }
                }
                __syncthreads();
                for (int e = tid; e < 128 * BM; e += THREADS) {
                    int dl = e / BM, ll = e - dl * BM;
                    int row = m0 + ll;
                    if (row < MROWS) {
                        int b = row / NL, l = row - b * NL;
                        int cv = (n0 - 2 * DDIM) + dl;
                        int h = cv >> 6, d = cv & 63;
                        int bh = b * NHEAD + h;
                        vo[((long)bh * HDIM + d) * LPAD + l] = vtile[dl * BM + (ll ^ ((dl & 7) << 4))];
                    }
                }
            } else {
                #pragma unroll
                for (int mi = 0; mi < MI; ++mi) {
                    #pragma unroll
                    for (int r = 0; r < 4; ++r) {
                        int row = m0 + wm * MI * 16 + mi * 16 + (lane >> 4) * 4 + r;
                        if (row >= MROWS) continue;
                        int b = row / NL, l = row - b * NL;
                        #pragma unroll
                        for (int ni = 0; ni < NI; ++ni) {
                            int c = n0 + wn * 64 + ni * 16 + lr;
                            float val = acc[mi][ni][r];
                            int sel = c / DDIM;
                            int cc = c - sel * DDIM;
                            int h = cc >> 6, d = cc & 63;
                            if (l > 0) {
                                int pos = l - 1;
                                float cs = cosT[pos * 64 + d], sn = sinT[pos * 64 + d];
                                float partner = acc[mi][ni ^ 2][r];
                                float rh = (d < 32) ? -partner : partner;
                                val = val * cs + rh * sn;
                            }
                            int bh = b * NHEAD + h;
                            if (sel == 0) qo[((long)bh * LPAD + l) * HDIM + d] = f2b(val * 0.125f);
                            else          ko[((long)bh * LPAD + l) * HDIM + d] = f2b(val);
                        }
                    }
                }
            }
        }
        return;
    }
    #pragma unroll
    for (int mi = 0; mi < MI; ++mi) {
        int rbase = m0 + wm * MI * 16 + mi * 16 + (lane >> 4) * 4;
        #pragma unroll
        for (int ni = 0; ni < NI; ++ni) {
            int c = n0 + wn * NI * 16 + ni * 16 + lr;
            float bv = (flags & 1) ? bias[c] : 0.f;
            #pragma unroll
            for (int r = 0; r < 4; ++r) {
                int row = rbase + r;
                float val = acc[mi][ni][r] + bv;
                if (flags & 4) val = 0.5f * val * (1.f + erff(val * 0.70710678118654752f));
                long orow = row;
                if (flags & 8) orow = (long)(row / NL0) * NL + 1 + (row % NL0);
                if (flags & 2) {
                    if (flags & 128) val += b2f(((const ushortT*)resid)[orow * (long)N + c]);
                    else             val += resid[orow * (long)N + c];
                }
                if (flags & 16) Cf[orow * (long)N + c] = val;
                if (flags & 32) Cb[orow * (long)N + c] = f2b(val);
            }
        }
    }
}

// ---------------- MFMA flash attention: 2 q-tiles per block + fused weight conversion ----------------
// T1 head-chunking: 480 = 8*60 bijective remap -> each XCD gets 12 whole heads.
__global__ __launch_bounds__(256) void fattn_k(const ushortT* __restrict__ q,
                                               const ushortT* __restrict__ k,
                                               const ushortT* __restrict__ vt,
                                               ushortT* __restrict__ o,
                                               const float* __restrict__ wa, ushortT* __restrict__ wao, long na,
                                               const float* __restrict__ wb, ushortT* __restrict__ wbo, long nbn,
                                               const float* __restrict__ wc, ushortT* __restrict__ wco, long nc,
                                               const float* __restrict__ wd, ushortT* __restrict__ wdo, long nd) {
    if (blockIdx.x >= 96 * QT2) {
        int cid = blockIdx.x - 96 * QT2;
        long stride = (long)NCONV * 1024;
        long i0 = ((long)cid * 256 + threadIdx.x) * 4;
        for (long i = i0; i < na; i += stride) {
            float4 v = *(const float4*)(wa + i);
            ushort4 t4; t4.x = f2b(v.x); t4.y = f2b(v.y); t4.z = f2b(v.z); t4.w = f2b(v.w);
            *(ushort4*)(wao + i) = t4;
        }
        for (long i = i0; i < nbn; i += stride) {
            float4 v = *(const float4*)(wb + i);
            ushort4 t4; t4.x = f2b(v.x); t4.y = f2b(v.y); t4.z = f2b(v.z); t4.w = f2b(v.w);
            *(ushort4*)(wbo + i) = t4;
        }
        for (long i = i0; i < nc; i += stride) {
            float4 v = *(const float4*)(wc + i);
            ushort4 t4; t4.x = f2b(v.x); t4.y = f2b(v.y); t4.z = f2b(v.z); t4.w = f2b(v.w);
            *(ushort4*)(wco + i) = t4;
        }
        for (long i = i0; i < nd; i += stride) {
            float4 v = *(const float4*)(wd + i);
            ushort4 t4; t4.x = f2b(v.x); t4.y = f2b(v.y); t4.z = f2b(v.z); t4.w = f2b(v.w);
            *(ushort4*)(wdo + i) = t4;
        }
        return;
    }
    int flat = blockIdx.x;
    int wg = (flat & 7) * 60 + (flat >> 3);
    __shared__ ushortT Qs[2][4096], Ks[4096], Vs[4096], Ps[4096];
    int tid = threadIdx.x;
    int wave = tid >> 6, lane = tid & 63;
    int lr = lane & 15, lk = lane >> 4, g = lk;
    int bh = wg / QT2, qp = wg % QT2;
    int q0 = qp * 128;
    int b = bh / NHEAD, h = bh - b * NHEAD;
    int l8 = lane >> 3, c16 = lane & 7;
    int colsw = (c16 * 16) ^ ((l8 & 7) << 4);

    #pragma unroll
    for (int qs = 0; qs < 2; ++qs) {
        const ushortT* src = q + ((long)bh * LPAD + q0 + qs * 64) * HDIM;
        #pragma unroll
        for (int j = 0; j < 2; ++j) {
            int row = wave * 16 + j * 8 + l8;
            load_lds16(src + (long)row * HDIM + (colsw >> 1), Qs[qs] + wave * 1024 + j * 512);
        }
    }
    __syncthreads();
    bf16x8 qF[2][2];
    #pragma unroll
    for (int qs = 0; qs < 2; ++qs)
        #pragma unroll
        for (int ks = 0; ks < 2; ++ks) {
            int row = wave * 16 + lr;
            qF[qs][ks] = *(const bf16x8*)((const char*)Qs[qs] + row * 128 +
                                          ((ks * 64 + lk * 16) ^ ((lr & 7) << 4)));
        }
    f32x4 oa[2][4] = {};
    float m_r[2][4], l_r[2][4];
    #pragma unroll
    for (int qs = 0; qs < 2; ++qs)
        #pragma unroll
        for (int r = 0; r < 4; ++r) { m_r[qs][r] = -3e38f; l_r[qs][r] = 0.f; }

    for (int t0 = 0; t0 < 10; ++t0) {
        int k0 = t0 * 64;
        __syncthreads();
        {
            const ushortT* srck = k + ((long)bh * LPAD + k0) * HDIM;
            const ushortT* srcv = vt + (long)bh * HDIM * LPAD + k0;
            #pragma unroll
            for (int j = 0; j < 2; ++j) {
                int row = wave * 16 + j * 8 + l8;
                load_lds16(srck + (long)row * HDIM + (colsw >> 1), Ks + wave * 1024 + j * 512);
                load_lds16(srcv + (long)row * LPAD + (colsw >> 1), Vs + wave * 1024 + j * 512);
            }
        }
        __syncthreads();
        #pragma unroll
        for (int qs = 0; qs < 2; ++qs) {
            f32x4 s[4] = {};
            #pragma unroll
            for (int ks = 0; ks < 2; ++ks) {
                #pragma unroll
                for (int kt = 0; kt < 4; ++kt) {
                    int row = kt * 16 + lr;
                    bf16x8 kF = *(const bf16x8*)((const char*)Ks + row * 128 +
                                                 ((ks * 64 + lk * 16) ^ ((lr & 7) << 4)));
                    s[kt] = __builtin_amdgcn_mfma_f32_16x16x32_bf16(qF[qs][ks], kF, s[kt], 0, 0, 0);
                }
            }
            if (k0 + 63 > 576) {
                #pragma unroll
                for (int kt = 0; kt < 4; ++kt)
                    if (k0 + kt * 16 + lr > 576) {
                        #pragma unroll
                        for (int r = 0; r < 4; ++r) s[kt][r] = -3e38f;
                    }
            }
            float mx[4], al[4], rs[4];
            #pragma unroll
            for (int r = 0; r < 4; ++r)
                mx[r] = fmaxf(fmaxf(s[0][r], s[1][r]), fmaxf(s[2][r], s[3][r]));
            #pragma unroll
            for (int off = 1; off < 16; off <<= 1) {
                #pragma unroll
                for (int r = 0; r < 4; ++r) mx[r] = fmaxf(mx[r], __shfl_xor(mx[r], off));
            }
            #pragma unroll
            for (int r = 0; r < 4; ++r) {
                float mn = fmaxf(m_r[qs][r], mx[r]);
                al[r] = __expf(m_r[qs][r] - mn);
                m_r[qs][r] = mn;
                rs[r] = 0.f;
            }
            #pragma unroll
            for (int kt = 0; kt < 4; ++kt) {
                #pragma unroll
                for (int r = 0; r < 4; ++r) {
                    float p = __expf(s[kt][r] - m_r[qs][r]);
                    rs[r] += p;
                    int rowp = g * 4 + r;
                    *(ushortT*)((char*)Ps + wave * 2048 + rowp * 128 +
                                ((kt * 32 + lr * 2) ^ ((rowp & 7) << 4))) = f2b(p);
                }
            }
            #pragma unroll
            for (int off = 1; off < 16; off <<= 1) {
                #pragma unroll
                for (int r = 0; r < 4; ++r) rs[r] += __shfl_xor(rs[r], off);
            }
            #pragma unroll
            for (int r = 0; r < 4; ++r) l_r[qs][r] = l_r[qs][r] * al[r] + rs[r];
            #pragma unroll
            for (int dt = 0; dt < 4; ++dt) {
                #pragma unroll
                for (int r = 0; r < 4; ++r) oa[qs][dt][r] *= al[r];
            }
            #pragma unroll
            for (int ks = 0; ks < 2; ++ks) {
                bf16x8 pA = *(const bf16x8*)((const char*)Ps + wave * 2048 + lr * 128 +
                                             ((ks * 64 + lk * 16) ^ ((lr & 7) << 4)));
                #pragma unroll
                for (int dt = 0; dt < 4; ++dt) {
                    bf16x8 vF = *(const bf16x8*)((const char*)Vs + (dt * 16 + lr) * 128 +
                                                 ((ks * 64 + lk * 16) ^ ((lr & 7) << 4)));
                    oa[qs][dt] = __builtin_amdgcn_mfma_f32_16x16x32_bf16(pA, vF, oa[qs][dt], 0, 0, 0);
                }
            }
        }
    }
    #pragma unroll
    for (int qs = 0; qs < 2; ++qs) {
        #pragma unroll
        for (int r = 0; r < 4; ++r) {
            int l = q0 + qs * 64 + wave * 16 + g * 4 + r;
            if (l > 576) continue;
            float inv = 1.f / l_r[qs][r];
            #pragma unroll
            for (int dt = 0; dt < 4; ++dt)
                o[((long)(b * NL + l)) * DDIM + h * HDIM + dt * 16 + lr] = f2b(oa[qs][dt][r] * inv);
        }
    }
}

extern "C" void kernel_launch(void* const* d_in, const int* in_sizes, int n_in,
                              void* d_out, int out_size, void* d_ws, size_t ws_size,
                              hipStream_t stream) {
    const float* x       = (const float*)d_in[0];
    const float* patch_w = (const float*)d_in[1];
    const float* patch_b = (const float*)d_in[2];
    const float* cls     = (const float*)d_in[3];
    const float* ln1_s   = (const float*)d_in[4];
    const float* ln1_b   = (const float*)d_in[5];
    const float* qkv_w   = (const float*)d_in[6];
    const float* proj_w  = (const float*)d_in[7];
    const float* proj_b  = (const float*)d_in[8];
    const float* ln2_s   = (const float*)d_in[9];
    const float* ln2_b   = (const float*)d_in[10];
    const float* mlp_w1  = (const float*)d_in[11];
    const float* mlp_b1  = (const float*)d_in[12];
    const float* mlp_w2  = (const float*)d_in[13];
    const float* mlp_b2  = (const float*)d_in[14];
    const float* norm_s  = (const float*)d_in[15];
    const float* norm_b  = (const float*)d_in[16];

    const size_t SZ_WQ = (size_t)3 * DDIM * DDIM;
    const size_t SZ_WP = (size_t)DDIM * DDIM;
    const size_t SZ_W1 = (size_t)NHID * DDIM;
    const size_t SZ_W2 = (size_t)DDIM * NHID;

    char* w = (char*)d_ws;
    ushortT* t    = (ushortT*)w;  w += (size_t)MPAD * DDIM * 2;      // bf16 residual stream
    float* sin_t  = (float*)w;  w += (size_t)NL0 * HDIM * 4;
    float* cos_t  = (float*)w;  w += (size_t)NL0 * HDIM * 4;
    ushortT* psum = (ushortT*)w; w += (size_t)2 * MPAD * DDIM * 2;   // bf16 partials (split-K=2)
    ushortT* h_bf   = (ushortT*)w; w += (size_t)MPAD * DDIM * 2;
    ushortT* o_bf   = (ushortT*)w; w += (size_t)MPAD * DDIM * 2;
    ushortT* mlp_bf = (ushortT*)w; w += (size_t)MPAD * NHID * 2;
    ushortT* patches = mlp_bf;    // alias: disjoint lifetime (pre-loop only)
    ushortT* q_bf   = (ushortT*)w; w += (size_t)96 * LPAD * HDIM * 2;
    ushortT* k_bf   = (ushortT*)w; w += (size_t)96 * LPAD * HDIM * 2;
    ushortT* v_t    = (ushortT*)w; w += (size_t)96 * HDIM * LPAD * 2;
    ushortT* pw_bf  = (ushortT*)w; w += (size_t)DDIM * 768 * 2;
    // double-buffered per-layer weight sets
    ushortT* wqB[2]; ushortT* wpB[2]; ushortT* w1B[2]; ushortT* w2B[2];
    for (int s = 0; s < 2; ++s) {
        wqB[s] = (ushortT*)w; w += SZ_WQ * 2;
        wpB[s] = (ushortT*)w; w += SZ_WP * 2;
        w1B[s] = (ushortT*)w; w += SZ_W1 * 2;
        w2B[s] = (ushortT*)w; w += SZ_W2 * 2;
    }

    const float* nfp = nullptr;
    ushortT* nus = nullptr;
    float* nf = nullptr;

    hipLaunchKernelGGL(rope_k, dim3(NL0), dim3(64), 0, stream, sin_t, cos_t);
    hipLaunchKernelGGL(im2col_k, dim3(2048), dim3(256), 0, stream, x, patches);
    hipLaunchKernelGGL(f2b_k, dim3(512), dim3(256), 0, stream, patch_w, pw_bf, (long)DDIM * 768);
    hipLaunchKernelGGL(cls_k, dim3(NB), dim3(DDIM), 0, stream, cls, t);
    // layer-0 weights
    hipLaunchKernelGGL(wconv4_k, dim3(1024), dim3(256), 0, stream,
                       qkv_w, wqB[0], (long)SZ_WQ,
                       proj_w, wpB[0], (long)SZ_WP,
                       mlp_w1, w1B[0], (long)SZ_W1,
                       mlp_w2, w2B[0], (long)SZ_W2);
    // patch embed: 64x128 tile, 8 waves, grid 6x72; store bf16 t with remap
    hipLaunchKernelGGL((gemm_t<2, 4, 2, 2, 1, 8>), dim3(DDIM / 128, 4608 / 64), dim3(512), 0, stream,
                       patches, pw_bf, patch_b, nfp, nf, t, nfp, nfp, nus, nus, nus, nus,
                       DDIM, 768, 1 | 8 | 32);

    for (int i = 0; i < NDEPTH; ++i) {
        int cur = i & 1, nxt = (i + 1) & 1;
        if (i == 0) {
            hipLaunchKernelGGL(ln_k, dim3(MROWS), dim3(256), 0, stream,
                               t, ln1_s, ln1_b, h_bf);
        } else {
            hipLaunchKernelGGL(red_ln_k, dim3(MROWS), dim3(256), 0, stream,
                               psum, mlp_b2 + (i - 1) * DDIM, t,
                               ln1_s + i * DDIM, ln1_b + i * DDIM, h_bf);
        }
        // QKV GEMM (128x128, 8 waves) with fused RoPE + scatter (coalesced V via LDS bounce)
        hipLaunchKernelGGL((gemm_t<4, 2, 2, 4, 1, 8>), dim3((3 * DDIM) / 128, MPAD / 128), dim3(512), 0, stream,
                           h_bf, wqB[cur], nfp, nfp, nf, nus, sin_t, cos_t,
                           q_bf, k_bf, v_t, nus, 3 * DDIM, DDIM, 64);
        // attention (2 q-tiles/block, T1 head-chunking) + fused next-layer weight conversion
        long cn = (i + 1 < NDEPTH) ? 1 : 0;
        hipLaunchKernelGGL(fattn_k, dim3(96 * QT2 + NCONV), dim3(256), 0, stream,
                           q_bf, k_bf, v_t, o_bf,
                           qkv_w + SZ_WQ * (i + 1), wqB[nxt], cn * (long)SZ_WQ,
                           proj_w + SZ_WP * (i + 1), wpB[nxt], cn * (long)SZ_WP,
                           mlp_w1 + SZ_W1 * (i + 1), w1B[nxt], cn * (long)SZ_W1,
                           mlp_w2 + SZ_W2 * (i + 1), w2B[nxt], cn * (long)SZ_W2);
        // proj: 64x128 tile, 8 waves; bf16 resid read + bf16 t store
        hipLaunchKernelGGL((gemm_t<2, 4, 2, 2, 1, 8>), dim3(DDIM / 128, MPAD / 64), dim3(512), 0, stream,
                           o_bf, wpB[cur], proj_b + i * DDIM, (const float*)t, nf, t,
                           nfp, nfp, nus, nus, nus, nus,
                           DDIM, DDIM, 1 | 2 | 32 | 128);
        hipLaunchKernelGGL(ln_k, dim3(MROWS), dim3(256), 0, stream,
                           t, ln2_s + i * DDIM, ln2_b + i * DDIM, h_bf);
        // mlp1: 128x128, 8 waves
        hipLaunchKernelGGL((gemm_t<4, 2, 2, 4, 1, 8>), dim3(NHID / 128, MPAD / 128), dim3(512), 0, stream,
                           h_bf, w1B[cur], mlp_b1 + i * NHID, nfp, nf, mlp_bf, nfp, nfp,
                           nus, nus, nus, nus, NHID, DDIM, 1 | 4 | 32);
        // mlp2: split-K 2 bf16 partials, 128x128, 8 waves
        hipLaunchKernelGGL((gemm_t<4, 2, 2, 4, 2, 8>), dim3(DDIM / 128, MPAD / 128, 2), dim3(512), 0, stream,
                           mlp_bf, w2B[cur], nfp, nfp, nf, nus, nfp, nfp,
                           nus, nus, nus, psum, DDIM, NHID, 0);
    }
    // final: reduce CLS rows + final LN -> d_out
    hipLaunchKernelGGL(red_final_k, dim3(NB), dim3(256), 0, stream,
                       psum, mlp_b2 + (NDEPTH - 1) * DDIM, t, norm_s, norm_b, (float*)d_out);
}

// Round 18
// 2245.157 us; speedup vs baseline: 1.1334x; 1.0053x over previous
//
#include <hip/hip_runtime.h>
#include <math.h>

#define NB 8
#define DDIM 768
#define NHEAD 12
#define NDEPTH 12
#define HDIM 64
#define GRIDW 24
#define NL0 576
#define NL 577
#define LPAD 640
#define NHID 3072
#define MROWS (NB*NL)     // 4616
#define MPAD 4736         // 37*128, 74*64
#define EPSV 1e-5f
#define QT2 5             // q-tile PAIRS per head (2x64 rows each)
#define NCONV 512

typedef unsigned short ushortT;
typedef __attribute__((ext_vector_type(8))) short bf16x8;
typedef __attribute__((ext_vector_type(4))) float f32x4;
typedef __attribute__((ext_vector_type(4))) unsigned int u32x4;

__device__ __forceinline__ ushortT f2b(float f) {
    union { float f; unsigned u; } x; x.f = f;
    unsigned r = x.u + 0x7fffu + ((x.u >> 16) & 1u);
    return (ushortT)(r >> 16);
}

__device__ __forceinline__ float b2f(ushortT u) {
    union { unsigned u; float f; } x; x.u = ((unsigned)u) << 16;
    return x.f;
}

__device__ __forceinline__ void load_lds16(const void* g, void* l) {
    __builtin_amdgcn_global_load_lds((const __attribute__((address_space(1))) void*)g,
                                     (__attribute__((address_space(3))) void*)l, 16, 0, 0);
}

// ---------------- fp32 -> bf16 convert ----------------
__global__ void f2b_k(const float* __restrict__ in, ushortT* __restrict__ out, long n) {
    for (long i = ((long)blockIdx.x * 256 + threadIdx.x) * 4; i < n; i += (long)gridDim.x * 1024) {
        float4 v = *(const float4*)(in + i);
        ushort4 o; o.x = f2b(v.x); o.y = f2b(v.y); o.z = f2b(v.z); o.w = f2b(v.w);
        *(ushort4*)(out + i) = o;
    }
}

// ---------------- 4-array convert (preamble: layer-0 weights) ----------------
__global__ void wconv4_k(const float* __restrict__ a, ushortT* __restrict__ ao, long na,
                         const float* __restrict__ b, ushortT* __restrict__ bo, long nb,
                         const float* __restrict__ c, ushortT* __restrict__ co, long nc,
                         const float* __restrict__ d, ushortT* __restrict__ dd, long nd) {
    long stride = (long)gridDim.x * 1024;
    long i0 = ((long)blockIdx.x * 256 + threadIdx.x) * 4;
    for (long i = i0; i < na; i += stride) {
        float4 v = *(const float4*)(a + i);
        ushort4 o; o.x = f2b(v.x); o.y = f2b(v.y); o.z = f2b(v.z); o.w = f2b(v.w);
        *(ushort4*)(ao + i) = o;
    }
    for (long i = i0; i < nb; i += stride) {
        float4 v = *(const float4*)(b + i);
        ushort4 o; o.x = f2b(v.x); o.y = f2b(v.y); o.z = f2b(v.z); o.w = f2b(v.w);
        *(ushort4*)(bo + i) = o;
    }
    for (long i = i0; i < nc; i += stride) {
        float4 v = *(const float4*)(c + i);
        ushort4 o; o.x = f2b(v.x); o.y = f2b(v.y); o.z = f2b(v.z); o.w = f2b(v.w);
        *(ushort4*)(co + i) = o;
    }
    for (long i = i0; i < nd; i += stride) {
        float4 v = *(const float4*)(d + i);
        ushort4 o; o.x = f2b(v.x); o.y = f2b(v.y); o.z = f2b(v.z); o.w = f2b(v.w);
        *(ushort4*)(dd + i) = o;
    }
}

// ---------------- im2col -> bf16 patches[4608, 768] ----------------
__global__ void im2col_k(const float* __restrict__ x, ushortT* __restrict__ p) {
    for (long idx = (long)blockIdx.x * 256 + threadIdx.x; idx < (long)4608 * 768; idx += (long)gridDim.x * 256) {
        int row = (int)(idx / 768), col = (int)(idx - (long)row * 768);
        int b = row / NL0, pi = row - b * NL0;
        int gy = pi / GRIDW, gx = pi - gy * GRIDW;
        int c = col >> 8, r = col & 255;
        int py = r >> 4, px = r & 15;
        p[idx] = f2b(x[(((long)(b * 3 + c) * 384) + gy * 16 + py) * 384 + gx * 16 + px]);
    }
}

__global__ void cls_k(const float* __restrict__ cls, ushortT* __restrict__ t) {
    t[(long)blockIdx.x * NL * DDIM + threadIdx.x] = f2b(cls[threadIdx.x]);
}

__global__ void rope_k(float* __restrict__ sin_t, float* __restrict__ cos_t) {
    int pos = blockIdx.x, d = threadIdx.x;
    int gy = pos / GRIDW, gx = pos - gy * GRIDW;
    int j = d >> 1;
    float ang;
    if (j < 16) ang = (float)gy * powf(10000.f, -(float)j / 16.f);
    else        ang = (float)gx * powf(10000.f, -(float)(j - 16) / 16.f);
    sin_t[pos * 64 + d] = sinf(ang);
    cos_t[pos * 64 + d] = cosf(ang);
}

// ---------------- LayerNorm over bf16 input (layer-0 ln1 and all ln2) ----------------
__global__ __launch_bounds__(256) void ln_k(const ushortT* __restrict__ in,
                                            const float* __restrict__ sc,
                                            const float* __restrict__ bi,
                                            ushortT* __restrict__ outb) {
    int row = blockIdx.x;
    const ushortT* ip = in + (size_t)row * DDIM;
    float x[3];
    float s = 0.f, s2 = 0.f;
    #pragma unroll
    for (int i = 0; i < 3; ++i) {
        x[i] = b2f(ip[threadIdx.x + i * 256]);
        s += x[i]; s2 += x[i] * x[i];
    }
    __shared__ float red0[256], red1[256];
    red0[threadIdx.x] = s; red1[threadIdx.x] = s2;
    __syncthreads();
    for (int off = 128; off; off >>= 1) {
        if (threadIdx.x < off) {
            red0[threadIdx.x] += red0[threadIdx.x + off];
            red1[threadIdx.x] += red1[threadIdx.x + off];
        }
        __syncthreads();
    }
    float mean = red0[0] * (1.f / 768.f);
    float var  = red1[0] * (1.f / 768.f) - mean * mean;
    float inv = rsqrtf(var + EPSV);
    #pragma unroll
    for (int i = 0; i < 3; ++i) {
        int c = threadIdx.x + i * 256;
        outb[(size_t)row * DDIM + c] = f2b((x[i] - mean) * inv * sc[c] + bi[c]);
    }
}

// ---------------- fused: t += mlp2_bias + sum2(bf16 psum); then LN1(next layer) -> h_bf ----------------
__global__ __launch_bounds__(256) void red_ln_k(const ushortT* __restrict__ psum,
                                                const float* __restrict__ b2,
                                                ushortT* __restrict__ t,
                                                const float* __restrict__ sc,
                                                const float* __restrict__ bi,
                                                ushortT* __restrict__ outb) {
    int row = blockIdx.x;
    const size_t S = (size_t)MPAD * DDIM;
    const size_t rb = (size_t)row * DDIM;
    float x[3];
    float s = 0.f, s2 = 0.f;
    #pragma unroll
    for (int i = 0; i < 3; ++i) {
        int c = threadIdx.x + i * 256;
        float v = b2f(t[rb + c]) + b2[c] + b2f(psum[rb + c]) + b2f(psum[S + rb + c]);
        x[i] = v; s += v; s2 += v * v;
        t[rb + c] = f2b(v);
    }
    __shared__ float red0[256], red1[256];
    red0[threadIdx.x] = s; red1[threadIdx.x] = s2;
    __syncthreads();
    for (int off = 128; off; off >>= 1) {
        if (threadIdx.x < off) {
            red0[threadIdx.x] += red0[threadIdx.x + off];
            red1[threadIdx.x] += red1[threadIdx.x + off];
        }
        __syncthreads();
    }
    float mean = red0[0] * (1.f / 768.f);
    float var  = red1[0] * (1.f / 768.f) - mean * mean;
    float inv = rsqrtf(var + EPSV);
    #pragma unroll
    for (int i = 0; i < 3; ++i) {
        int c = threadIdx.x + i * 256;
        outb[rb + c] = f2b((x[i] - mean) * inv * sc[c] + bi[c]);
    }
}

// ---------------- final: reduce CLS rows only + final LN -> d_out[8,768] f32 ----------------
__global__ __launch_bounds__(256) void red_final_k(const ushortT* __restrict__ psum,
                                                   const float* __restrict__ b2,
                                                   const ushortT* __restrict__ t,
                                                   const float* __restrict__ sc,
                                                   const float* __restrict__ bi,
                                                   float* __restrict__ outf) {
    int row = blockIdx.x * NL;            // CLS row of batch blockIdx.x
    const size_t S = (size_t)MPAD * DDIM;
    const size_t rb = (size_t)row * DDIM;
    float x[3];
    float s = 0.f, s2 = 0.f;
    #pragma unroll
    for (int i = 0; i < 3; ++i) {
        int c = threadIdx.x + i * 256;
        float v = b2f(t[rb + c]) + b2[c] + b2f(psum[rb + c]) + b2f(psum[S + rb + c]);
        x[i] = v; s += v; s2 += v * v;
    }
    __shared__ float red0[256], red1[256];
    red0[threadIdx.x] = s; red1[threadIdx.x] = s2;
    __syncthreads();
    for (int off = 128; off; off >>= 1) {
        if (threadIdx.x < off) {
            red0[threadIdx.x] += red0[threadIdx.x + off];
            red1[threadIdx.x] += red1[threadIdx.x + off];
        }
        __syncthreads();
    }
    float mean = red0[0] * (1.f / 768.f);
    float var  = red1[0] * (1.f / 768.f) - mean * mean;
    float inv = rsqrtf(var + EPSV);
    #pragma unroll
    for (int i = 0; i < 3; ++i) {
        int c = threadIdx.x + i * 256;
        outf[(long)blockIdx.x * 768 + c] = (x[i] - mean) * inv * sc[c] + bi[c];
    }
}

// ---------------- templated bf16 MFMA GEMM (2-stage dbuf, NW waves) ----------------
// flags: 1=bias 2=resid 4=gelu 8=remap 16=store f32 32=store bf16 64=qkv mode
//        128=resid is bf16 (residual-stream)
template<int WR, int WC, int MI, int NI, int SPLITK, int NW>
__global__ __launch_bounds__(NW * 64) void gemm_t(const ushortT* __restrict__ A,
                                                  const ushortT* __restrict__ W,
                                                  const float* __restrict__ bias,
                                                  const float* __restrict__ resid,
                                                  float* __restrict__ Cf,
                                                  ushortT* __restrict__ Cb,
                                                  const float* __restrict__ sinT,
                                                  const float* __restrict__ cosT,
                                                  ushortT* __restrict__ qo,
                                                  ushortT* __restrict__ ko,
                                                  ushortT* __restrict__ vo,
                                                  ushortT* __restrict__ psum,
                                                  int N, int K, int flags) {
    constexpr int BM = WR * MI * 16;
    constexpr int BN = WC * NI * 16;
    constexpr int THREADS = NW * 64;
    constexpr int ACH = (BM * 64) / (THREADS * 8);
    constexpr int BCH = (BN * 64) / (THREADS * 8);
    __shared__ ushortT As[2][BM * 64];
    __shared__ ushortT Bs[2][BN * 64];
    int tid = threadIdx.x;
    int lane = tid & 63, wid = tid >> 6;
    int wm = wid / WC, wn = wid % WC;
    int lr = lane & 15, lk = lane >> 4;
    int nwg = gridDim.x * gridDim.y;
    int flat = blockIdx.y * gridDim.x + blockIdx.x;
    int qq = nwg >> 3, rr = nwg & 7;
    int xcd = flat & 7, idx = flat >> 3;
    int wg = (xcd < rr ? xcd * (qq + 1) : rr * (qq + 1) + (xcd - rr) * qq) + idx;
    int bx = wg % gridDim.x, by = wg / gridDim.x;
    int m0 = by * BM, n0 = bx * BN;
    int kspan = K / SPLITK;
    int k0 = (SPLITK > 1) ? blockIdx.z * kspan : 0;
    f32x4 acc[MI][NI] = {};

    auto stage = [&](int buf, int kt) {
        #pragma unroll
        for (int i = 0; i < ACH; ++i) {
            int ch = i * THREADS + tid;
            int r = ch >> 3, cb = (ch & 7) * 16;
            int cbs = cb ^ ((r & 7) << 4);
            load_lds16(A + (size_t)(m0 + r) * K + kt + (cbs >> 1), &As[buf][ch * 8]);
        }
        #pragma unroll
        for (int i = 0; i < BCH; ++i) {
            int ch = i * THREADS + tid;
            int r = ch >> 3, cb = (ch & 7) * 16;
            int cbs = cb ^ ((r & 7) << 4);
            load_lds16(W + (size_t)(n0 + r) * K + kt + (cbs >> 1), &Bs[buf][ch * 8]);
        }
    };

    stage(0, k0);
    asm volatile("s_waitcnt vmcnt(0)" ::: "memory");
    __builtin_amdgcn_s_barrier();
    int nk = kspan / 64;
    int cur = 0;
    for (int it = 0; it < nk; ++it) {
        if (it + 1 < nk) stage(cur ^ 1, k0 + (it + 1) * 64);
        #pragma unroll
        for (int ks = 0; ks < 2; ++ks) {
            bf16x8 aF[MI], bF[NI];
            #pragma unroll
            for (int mi = 0; mi < MI; ++mi) {
                int row = wm * MI * 16 + mi * 16 + lr;
                aF[mi] = *(const bf16x8*)((const char*)&As[cur][0] + row * 128 +
                                          ((ks * 64 + lk * 16) ^ ((row & 7) << 4)));
            }
            #pragma unroll
            for (int ni = 0; ni < NI; ++ni) {
                int row = wn * NI * 16 + ni * 16 + lr;
                bF[ni] = *(const bf16x8*)((const char*)&Bs[cur][0] + row * 128 +
                                          ((ks * 64 + lk * 16) ^ ((row & 7) << 4)));
            }
            #pragma unroll
            for (int mi = 0; mi < MI; ++mi)
                #pragma unroll
                for (int ni = 0; ni < NI; ++ni)
                    acc[mi][ni] = __builtin_amdgcn_mfma_f32_16x16x32_bf16(aF[mi], bF[ni], acc[mi][ni], 0, 0, 0);
        }
        asm volatile("s_waitcnt vmcnt(0)" ::: "memory");
        __builtin_amdgcn_s_barrier();
        cur ^= 1;
    }

    if (SPLITK > 1) {
        #pragma unroll
        for (int mi = 0; mi < MI; ++mi) {
            int rbase = m0 + wm * MI * 16 + mi * 16 + (lane >> 4) * 4;
            #pragma unroll
            for (int ni = 0; ni < NI; ++ni) {
                int c = n0 + wn * NI * 16 + ni * 16 + lr;
                #pragma unroll
                for (int r = 0; r < 4; ++r)
                    psum[((size_t)blockIdx.z * MPAD + rbase + r) * N + c] = f2b(acc[mi][ni][r]);
            }
        }
        return;
    }
    if (flags & 64) {
        if constexpr (NI == 4 && BN == 128) {
            int selB = n0 / DDIM;      // 768 % 128 == 0: block lies wholly in q, k, or v
            if (selB == 2) {
                // V block: bounce through LDS (reuse As) for coalesced transposed writes.
                ushortT* vtile = &As[0][0];
                #pragma unroll
                for (int mi = 0; mi < MI; ++mi) {
                    #pragma unroll
                    for (int ni = 0; ni < NI; ++ni) {
                        #pragma unroll
                        for (int r = 0; r < 4; ++r) {
                            int ll = wm * MI * 16 + mi * 16 + (lane >> 4) * 4 + r;
                            int dl = wn * 64 + ni * 16 + lr;
                            vtile[dl * BM + (ll ^ ((dl & 7) << 4))] = f2b(acc[mi][ni][r]);
                        }
                    }
                }
                __syncthreads();
                for (int e = tid; e < 128 * BM; e += THREADS) {
                    int dl = e / BM, ll = e - dl * BM;
                    int row = m0 + ll;
                    if (row < MROWS) {
                        int b = row / NL, l = row - b * NL;
                        int cv = (n0 - 2 * DDIM) + dl;
                        int h = cv >> 6, d = cv & 63;
                        int bh = b * NHEAD + h;
                        vo[((long)bh * HDIM + d) * LPAD + l] = vtile[dl * BM + (ll ^ ((dl & 7) << 4))];
                    }
                }
            } else {
                #pragma unroll
                for (int mi = 0; mi < MI; ++mi) {
                    #pragma unroll
                    for (int r = 0; r < 4; ++r) {
                        int row = m0 + wm * MI * 16 + mi * 16 + (lane >> 4) * 4 + r;
                        if (row >= MROWS) continue;
                        int b = row / NL, l = row - b * NL;
                        #pragma unroll
                        for (int ni = 0; ni < NI; ++ni) {
                            int c = n0 + wn * 64 + ni * 16 + lr;
                            float val = acc[mi][ni][r];
                            int sel = c / DDIM;
                            int cc = c - sel * DDIM;
                            int h = cc >> 6, d = cc & 63;
                            if (l > 0) {
                                int pos = l - 1;
                                float cs = cosT[pos * 64 + d], sn = sinT[pos * 64 + d];
                                float partner = acc[mi][ni ^ 2][r];
                                float rh = (d < 32) ? -partner : partner;
                                val = val * cs + rh * sn;
                            }
                            int bh = b * NHEAD + h;
                            if (sel == 0) qo[((long)bh * LPAD + l) * HDIM + d] = f2b(val * 0.125f);
                            else          ko[((long)bh * LPAD + l) * HDIM + d] = f2b(val);
                        }
                    }
                }
            }
        }
        return;
    }
    #pragma unroll
    for (int mi = 0; mi < MI; ++mi) {
        int rbase = m0 + wm * MI * 16 + mi * 16 + (lane >> 4) * 4;
        #pragma unroll
        for (int ni = 0; ni < NI; ++ni) {
            int c = n0 + wn * NI * 16 + ni * 16 + lr;
            float bv = (flags & 1) ? bias[c] : 0.f;
            #pragma unroll
            for (int r = 0; r < 4; ++r) {
                int row = rbase + r;
                float val = acc[mi][ni][r] + bv;
                if (flags & 4) val = 0.5f * val * (1.f + erff(val * 0.70710678118654752f));
                long orow = row;
                if (flags & 8) orow = (long)(row / NL0) * NL + 1 + (row % NL0);
                if (flags & 2) {
                    if (flags & 128) val += b2f(((const ushortT*)resid)[orow * (long)N + c]);
                    else             val += resid[orow * (long)N + c];
                }
                if (flags & 16) Cf[orow * (long)N + c] = val;
                if (flags & 32) Cb[orow * (long)N + c] = f2b(val);
            }
        }
    }
}

// ---------------- MFMA flash attention: 2 q-tiles per block + fused weight conversion ----------------
// T1 head-chunking (480 = 8*60). T14 async-STAGE: next K/V tile loaded into
// registers BEFORE compute (latency hides under MFMA+softmax); ds_write between
// barriers replaces the serial global_load_lds + vmcnt(0) drain.
__global__ __launch_bounds__(256) void fattn_k(const ushortT* __restrict__ q,
                                               const ushortT* __restrict__ k,
                                               const ushortT* __restrict__ vt,
                                               ushortT* __restrict__ o,
                                               const float* __restrict__ wa, ushortT* __restrict__ wao, long na,
                                               const float* __restrict__ wb, ushortT* __restrict__ wbo, long nbn,
                                               const float* __restrict__ wc, ushortT* __restrict__ wco, long nc,
                                               const float* __restrict__ wd, ushortT* __restrict__ wdo, long nd) {
    if (blockIdx.x >= 96 * QT2) {
        int cid = blockIdx.x - 96 * QT2;
        long stride = (long)NCONV * 1024;
        long i0 = ((long)cid * 256 + threadIdx.x) * 4;
        for (long i = i0; i < na; i += stride) {
            float4 v = *(const float4*)(wa + i);
            ushort4 t4; t4.x = f2b(v.x); t4.y = f2b(v.y); t4.z = f2b(v.z); t4.w = f2b(v.w);
            *(ushort4*)(wao + i) = t4;
        }
        for (long i = i0; i < nbn; i += stride) {
            float4 v = *(const float4*)(wb + i);
            ushort4 t4; t4.x = f2b(v.x); t4.y = f2b(v.y); t4.z = f2b(v.z); t4.w = f2b(v.w);
            *(ushort4*)(wbo + i) = t4;
        }
        for (long i = i0; i < nc; i += stride) {
            float4 v = *(const float4*)(wc + i);
            ushort4 t4; t4.x = f2b(v.x); t4.y = f2b(v.y); t4.z = f2b(v.z); t4.w = f2b(v.w);
            *(ushort4*)(wco + i) = t4;
        }
        for (long i = i0; i < nd; i += stride) {
            float4 v = *(const float4*)(wd + i);
            ushort4 t4; t4.x = f2b(v.x); t4.y = f2b(v.y); t4.z = f2b(v.z); t4.w = f2b(v.w);
            *(ushort4*)(wdo + i) = t4;
        }
        return;
    }
    int flat = blockIdx.x;
    int wg = (flat & 7) * 60 + (flat >> 3);
    __shared__ ushortT Qs[2][4096], Ks[4096], Vs[4096], Ps[4096];
    int tid = threadIdx.x;
    int wave = tid >> 6, lane = tid & 63;
    int lr = lane & 15, lk = lane >> 4, g = lk;
    int bh = wg / QT2, qp = wg % QT2;
    int q0 = qp * 128;
    int b = bh / NHEAD, h = bh - b * NHEAD;
    int l8 = lane >> 3, c16 = lane & 7;
    int colsw = (c16 * 16) ^ ((l8 & 7) << 4);

    #pragma unroll
    for (int qs = 0; qs < 2; ++qs) {
        const ushortT* src = q + ((long)bh * LPAD + q0 + qs * 64) * HDIM;
        #pragma unroll
        for (int j = 0; j < 2; ++j) {
            int row = wave * 16 + j * 8 + l8;
            load_lds16(src + (long)row * HDIM + (colsw >> 1), Qs[qs] + wave * 1024 + j * 512);
        }
    }
    // prologue: tile 0 K/V into registers (latency overlaps Q staging + qF setup)
    u32x4 kr[2], vr[2];
    {
        const ushortT* srck = k + (long)bh * LPAD * HDIM;
        const ushortT* srcv = vt + (long)bh * HDIM * LPAD;
        #pragma unroll
        for (int j = 0; j < 2; ++j) {
            int row = wave * 16 + j * 8 + l8;
            kr[j] = *(const u32x4*)(srck + (long)row * HDIM + (colsw >> 1));
            vr[j] = *(const u32x4*)(srcv + (long)row * LPAD + (colsw >> 1));
        }
    }
    __syncthreads();
    bf16x8 qF[2][2];
    #pragma unroll
    for (int qs = 0; qs < 2; ++qs)
        #pragma unroll
        for (int ks = 0; ks < 2; ++ks) {
            int row = wave * 16 + lr;
            qF[qs][ks] = *(const bf16x8*)((const char*)Qs[qs] + row * 128 +
                                          ((ks * 64 + lk * 16) ^ ((lr & 7) << 4)));
        }
    f32x4 oa[2][4] = {};
    float m_r[2][4], l_r[2][4];
    #pragma unroll
    for (int qs = 0; qs < 2; ++qs)
        #pragma unroll
        for (int r = 0; r < 4; ++r) { m_r[qs][r] = -3e38f; l_r[qs][r] = 0.f; }

    for (int t0 = 0; t0 < 10; ++t0) {
        // write current K/V regs to LDS (same bytes/layout global_load_lds produced)
        #pragma unroll
        for (int j = 0; j < 2; ++j) {
            *(u32x4*)((char*)Ks + wave * 2048 + j * 1024 + lane * 16) = kr[j];
            *(u32x4*)((char*)Vs + wave * 2048 + j * 1024 + lane * 16) = vr[j];
        }
        __syncthreads();
        // issue next tile's loads BEFORE compute (T14: latency hides under MFMA/softmax)
        if (t0 + 1 < 10) {
            int k1 = (t0 + 1) * 64;
            const ushortT* srck = k + ((long)bh * LPAD + k1) * HDIM;
            const ushortT* srcv = vt + (long)bh * HDIM * LPAD + k1;
            #pragma unroll
            for (int j = 0; j < 2; ++j) {
                int row = wave * 16 + j * 8 + l8;
                kr[j] = *(const u32x4*)(srck + (long)row * HDIM + (colsw >> 1));
                vr[j] = *(const u32x4*)(srcv + (long)row * LPAD + (colsw >> 1));
            }
        }
        int k0 = t0 * 64;
        #pragma unroll
        for (int qs = 0; qs < 2; ++qs) {
            f32x4 s[4] = {};
            #pragma unroll
            for (int ks = 0; ks < 2; ++ks) {
                #pragma unroll
                for (int kt = 0; kt < 4; ++kt) {
                    int row = kt * 16 + lr;
                    bf16x8 kF = *(const bf16x8*)((const char*)Ks + row * 128 +
                                                 ((ks * 64 + lk * 16) ^ ((lr & 7) << 4)));
                    s[kt] = __builtin_amdgcn_mfma_f32_16x16x32_bf16(qF[qs][ks], kF, s[kt], 0, 0, 0);
                }
            }
            if (k0 + 63 > 576) {
                #pragma unroll
                for (int kt = 0; kt < 4; ++kt)
                    if (k0 + kt * 16 + lr > 576) {
                        #pragma unroll
                        for (int r = 0; r < 4; ++r) s[kt][r] = -3e38f;
                    }
            }
            float mx[4], al[4], rs[4];
            #pragma unroll
            for (int r = 0; r < 4; ++r)
                mx[r] = fmaxf(fmaxf(s[0][r], s[1][r]), fmaxf(s[2][r], s[3][r]));
            #pragma unroll
            for (int off = 1; off < 16; off <<= 1) {
                #pragma unroll
                for (int r = 0; r < 4; ++r) mx[r] = fmaxf(mx[r], __shfl_xor(mx[r], off));
            }
            #pragma unroll
            for (int r = 0; r < 4; ++r) {
                float mn = fmaxf(m_r[qs][r], mx[r]);
                al[r] = __expf(m_r[qs][r] - mn);
                m_r[qs][r] = mn;
                rs[r] = 0.f;
            }
            #pragma unroll
            for (int kt = 0; kt < 4; ++kt) {
                #pragma unroll
                for (int r = 0; r < 4; ++r) {
                    float p = __expf(s[kt][r] - m_r[qs][r]);
                    rs[r] += p;
                    int rowp = g * 4 + r;
                    *(ushortT*)((char*)Ps + wave * 2048 + rowp * 128 +
                                ((kt * 32 + lr * 2) ^ ((rowp & 7) << 4))) = f2b(p);
                }
            }
            #pragma unroll
            for (int off = 1; off < 16; off <<= 1) {
                #pragma unroll
                for (int r = 0; r < 4; ++r) rs[r] += __shfl_xor(rs[r], off);
            }
            #pragma unroll
            for (int r = 0; r < 4; ++r) l_r[qs][r] = l_r[qs][r] * al[r] + rs[r];
            #pragma unroll
            for (int dt = 0; dt < 4; ++dt) {
                #pragma unroll
                for (int r = 0; r < 4; ++r) oa[qs][dt][r] *= al[r];
            }
            #pragma unroll
            for (int ks = 0; ks < 2; ++ks) {
                bf16x8 pA = *(const bf16x8*)((const char*)Ps + wave * 2048 + lr * 128 +
                                             ((ks * 64 + lk * 16) ^ ((lr & 7) << 4)));
                #pragma unroll
                for (int dt = 0; dt < 4; ++dt) {
                    bf16x8 vF = *(const bf16x8*)((const char*)Vs + (dt * 16 + lr) * 128 +
                                                 ((ks * 64 + lk * 16) ^ ((lr & 7) << 4)));
                    oa[qs][dt] = __builtin_amdgcn_mfma_f32_16x16x32_bf16(pA, vF, oa[qs][dt], 0, 0, 0);
                }
            }
        }
        __syncthreads();   // all reads of Ks/Vs done before next iteration's ds_write
    }
    #pragma unroll
    for (int qs = 0; qs < 2; ++qs) {
        #pragma unroll
        for (int r = 0; r < 4; ++r) {
            int l = q0 + qs * 64 + wave * 16 + g * 4 + r;
            if (l > 576) continue;
            float inv = 1.f / l_r[qs][r];
            #pragma unroll
            for (int dt = 0; dt < 4; ++dt)
                o[((long)(b * NL + l)) * DDIM + h * HDIM + dt * 16 + lr] = f2b(oa[qs][dt][r] * inv);
        }
    }
}

extern "C" void kernel_launch(void* const* d_in, const int* in_sizes, int n_in,
                              void* d_out, int out_size, void* d_ws, size_t ws_size,
                              hipStream_t stream) {
    const float* x       = (const float*)d_in[0];
    const float* patch_w = (const float*)d_in[1];
    const float* patch_b = (const float*)d_in[2];
    const float* cls     = (const float*)d_in[3];
    const float* ln1_s   = (const float*)d_in[4];
    const float* ln1_b   = (const float*)d_in[5];
    const float* qkv_w   = (const float*)d_in[6];
    const float* proj_w  = (const float*)d_in[7];
    const float* proj_b  = (const float*)d_in[8];
    const float* ln2_s   = (const float*)d_in[9];
    const float* ln2_b   = (const float*)d_in[10];
    const float* mlp_w1  = (const float*)d_in[11];
    const float* mlp_b1  = (const float*)d_in[12];
    const float* mlp_w2  = (const float*)d_in[13];
    const float* mlp_b2  = (const float*)d_in[14];
    const float* norm_s  = (const float*)d_in[15];
    const float* norm_b  = (const float*)d_in[16];

    const size_t SZ_WQ = (size_t)3 * DDIM * DDIM;
    const size_t SZ_WP = (size_t)DDIM * DDIM;
    const size_t SZ_W1 = (size_t)NHID * DDIM;
    const size_t SZ_W2 = (size_t)DDIM * NHID;

    char* w = (char*)d_ws;
    ushortT* t    = (ushortT*)w;  w += (size_t)MPAD * DDIM * 2;      // bf16 residual stream
    float* sin_t  = (float*)w;  w += (size_t)NL0 * HDIM * 4;
    float* cos_t  = (float*)w;  w += (size_t)NL0 * HDIM * 4;
    ushortT* psum = (ushortT*)w; w += (size_t)2 * MPAD * DDIM * 2;   // bf16 partials (split-K=2)
    ushortT* h_bf   = (ushortT*)w; w += (size_t)MPAD * DDIM * 2;
    ushortT* o_bf   = (ushortT*)w; w += (size_t)MPAD * DDIM * 2;
    ushortT* mlp_bf = (ushortT*)w; w += (size_t)MPAD * NHID * 2;
    ushortT* patches = mlp_bf;    // alias: disjoint lifetime (pre-loop only)
    ushortT* q_bf   = (ushortT*)w; w += (size_t)96 * LPAD * HDIM * 2;
    ushortT* k_bf   = (ushortT*)w; w += (size_t)96 * LPAD * HDIM * 2;
    ushortT* v_t    = (ushortT*)w; w += (size_t)96 * HDIM * LPAD * 2;
    ushortT* pw_bf  = (ushortT*)w; w += (size_t)DDIM * 768 * 2;
    // double-buffered per-layer weight sets
    ushortT* wqB[2]; ushortT* wpB[2]; ushortT* w1B[2]; ushortT* w2B[2];
    for (int s = 0; s < 2; ++s) {
        wqB[s] = (ushortT*)w; w += SZ_WQ * 2;
        wpB[s] = (ushortT*)w; w += SZ_WP * 2;
        w1B[s] = (ushortT*)w; w += SZ_W1 * 2;
        w2B[s] = (ushortT*)w; w += SZ_W2 * 2;
    }

    const float* nfp = nullptr;
    ushortT* nus = nullptr;
    float* nf = nullptr;

    hipLaunchKernelGGL(rope_k, dim3(NL0), dim3(64), 0, stream, sin_t, cos_t);
    hipLaunchKernelGGL(im2col_k, dim3(2048), dim3(256), 0, stream, x, patches);
    hipLaunchKernelGGL(f2b_k, dim3(512), dim3(256), 0, stream, patch_w, pw_bf, (long)DDIM * 768);
    hipLaunchKernelGGL(cls_k, dim3(NB), dim3(DDIM), 0, stream, cls, t);
    // layer-0 weights
    hipLaunchKernelGGL(wconv4_k, dim3(1024), dim3(256), 0, stream,
                       qkv_w, wqB[0], (long)SZ_WQ,
                       proj_w, wpB[0], (long)SZ_WP,
                       mlp_w1, w1B[0], (long)SZ_W1,
                       mlp_w2, w2B[0], (long)SZ_W2);
    // patch embed: 64x128 tile, 8 waves, grid 6x72; store bf16 t with remap
    hipLaunchKernelGGL((gemm_t<2, 4, 2, 2, 1, 8>), dim3(DDIM / 128, 4608 / 64), dim3(512), 0, stream,
                       patches, pw_bf, patch_b, nfp, nf, t, nfp, nfp, nus, nus, nus, nus,
                       DDIM, 768, 1 | 8 | 32);

    for (int i = 0; i < NDEPTH; ++i) {
        int cur = i & 1, nxt = (i + 1) & 1;
        if (i == 0) {
            hipLaunchKernelGGL(ln_k, dim3(MROWS), dim3(256), 0, stream,
                               t, ln1_s, ln1_b, h_bf);
        } else {
            hipLaunchKernelGGL(red_ln_k, dim3(MROWS), dim3(256), 0, stream,
                               psum, mlp_b2 + (i - 1) * DDIM, t,
                               ln1_s + i * DDIM, ln1_b + i * DDIM, h_bf);
        }
        // QKV GEMM (128x128, 8 waves) with fused RoPE + scatter (coalesced V via LDS bounce)
        hipLaunchKernelGGL((gemm_t<4, 2, 2, 4, 1, 8>), dim3((3 * DDIM) / 128, MPAD / 128), dim3(512), 0, stream,
                           h_bf, wqB[cur], nfp, nfp, nf, nus, sin_t, cos_t,
                           q_bf, k_bf, v_t, nus, 3 * DDIM, DDIM, 64);
        // attention (2 q-tiles/block, T1 head-chunking, T14 async-stage) + fused weight conversion
        long cn = (i + 1 < NDEPTH) ? 1 : 0;
        hipLaunchKernelGGL(fattn_k, dim3(96 * QT2 + NCONV), dim3(256), 0, stream,
                           q_bf, k_bf, v_t, o_bf,
                           qkv_w + SZ_WQ * (i + 1), wqB[nxt], cn * (long)SZ_WQ,
                           proj_w + SZ_WP * (i + 1), wpB[nxt], cn * (long)SZ_WP,
                           mlp_w1 + SZ_W1 * (i + 1), w1B[nxt], cn * (long)SZ_W1,
                           mlp_w2 + SZ_W2 * (i + 1), w2B[nxt], cn * (long)SZ_W2);
        // proj: 64x128 tile, 8 waves; bf16 resid read + bf16 t store
        hipLaunchKernelGGL((gemm_t<2, 4, 2, 2, 1, 8>), dim3(DDIM / 128, MPAD / 64), dim3(512), 0, stream,
                           o_bf, wpB[cur], proj_b + i * DDIM, (const float*)t, nf, t,
                           nfp, nfp, nus, nus, nus, nus,
                           DDIM, DDIM, 1 | 2 | 32 | 128);
        hipLaunchKernelGGL(ln_k, dim3(MROWS), dim3(256), 0, stream,
                           t, ln2_s + i * DDIM, ln2_b + i * DDIM, h_bf);
        // mlp1: 128x128, 8 waves
        hipLaunchKernelGGL((gemm_t<4, 2, 2, 4, 1, 8>), dim3(NHID / 128, MPAD / 128), dim3(512), 0, stream,
                           h_bf, w1B[cur], mlp_b1 + i * NHID, nfp, nf, mlp_bf, nfp, nfp,
                           nus, nus, nus, nus, NHID, DDIM, 1 | 4 | 32);
        // mlp2: split-K 2 bf16 partials, 128x128, 8 waves
        hipLaunchKernelGGL((gemm_t<4, 2, 2, 4, 2, 8>), dim3(DDIM / 128, MPAD / 128, 2), dim3(512), 0, stream,
                           mlp_bf, w2B[cur], nfp, nfp, nf, nus, nfp, nfp,
                           nus, nus, nus, psum, DDIM, NHID, 0);
    }
    // final: reduce CLS rows + final LN -> d_out
    hipLaunchKernelGGL(red_final_k, dim3(NB), dim3(256), 0, stream,
                       psum, mlp_b2 + (NDEPTH - 1) * DDIM, t, norm_s, norm_b, (float*)d_out);
}

// Round 19
// 2229.762 us; speedup vs baseline: 1.1413x; 1.0069x over previous
//
#include <hip/hip_runtime.h>
#include <math.h>

#define NB 8
#define DDIM 768
#define NHEAD 12
#define NDEPTH 12
#define HDIM 64
#define GRIDW 24
#define NL0 576
#define NL 577
#define LPAD 640
#define NHID 3072
#define MROWS (NB*NL)     // 4616
#define MPAD 4736         // 37*128, 74*64
#define EPSV 1e-5f
#define QT2 5             // q-tile PAIRS per head (2x64 rows each)
#define NCONV 512

typedef unsigned short ushortT;
typedef __attribute__((ext_vector_type(8))) short bf16x8;
typedef __attribute__((ext_vector_type(4))) float f32x4;
typedef __attribute__((ext_vector_type(4))) unsigned int u32x4;

__device__ __forceinline__ ushortT f2b(float f) {
    union { float f; unsigned u; } x; x.f = f;
    unsigned r = x.u + 0x7fffu + ((x.u >> 16) & 1u);
    return (ushortT)(r >> 16);
}

__device__ __forceinline__ float b2f(ushortT u) {
    union { unsigned u; float f; } x; x.u = ((unsigned)u) << 16;
    return x.f;
}

__device__ __forceinline__ void unpack8(u32x4 v, float* x) {
    #pragma unroll
    for (int i = 0; i < 4; ++i) {
        union { unsigned u; float f; } lo, hi;
        lo.u = v[i] << 16;
        hi.u = v[i] & 0xffff0000u;
        x[2 * i] = lo.f; x[2 * i + 1] = hi.f;
    }
}

__device__ __forceinline__ u32x4 pack8(const float* x) {
    u32x4 v;
    #pragma unroll
    for (int i = 0; i < 4; ++i)
        v[i] = (unsigned)f2b(x[2 * i]) | ((unsigned)f2b(x[2 * i + 1]) << 16);
    return v;
}

__device__ __forceinline__ void load_lds16(const void* g, void* l) {
    __builtin_amdgcn_global_load_lds((const __attribute__((address_space(1))) void*)g,
                                     (__attribute__((address_space(3))) void*)l, 16, 0, 0);
}

// ---------------- fp32 -> bf16 convert ----------------
__global__ void f2b_k(const float* __restrict__ in, ushortT* __restrict__ out, long n) {
    for (long i = ((long)blockIdx.x * 256 + threadIdx.x) * 4; i < n; i += (long)gridDim.x * 1024) {
        float4 v = *(const float4*)(in + i);
        ushort4 o; o.x = f2b(v.x); o.y = f2b(v.y); o.z = f2b(v.z); o.w = f2b(v.w);
        *(ushort4*)(out + i) = o;
    }
}

// ---------------- 4-array convert (preamble: layer-0 weights) ----------------
__global__ void wconv4_k(const float* __restrict__ a, ushortT* __restrict__ ao, long na,
                         const float* __restrict__ b, ushortT* __restrict__ bo, long nb,
                         const float* __restrict__ c, ushortT* __restrict__ co, long nc,
                         const float* __restrict__ d, ushortT* __restrict__ dd, long nd) {
    long stride = (long)gridDim.x * 1024;
    long i0 = ((long)blockIdx.x * 256 + threadIdx.x) * 4;
    for (long i = i0; i < na; i += stride) {
        float4 v = *(const float4*)(a + i);
        ushort4 o; o.x = f2b(v.x); o.y = f2b(v.y); o.z = f2b(v.z); o.w = f2b(v.w);
        *(ushort4*)(ao + i) = o;
    }
    for (long i = i0; i < nb; i += stride) {
        float4 v = *(const float4*)(b + i);
        ushort4 o; o.x = f2b(v.x); o.y = f2b(v.y); o.z = f2b(v.z); o.w = f2b(v.w);
        *(ushort4*)(bo + i) = o;
    }
    for (long i = i0; i < nc; i += stride) {
        float4 v = *(const float4*)(c + i);
        ushort4 o; o.x = f2b(v.x); o.y = f2b(v.y); o.z = f2b(v.z); o.w = f2b(v.w);
        *(ushort4*)(co + i) = o;
    }
    for (long i = i0; i < nd; i += stride) {
        float4 v = *(const float4*)(d + i);
        ushort4 o; o.x = f2b(v.x); o.y = f2b(v.y); o.z = f2b(v.z); o.w = f2b(v.w);
        *(ushort4*)(dd + i) = o;
    }
}

// ---------------- im2col -> bf16 patches[4608, 768] ----------------
__global__ void im2col_k(const float* __restrict__ x, ushortT* __restrict__ p) {
    for (long idx = (long)blockIdx.x * 256 + threadIdx.x; idx < (long)4608 * 768; idx += (long)gridDim.x * 256) {
        int row = (int)(idx / 768), col = (int)(idx - (long)row * 768);
        int b = row / NL0, pi = row - b * NL0;
        int gy = pi / GRIDW, gx = pi - gy * GRIDW;
        int c = col >> 8, r = col & 255;
        int py = r >> 4, px = r & 15;
        p[idx] = f2b(x[(((long)(b * 3 + c) * 384) + gy * 16 + py) * 384 + gx * 16 + px]);
    }
}

__global__ void cls_k(const float* __restrict__ cls, ushortT* __restrict__ t) {
    t[(long)blockIdx.x * NL * DDIM + threadIdx.x] = f2b(cls[threadIdx.x]);
}

__global__ void rope_k(float* __restrict__ sin_t, float* __restrict__ cos_t) {
    int pos = blockIdx.x, d = threadIdx.x;
    int gy = pos / GRIDW, gx = pos - gy * GRIDW;
    int j = d >> 1;
    float ang;
    if (j < 16) ang = (float)gy * powf(10000.f, -(float)j / 16.f);
    else        ang = (float)gx * powf(10000.f, -(float)(j - 16) / 16.f);
    sin_t[pos * 64 + d] = sinf(ang);
    cos_t[pos * 64 + d] = cosf(ang);
}

// ---------------- LayerNorm over bf16 input, vectorized: 2 rows/block ----------------
// threads 0-191 active: row r = tid/96, 8 cols each via u32x4 (16B/lane).
__global__ __launch_bounds__(256) void ln_k(const ushortT* __restrict__ in,
                                            const float* __restrict__ sc,
                                            const float* __restrict__ bi,
                                            ushortT* __restrict__ outb) {
    int tid = threadIdx.x;
    int r = tid / 96, j = tid - r * 96;
    bool act = tid < 192;
    size_t rb = ((size_t)blockIdx.x * 2 + (act ? r : 0)) * DDIM;
    float x[8];
    float s = 0.f, s2 = 0.f;
    if (act) {
        u32x4 v = *(const u32x4*)(in + rb + j * 8);
        unpack8(v, x);
        #pragma unroll
        for (int i = 0; i < 8; ++i) { s += x[i]; s2 += x[i] * x[i]; }
    }
    __shared__ float red0[2][128], red1[2][128];
    if (act) { red0[r][j] = s; red1[r][j] = s2; }
    else { int idx = tid - 192; red0[idx >> 5][96 + (idx & 31)] = 0.f; red1[idx >> 5][96 + (idx & 31)] = 0.f; }
    __syncthreads();
    int rr = tid >> 7, q = tid & 127;
    for (int off = 64; off; off >>= 1) {
        if (q < off) { red0[rr][q] += red0[rr][q + off]; red1[rr][q] += red1[rr][q + off]; }
        __syncthreads();
    }
    if (act) {
        float mean = red0[r][0] * (1.f / 768.f);
        float var  = red1[r][0] * (1.f / 768.f) - mean * mean;
        float inv = rsqrtf(var + EPSV);
        float y[8];
        #pragma unroll
        for (int i = 0; i < 8; ++i) { int c = j * 8 + i; y[i] = (x[i] - mean) * inv * sc[c] + bi[c]; }
        *(u32x4*)(outb + rb + j * 8) = pack8(y);
    }
}

// ---------------- fused: t += mlp2_bias + sum2(bf16 psum); then LN1 -> h_bf (vectorized, 2 rows/block) ----
__global__ __launch_bounds__(256) void red_ln_k(const ushortT* __restrict__ psum,
                                                const float* __restrict__ b2,
                                                ushortT* __restrict__ t,
                                                const float* __restrict__ sc,
                                                const float* __restrict__ bi,
                                                ushortT* __restrict__ outb) {
    int tid = threadIdx.x;
    int r = tid / 96, j = tid - r * 96;
    bool act = tid < 192;
    const size_t S = (size_t)MPAD * DDIM;
    size_t rb = ((size_t)blockIdx.x * 2 + (act ? r : 0)) * DDIM;
    float x[8];
    float s = 0.f, s2 = 0.f;
    if (act) {
        float xt[8], p0[8], p1[8];
        unpack8(*(const u32x4*)(t + rb + j * 8), xt);
        unpack8(*(const u32x4*)(psum + rb + j * 8), p0);
        unpack8(*(const u32x4*)(psum + S + rb + j * 8), p1);
        #pragma unroll
        for (int i = 0; i < 8; ++i) {
            int c = j * 8 + i;
            x[i] = xt[i] + b2[c] + p0[i] + p1[i];
            s += x[i]; s2 += x[i] * x[i];
        }
        *(u32x4*)(t + rb + j * 8) = pack8(x);
    }
    __shared__ float red0[2][128], red1[2][128];
    if (act) { red0[r][j] = s; red1[r][j] = s2; }
    else { int idx = tid - 192; red0[idx >> 5][96 + (idx & 31)] = 0.f; red1[idx >> 5][96 + (idx & 31)] = 0.f; }
    __syncthreads();
    int rr = tid >> 7, q = tid & 127;
    for (int off = 64; off; off >>= 1) {
        if (q < off) { red0[rr][q] += red0[rr][q + off]; red1[rr][q] += red1[rr][q + off]; }
        __syncthreads();
    }
    if (act) {
        float mean = red0[r][0] * (1.f / 768.f);
        float var  = red1[r][0] * (1.f / 768.f) - mean * mean;
        float inv = rsqrtf(var + EPSV);
        float y[8];
        #pragma unroll
        for (int i = 0; i < 8; ++i) { int c = j * 8 + i; y[i] = (x[i] - mean) * inv * sc[c] + bi[c]; }
        *(u32x4*)(outb + rb + j * 8) = pack8(y);
    }
}

// ---------------- final: reduce CLS rows only + final LN -> d_out[8,768] f32 ----------------
__global__ __launch_bounds__(256) void red_final_k(const ushortT* __restrict__ psum,
                                                   const float* __restrict__ b2,
                                                   const ushortT* __restrict__ t,
                                                   const float* __restrict__ sc,
                                                   const float* __restrict__ bi,
                                                   float* __restrict__ outf) {
    int row = blockIdx.x * NL;            // CLS row of batch blockIdx.x
    const size_t S = (size_t)MPAD * DDIM;
    const size_t rb = (size_t)row * DDIM;
    float x[3];
    float s = 0.f, s2 = 0.f;
    #pragma unroll
    for (int i = 0; i < 3; ++i) {
        int c = threadIdx.x + i * 256;
        float v = b2f(t[rb + c]) + b2[c] + b2f(psum[rb + c]) + b2f(psum[S + rb + c]);
        x[i] = v; s += v; s2 += v * v;
    }
    __shared__ float red0[256], red1[256];
    red0[threadIdx.x] = s; red1[threadIdx.x] = s2;
    __syncthreads();
    for (int off = 128; off; off >>= 1) {
        if (threadIdx.x < off) {
            red0[threadIdx.x] += red0[threadIdx.x + off];
            red1[threadIdx.x] += red1[threadIdx.x + off];
        }
        __syncthreads();
    }
    float mean = red0[0] * (1.f / 768.f);
    float var  = red1[0] * (1.f / 768.f) - mean * mean;
    float inv = rsqrtf(var + EPSV);
    #pragma unroll
    for (int i = 0; i < 3; ++i) {
        int c = threadIdx.x + i * 256;
        outf[(long)blockIdx.x * 768 + c] = (x[i] - mean) * inv * sc[c] + bi[c];
    }
}

// ---------------- templated bf16 MFMA GEMM (2-stage dbuf, NW waves) ----------------
// flags: 1=bias 2=resid 4=gelu 8=remap 16=store f32 32=store bf16 64=qkv mode
//        128=resid is bf16 (residual-stream)
template<int WR, int WC, int MI, int NI, int SPLITK, int NW>
__global__ __launch_bounds__(NW * 64) void gemm_t(const ushortT* __restrict__ A,
                                                  const ushortT* __restrict__ W,
                                                  const float* __restrict__ bias,
                                                  const float* __restrict__ resid,
                                                  float* __restrict__ Cf,
                                                  ushortT* __restrict__ Cb,
                                                  const float* __restrict__ sinT,
                                                  const float* __restrict__ cosT,
                                                  ushortT* __restrict__ qo,
                                                  ushortT* __restrict__ ko,
                                                  ushortT* __restrict__ vo,
                                                  ushortT* __restrict__ psum,
                                                  int N, int K, int flags) {
    constexpr int BM = WR * MI * 16;
    constexpr int BN = WC * NI * 16;
    constexpr int THREADS = NW * 64;
    constexpr int ACH = (BM * 64) / (THREADS * 8);
    constexpr int BCH = (BN * 64) / (THREADS * 8);
    __shared__ ushortT As[2][BM * 64];
    __shared__ ushortT Bs[2][BN * 64];
    int tid = threadIdx.x;
    int lane = tid & 63, wid = tid >> 6;
    int wm = wid / WC, wn = wid % WC;
    int lr = lane & 15, lk = lane >> 4;
    int nwg = gridDim.x * gridDim.y;
    int flat = blockIdx.y * gridDim.x + blockIdx.x;
    int qq = nwg >> 3, rr = nwg & 7;
    int xcd = flat & 7, idx = flat >> 3;
    int wg = (xcd < rr ? xcd * (qq + 1) : rr * (qq + 1) + (xcd - rr) * qq) + idx;
    int bx = wg % gridDim.x, by = wg / gridDim.x;
    int m0 = by * BM, n0 = bx * BN;
    int kspan = K / SPLITK;
    int k0 = (SPLITK > 1) ? blockIdx.z * kspan : 0;
    f32x4 acc[MI][NI] = {};

    auto stage = [&](int buf, int kt) {
        #pragma unroll
        for (int i = 0; i < ACH; ++i) {
            int ch = i * THREADS + tid;
            int r = ch >> 3, cb = (ch & 7) * 16;
            int cbs = cb ^ ((r & 7) << 4);
            load_lds16(A + (size_t)(m0 + r) * K + kt + (cbs >> 1), &As[buf][ch * 8]);
        }
        #pragma unroll
        for (int i = 0; i < BCH; ++i) {
            int ch = i * THREADS + tid;
            int r = ch >> 3, cb = (ch & 7) * 16;
            int cbs = cb ^ ((r & 7) << 4);
            load_lds16(W + (size_t)(n0 + r) * K + kt + (cbs >> 1), &Bs[buf][ch * 8]);
        }
    };

    stage(0, k0);
    asm volatile("s_waitcnt vmcnt(0)" ::: "memory");
    __builtin_amdgcn_s_barrier();
    int nk = kspan / 64;
    int cur = 0;
    for (int it = 0; it < nk; ++it) {
        if (it + 1 < nk) stage(cur ^ 1, k0 + (it + 1) * 64);
        #pragma unroll
        for (int ks = 0; ks < 2; ++ks) {
            bf16x8 aF[MI], bF[NI];
            #pragma unroll
            for (int mi = 0; mi < MI; ++mi) {
                int row = wm * MI * 16 + mi * 16 + lr;
                aF[mi] = *(const bf16x8*)((const char*)&As[cur][0] + row * 128 +
                                          ((ks * 64 + lk * 16) ^ ((row & 7) << 4)));
            }
            #pragma unroll
            for (int ni = 0; ni < NI; ++ni) {
                int row = wn * NI * 16 + ni * 16 + lr;
                bF[ni] = *(const bf16x8*)((const char*)&Bs[cur][0] + row * 128 +
                                          ((ks * 64 + lk * 16) ^ ((row & 7) << 4)));
            }
            #pragma unroll
            for (int mi = 0; mi < MI; ++mi)
                #pragma unroll
                for (int ni = 0; ni < NI; ++ni)
                    acc[mi][ni] = __builtin_amdgcn_mfma_f32_16x16x32_bf16(aF[mi], bF[ni], acc[mi][ni], 0, 0, 0);
        }
        asm volatile("s_waitcnt vmcnt(0)" ::: "memory");
        __builtin_amdgcn_s_barrier();
        cur ^= 1;
    }

    if (SPLITK > 1) {
        #pragma unroll
        for (int mi = 0; mi < MI; ++mi) {
            int rbase = m0 + wm * MI * 16 + mi * 16 + (lane >> 4) * 4;
            #pragma unroll
            for (int ni = 0; ni < NI; ++ni) {
                int c = n0 + wn * NI * 16 + ni * 16 + lr;
                #pragma unroll
                for (int r = 0; r < 4; ++r)
                    psum[((size_t)blockIdx.z * MPAD + rbase + r) * N + c] = f2b(acc[mi][ni][r]);
            }
        }
        return;
    }
    if (flags & 64) {
        if constexpr (NI == 4 && BN == 128) {
            int selB = n0 / DDIM;      // 768 % 128 == 0: block lies wholly in q, k, or v
            if (selB == 2) {
                // V block: bounce through LDS (reuse As) for coalesced transposed writes.
                ushortT* vtile = &As[0][0];
                #pragma unroll
                for (int mi = 0; mi < MI; ++mi) {
                    #pragma unroll
                    for (int ni = 0; ni < NI; ++ni) {
                        #pragma unroll
                        for (int r = 0; r < 4; ++r) {
                            int ll = wm * MI * 16 + mi * 16 + (lane >> 4) * 4 + r;
                            int dl = wn * 64 + ni * 16 + lr;
                            vtile[dl * BM + (ll ^ ((dl & 7) << 4))] = f2b(acc[mi][ni][r]);
                        }
                    }
                }
                __syncthreads();
                for (int e = tid; e < 128 * BM; e += THREADS) {
                    int dl = e / BM, ll = e - dl * BM;
                    int row = m0 + ll;
                    if (row < MROWS) {
                        int b = row / NL, l = row - b * NL;
                        int cv = (n0 - 2 * DDIM) + dl;
                        int h = cv >> 6, d = cv & 63;
                        int bh = b * NHEAD + h;
                        vo[((long)bh * HDIM + d) * LPAD + l] = vtile[dl * BM + (ll ^ ((dl & 7) << 4))];
                    }
                }
            } else {
                #pragma unroll
                for (int mi = 0; mi < MI; ++mi) {
                    #pragma unroll
                    for (int r = 0; r < 4; ++r) {
                        int row = m0 + wm * MI * 16 + mi * 16 + (lane >> 4) * 4 + r;
                        if (row >= MROWS) continue;
                        int b = row / NL, l = row - b * NL;
                        #pragma unroll
                        for (int ni = 0; ni < NI; ++ni) {
                            int c = n0 + wn * 64 + ni * 16 + lr;
                            float val = acc[mi][ni][r];
                            int sel = c / DDIM;
                            int cc = c - sel * DDIM;
                            int h = cc >> 6, d = cc & 63;
                            if (l > 0) {
                                int pos = l - 1;
                                float cs = cosT[pos * 64 + d], sn = sinT[pos * 64 + d];
                                float partner = acc[mi][ni ^ 2][r];
                                float rh = (d < 32) ? -partner : partner;
                                val = val * cs + rh * sn;
                            }
                            int bh = b * NHEAD + h;
                            if (sel == 0) qo[((long)bh * LPAD + l) * HDIM + d] = f2b(val * 0.125f);
                            else          ko[((long)bh * LPAD + l) * HDIM + d] = f2b(val);
                        }
                    }
                }
            }
        }
        return;
    }
    #pragma unroll
    for (int mi = 0; mi < MI; ++mi) {
        int rbase = m0 + wm * MI * 16 + mi * 16 + (lane >> 4) * 4;
        #pragma unroll
        for (int ni = 0; ni < NI; ++ni) {
            int c = n0 + wn * NI * 16 + ni * 16 + lr;
            float bv = (flags & 1) ? bias[c] : 0.f;
            #pragma unroll
            for (int r = 0; r < 4; ++r) {
                int row = rbase + r;
                float val = acc[mi][ni][r] + bv;
                if (flags & 4) val = 0.5f * val * (1.f + erff(val * 0.70710678118654752f));
                long orow = row;
                if (flags & 8) orow = (long)(row / NL0) * NL + 1 + (row % NL0);
                if (flags & 2) {
                    if (flags & 128) val += b2f(((const ushortT*)resid)[orow * (long)N + c]);
                    else             val += resid[orow * (long)N + c];
                }
                if (flags & 16) Cf[orow * (long)N + c] = val;
                if (flags & 32) Cb[orow * (long)N + c] = f2b(val);
            }
        }
    }
}

// ---------------- MFMA flash attention: 2 q-tiles per block + fused weight conversion ----------------
// T1 head-chunking (480 = 8*60). T14 async-STAGE: next K/V tile loaded into
// registers BEFORE compute; ds_write between barriers replaces the drain.
__global__ __launch_bounds__(256) void fattn_k(const ushortT* __restrict__ q,
                                               const ushortT* __restrict__ k,
                                               const ushortT* __restrict__ vt,
                                               ushortT* __restrict__ o,
                                               const float* __restrict__ wa, ushortT* __restrict__ wao, long na,
                                               const float* __restrict__ wb, ushortT* __restrict__ wbo, long nbn,
                                               const float* __restrict__ wc, ushortT* __restrict__ wco, long nc,
                                               const float* __restrict__ wd, ushortT* __restrict__ wdo, long nd) {
    if (blockIdx.x >= 96 * QT2) {
        int cid = blockIdx.x - 96 * QT2;
        long stride = (long)NCONV * 1024;
        long i0 = ((long)cid * 256 + threadIdx.x) * 4;
        for (long i = i0; i < na; i += stride) {
            float4 v = *(const float4*)(wa + i);
            ushort4 t4; t4.x = f2b(v.x); t4.y = f2b(v.y); t4.z = f2b(v.z); t4.w = f2b(v.w);
            *(ushort4*)(wao + i) = t4;
        }
        for (long i = i0; i < nbn; i += stride) {
            float4 v = *(const float4*)(wb + i);
            ushort4 t4; t4.x = f2b(v.x); t4.y = f2b(v.y); t4.z = f2b(v.z); t4.w = f2b(v.w);
            *(ushort4*)(wbo + i) = t4;
        }
        for (long i = i0; i < nc; i += stride) {
            float4 v = *(const float4*)(wc + i);
            ushort4 t4; t4.x = f2b(v.x); t4.y = f2b(v.y); t4.z = f2b(v.z); t4.w = f2b(v.w);
            *(ushort4*)(wco + i) = t4;
        }
        for (long i = i0; i < nd; i += stride) {
            float4 v = *(const float4*)(wd + i);
            ushort4 t4; t4.x = f2b(v.x); t4.y = f2b(v.y); t4.z = f2b(v.z); t4.w = f2b(v.w);
            *(ushort4*)(wdo + i) = t4;
        }
        return;
    }
    int flat = blockIdx.x;
    int wg = (flat & 7) * 60 + (flat >> 3);
    __shared__ ushortT Qs[2][4096], Ks[4096], Vs[4096], Ps[4096];
    int tid = threadIdx.x;
    int wave = tid >> 6, lane = tid & 63;
    int lr = lane & 15, lk = lane >> 4, g = lk;
    int bh = wg / QT2, qp = wg % QT2;
    int q0 = qp * 128;
    int b = bh / NHEAD, h = bh - b * NHEAD;
    int l8 = lane >> 3, c16 = lane & 7;
    int colsw = (c16 * 16) ^ ((l8 & 7) << 4);

    #pragma unroll
    for (int qs = 0; qs < 2; ++qs) {
        const ushortT* src = q + ((long)bh * LPAD + q0 + qs * 64) * HDIM;
        #pragma unroll
        for (int j = 0; j < 2; ++j) {
            int row = wave * 16 + j * 8 + l8;
            load_lds16(src + (long)row * HDIM + (colsw >> 1), Qs[qs] + wave * 1024 + j * 512);
        }
    }
    // prologue: tile 0 K/V into registers (latency overlaps Q staging + qF setup)
    u32x4 kr[2], vr[2];
    {
        const ushortT* srck = k + (long)bh * LPAD * HDIM;
        const ushortT* srcv = vt + (long)bh * HDIM * LPAD;
        #pragma unroll
        for (int j = 0; j < 2; ++j) {
            int row = wave * 16 + j * 8 + l8;
            kr[j] = *(const u32x4*)(srck + (long)row * HDIM + (colsw >> 1));
            vr[j] = *(const u32x4*)(srcv + (long)row * LPAD + (colsw >> 1));
        }
    }
    __syncthreads();
    bf16x8 qF[2][2];
    #pragma unroll
    for (int qs = 0; qs < 2; ++qs)
        #pragma unroll
        for (int ks = 0; ks < 2; ++ks) {
            int row = wave * 16 + lr;
            qF[qs][ks] = *(const bf16x8*)((const char*)Qs[qs] + row * 128 +
                                          ((ks * 64 + lk * 16) ^ ((lr & 7) << 4)));
        }
    f32x4 oa[2][4] = {};
    float m_r[2][4], l_r[2][4];
    #pragma unroll
    for (int qs = 0; qs < 2; ++qs)
        #pragma unroll
        for (int r = 0; r < 4; ++r) { m_r[qs][r] = -3e38f; l_r[qs][r] = 0.f; }

    for (int t0 = 0; t0 < 10; ++t0) {
        #pragma unroll
        for (int j = 0; j < 2; ++j) {
            *(u32x4*)((char*)Ks + wave * 2048 + j * 1024 + lane * 16) = kr[j];
            *(u32x4*)((char*)Vs + wave * 2048 + j * 1024 + lane * 16) = vr[j];
        }
        __syncthreads();
        if (t0 + 1 < 10) {
            int k1 = (t0 + 1) * 64;
            const ushortT* srck = k + ((long)bh * LPAD + k1) * HDIM;
            const ushortT* srcv = vt + (long)bh * HDIM * LPAD + k1;
            #pragma unroll
            for (int j = 0; j < 2; ++j) {
                int row = wave * 16 + j * 8 + l8;
                kr[j] = *(const u32x4*)(srck + (long)row * HDIM + (colsw >> 1));
                vr[j] = *(const u32x4*)(srcv + (long)row * LPAD + (colsw >> 1));
            }
        }
        int k0 = t0 * 64;
        #pragma unroll
        for (int qs = 0; qs < 2; ++qs) {
            f32x4 s[4] = {};
            #pragma unroll
            for (int ks = 0; ks < 2; ++ks) {
                #pragma unroll
                for (int kt = 0; kt < 4; ++kt) {
                    int row = kt * 16 + lr;
                    bf16x8 kF = *(const bf16x8*)((const char*)Ks + row * 128 +
                                                 ((ks * 64 + lk * 16) ^ ((lr & 7) << 4)));
                    s[kt] = __builtin_amdgcn_mfma_f32_16x16x32_bf16(qF[qs][ks], kF, s[kt], 0, 0, 0);
                }
            }
            if (k0 + 63 > 576) {
                #pragma unroll
                for (int kt = 0; kt < 4; ++kt)
                    if (k0 + kt * 16 + lr > 576) {
                        #pragma unroll
                        for (int r = 0; r < 4; ++r) s[kt][r] = -3e38f;
                    }
            }
            float mx[4], al[4], rs[4];
            #pragma unroll
            for (int r = 0; r < 4; ++r)
                mx[r] = fmaxf(fmaxf(s[0][r], s[1][r]), fmaxf(s[2][r], s[3][r]));
            #pragma unroll
            for (int off = 1; off < 16; off <<= 1) {
                #pragma unroll
                for (int r = 0; r < 4; ++r) mx[r] = fmaxf(mx[r], __shfl_xor(mx[r], off));
            }
            #pragma unroll
            for (int r = 0; r < 4; ++r) {
                float mn = fmaxf(m_r[qs][r], mx[r]);
                al[r] = __expf(m_r[qs][r] - mn);
                m_r[qs][r] = mn;
                rs[r] = 0.f;
            }
            #pragma unroll
            for (int kt = 0; kt < 4; ++kt) {
                #pragma unroll
                for (int r = 0; r < 4; ++r) {
                    float p = __expf(s[kt][r] - m_r[qs][r]);
                    rs[r] += p;
                    int rowp = g * 4 + r;
                    *(ushortT*)((char*)Ps + wave * 2048 + rowp * 128 +
                                ((kt * 32 + lr * 2) ^ ((rowp & 7) << 4))) = f2b(p);
                }
            }
            #pragma unroll
            for (int off = 1; off < 16; off <<= 1) {
                #pragma unroll
                for (int r = 0; r < 4; ++r) rs[r] += __shfl_xor(rs[r], off);
            }
            #pragma unroll
            for (int r = 0; r < 4; ++r) l_r[qs][r] = l_r[qs][r] * al[r] + rs[r];
            #pragma unroll
            for (int dt = 0; dt < 4; ++dt) {
                #pragma unroll
                for (int r = 0; r < 4; ++r) oa[qs][dt][r] *= al[r];
            }
            #pragma unroll
            for (int ks = 0; ks < 2; ++ks) {
                bf16x8 pA = *(const bf16x8*)((const char*)Ps + wave * 2048 + lr * 128 +
                                             ((ks * 64 + lk * 16) ^ ((lr & 7) << 4)));
                #pragma unroll
                for (int dt = 0; dt < 4; ++dt) {
                    bf16x8 vF = *(const bf16x8*)((const char*)Vs + (dt * 16 + lr) * 128 +
                                                 ((ks * 64 + lk * 16) ^ ((lr & 7) << 4)));
                    oa[qs][dt] = __builtin_amdgcn_mfma_f32_16x16x32_bf16(pA, vF, oa[qs][dt], 0, 0, 0);
                }
            }
        }
        __syncthreads();
    }
    #pragma unroll
    for (int qs = 0; qs < 2; ++qs) {
        #pragma unroll
        for (int r = 0; r < 4; ++r) {
            int l = q0 + qs * 64 + wave * 16 + g * 4 + r;
            if (l > 576) continue;
            float inv = 1.f / l_r[qs][r];
            #pragma unroll
            for (int dt = 0; dt < 4; ++dt)
                o[((long)(b * NL + l)) * DDIM + h * HDIM + dt * 16 + lr] = f2b(oa[qs][dt][r] * inv);
        }
    }
}

extern "C" void kernel_launch(void* const* d_in, const int* in_sizes, int n_in,
                              void* d_out, int out_size, void* d_ws, size_t ws_size,
                              hipStream_t stream) {
    const float* x       = (const float*)d_in[0];
    const float* patch_w = (const float*)d_in[1];
    const float* patch_b = (const float*)d_in[2];
    const float* cls     = (const float*)d_in[3];
    const float* ln1_s   = (const float*)d_in[4];
    const float* ln1_b   = (const float*)d_in[5];
    const float* qkv_w   = (const float*)d_in[6];
    const float* proj_w  = (const float*)d_in[7];
    const float* proj_b  = (const float*)d_in[8];
    const float* ln2_s   = (const float*)d_in[9];
    const float* ln2_b   = (const float*)d_in[10];
    const float* mlp_w1  = (const float*)d_in[11];
    const float* mlp_b1  = (const float*)d_in[12];
    const float* mlp_w2  = (const float*)d_in[13];
    const float* mlp_b2  = (const float*)d_in[14];
    const float* norm_s  = (const float*)d_in[15];
    const float* norm_b  = (const float*)d_in[16];

    const size_t SZ_WQ = (size_t)3 * DDIM * DDIM;
    const size_t SZ_WP = (size_t)DDIM * DDIM;
    const size_t SZ_W1 = (size_t)NHID * DDIM;
    const size_t SZ_W2 = (size_t)DDIM * NHID;

    char* w = (char*)d_ws;
    ushortT* t    = (ushortT*)w;  w += (size_t)MPAD * DDIM * 2;      // bf16 residual stream
    float* sin_t  = (float*)w;  w += (size_t)NL0 * HDIM * 4;
    float* cos_t  = (float*)w;  w += (size_t)NL0 * HDIM * 4;
    ushortT* psum = (ushortT*)w; w += (size_t)2 * MPAD * DDIM * 2;   // bf16 partials (split-K=2)
    ushortT* h_bf   = (ushortT*)w; w += (size_t)MPAD * DDIM * 2;
    ushortT* o_bf   = (ushortT*)w; w += (size_t)MPAD * DDIM * 2;
    ushortT* mlp_bf = (ushortT*)w; w += (size_t)MPAD * NHID * 2;
    ushortT* patches = mlp_bf;    // alias: disjoint lifetime (pre-loop only)
    ushortT* q_bf   = (ushortT*)w; w += (size_t)96 * LPAD * HDIM * 2;
    ushortT* k_bf   = (ushortT*)w; w += (size_t)96 * LPAD * HDIM * 2;
    ushortT* v_t    = (ushortT*)w; w += (size_t)96 * HDIM * LPAD * 2;
    ushortT* pw_bf  = (ushortT*)w; w += (size_t)DDIM * 768 * 2;
    // double-buffered per-layer weight sets
    ushortT* wqB[2]; ushortT* wpB[2]; ushortT* w1B[2]; ushortT* w2B[2];
    for (int s = 0; s < 2; ++s) {
        wqB[s] = (ushortT*)w; w += SZ_WQ * 2;
        wpB[s] = (ushortT*)w; w += SZ_WP * 2;
        w1B[s] = (ushortT*)w; w += SZ_W1 * 2;
        w2B[s] = (ushortT*)w; w += SZ_W2 * 2;
    }

    const float* nfp = nullptr;
    ushortT* nus = nullptr;
    float* nf = nullptr;

    hipLaunchKernelGGL(rope_k, dim3(NL0), dim3(64), 0, stream, sin_t, cos_t);
    hipLaunchKernelGGL(im2col_k, dim3(2048), dim3(256), 0, stream, x, patches);
    hipLaunchKernelGGL(f2b_k, dim3(512), dim3(256), 0, stream, patch_w, pw_bf, (long)DDIM * 768);
    hipLaunchKernelGGL(cls_k, dim3(NB), dim3(DDIM), 0, stream, cls, t);
    // layer-0 weights
    hipLaunchKernelGGL(wconv4_k, dim3(1024), dim3(256), 0, stream,
                       qkv_w, wqB[0], (long)SZ_WQ,
                       proj_w, wpB[0], (long)SZ_WP,
                       mlp_w1, w1B[0], (long)SZ_W1,
                       mlp_w2, w2B[0], (long)SZ_W2);
    // patch embed: 64x128 tile, 8 waves, grid 6x72; store bf16 t with remap
    hipLaunchKernelGGL((gemm_t<2, 4, 2, 2, 1, 8>), dim3(DDIM / 128, 4608 / 64), dim3(512), 0, stream,
                       patches, pw_bf, patch_b, nfp, nf, t, nfp, nfp, nus, nus, nus, nus,
                       DDIM, 768, 1 | 8 | 32);

    for (int i = 0; i < NDEPTH; ++i) {
        int cur = i & 1, nxt = (i + 1) & 1;
        if (i == 0) {
            hipLaunchKernelGGL(ln_k, dim3(MROWS / 2), dim3(256), 0, stream,
                               t, ln1_s, ln1_b, h_bf);
        } else {
            hipLaunchKernelGGL(red_ln_k, dim3(MROWS / 2), dim3(256), 0, stream,
                               psum, mlp_b2 + (i - 1) * DDIM, t,
                               ln1_s + i * DDIM, ln1_b + i * DDIM, h_bf);
        }
        // QKV GEMM (128x128, 8 waves) with fused RoPE + scatter (coalesced V via LDS bounce)
        hipLaunchKernelGGL((gemm_t<4, 2, 2, 4, 1, 8>), dim3((3 * DDIM) / 128, MPAD / 128), dim3(512), 0, stream,
                           h_bf, wqB[cur], nfp, nfp, nf, nus, sin_t, cos_t,
                           q_bf, k_bf, v_t, nus, 3 * DDIM, DDIM, 64);
        // attention (2 q-tiles/block, T1 head-chunking, T14 async-stage) + fused weight conversion
        long cn = (i + 1 < NDEPTH) ? 1 : 0;
        hipLaunchKernelGGL(fattn_k, dim3(96 * QT2 + NCONV), dim3(256), 0, stream,
                           q_bf, k_bf, v_t, o_bf,
                           qkv_w + SZ_WQ * (i + 1), wqB[nxt], cn * (long)SZ_WQ,
                           proj_w + SZ_WP * (i + 1), wpB[nxt], cn * (long)SZ_WP,
                           mlp_w1 + SZ_W1 * (i + 1), w1B[nxt], cn * (long)SZ_W1,
                           mlp_w2 + SZ_W2 * (i + 1), w2B[nxt], cn * (long)SZ_W2);
        // proj: 64x128 tile, 8 waves; bf16 resid read + bf16 t store
        hipLaunchKernelGGL((gemm_t<2, 4, 2, 2, 1, 8>), dim3(DDIM / 128, MPAD / 64), dim3(512), 0, stream,
                           o_bf, wpB[cur], proj_b + i * DDIM, (const float*)t, nf, t,
                           nfp, nfp, nus, nus, nus, nus,
                           DDIM, DDIM, 1 | 2 | 32 | 128);
        hipLaunchKernelGGL(ln_k, dim3(MROWS / 2), dim3(256), 0, stream,
                           t, ln2_s + i * DDIM, ln2_b + i * DDIM, h_bf);
        // mlp1: 128x128, 8 waves
        hipLaunchKernelGGL((gemm_t<4, 2, 2, 4, 1, 8>), dim3(NHID / 128, MPAD / 128), dim3(512), 0, stream,
                           h_bf, w1B[cur], mlp_b1 + i * NHID, nfp, nf, mlp_bf, nfp, nfp,
                           nus, nus, nus, nus, NHID, DDIM, 1 | 4 | 32);
        // mlp2: split-K 2 bf16 partials, 128x128, 8 waves
        hipLaunchKernelGGL((gemm_t<4, 2, 2, 4, 2, 8>), dim3(DDIM / 128, MPAD / 128, 2), dim3(512), 0, stream,
                           mlp_bf, w2B[cur], nfp, nfp, nf, nus, nfp, nfp,
                           nus, nus, nus, psum, DDIM, NHID, 0);
    }
    // final: reduce CLS rows + final LN -> d_out
    hipLaunchKernelGGL(red_final_k, dim3(NB), dim3(256), 0, stream,
                       psum, mlp_b2 + (NDEPTH - 1) * DDIM, t, norm_s, norm_b, (float*)d_out);
}